// Round 9
// baseline (352.626 us; speedup 1.0000x reference)
//
#include <hip/hip_runtime.h>
#include <hip/hip_bf16.h>
#include <float.h>

#define N_PTS 2048
#define B_SZ  4
#define KNN   20
#define LRELU_S 0.2f
#define FT    512          // featT row stride (channels)
#define NPOOL 16           // conv5 n-chunk partials (128 rows each)

typedef __hip_bfloat16 bf16;
typedef __attribute__((ext_vector_type(8))) short short8v;   // 8 bf16 (4 VGPRs)
typedef __attribute__((ext_vector_type(4))) short short4v;   // 4 bf16
typedef __attribute__((ext_vector_type(4))) float floatx4;

__device__ __forceinline__ float b2f(const bf16 v) { return __bfloat162float(v); }
__device__ __forceinline__ float ldf(const float* p) { return *p; }
__device__ __forceinline__ float ldf(const bf16* p)  { return __bfloat162float(*p); }
__device__ __forceinline__ short8v ld8(const bf16* p) { return *(const short8v*)p; }
__device__ __forceinline__ unsigned umin(unsigned a, unsigned b) { return a < b ? a : b; }
__device__ __forceinline__ short bfbits(float f) {
    bf16 t = __float2bfloat16(f);
    return *reinterpret_cast<short*>(&t);
}

// Direct global->LDS DMA, 16 B per lane. LDS dest is wave-uniform base +
// lane*16 (linear); swizzling is achieved by pre-swizzling the GLOBAL source
// address (rule: both-sides-or-neither).
__device__ __forceinline__ void gload16(const void* g, void* l) {
    __builtin_amdgcn_global_load_lds(
        (const __attribute__((address_space(1))) void*)g,
        (__attribute__((address_space(3))) void*)l, 16, 0, 0);
}

// ---------------------------------------------------------------------------
// Dtype sniffer: bf16 (flag=1) vs fp32 (flag=0). Reads 256 B.
__device__ __forceinline__ int sniff_body(const unsigned short* pts_hw) {
    int sane = 0;
    for (int j = 0; j < 64; ++j) {
        unsigned short v = pts_hw[2 * j];
        int e = (v >> 7) & 0xFF;
        if (e >= 100 && e <= 140) ++sane;
    }
    return (sane >= 32) ? 1 : 0;
}

__global__ void k_sniff(const unsigned short* __restrict__ pts_hw, int* __restrict__ flag) {
    if (threadIdx.x != 0 || blockIdx.x != 0) return;
    *flag = sniff_body(pts_hw);
}

// ---------------------------------------------------------------------------
// Weight repack metadata.
struct WPack {
    const void* src[23];
    int off[24];
    int rows[23];
    int cols[23];
};

__device__ __forceinline__ void repack_body(const WPack& wp, int isb,
                                            float* __restrict__ dst, int i, int limit,
                                            int skip12) {
    if (i >= limit) return;
    int lo = 0, hi = 23;
    while (lo + 1 < hi) { int mid = (lo + hi) >> 1; if (i >= wp.off[mid]) lo = mid; else hi = mid; }
    if (skip12 && lo == 12) return;    // gram path reads w5 only via w5sp
    int j = i - wp.off[lo];
    float v = isb ? b2f(((const bf16*)wp.src[lo])[j]) : ((const float*)wp.src[lo])[j];
    int dj = j;
    int cols = wp.cols[lo];
    if (cols) dj = (j % cols) * wp.rows[lo] + (j / cols);
    dst[wp.off[lo] + dj] = v;
}

// Split EdgeConv weights into bf16 hi/lo pairs for MFMA:
// dst = [W2hi | W2lo | Wdhi | Wdlo], each (COUT, C) row-major, Wd = W1 - W2.
template<int C, int COUT>
__device__ __forceinline__ void wsplit_body(const void* __restrict__ W, int isb,
                                            bf16* __restrict__ dst, int i) {
    if (i >= COUT * C) return;
    int o = i / C, c = i % C;
    float w1 = isb ? b2f(((const bf16*)W)[(size_t)o * 2 * C + c])
                   : ((const float*)W)[(size_t)o * 2 * C + c];
    float w2 = isb ? b2f(((const bf16*)W)[(size_t)o * 2 * C + C + c])
                   : ((const float*)W)[(size_t)o * 2 * C + C + c];
    float wd = w1 - w2;
    bf16 h2 = __float2bfloat16(w2);
    bf16 hd = __float2bfloat16(wd);
    dst[i]                = h2;
    dst[COUT * C + i]     = __float2bfloat16(w2 - b2f(h2));
    dst[2 * COUT * C + i] = hd;
    dst[3 * COUT * C + i] = __float2bfloat16(wd - b2f(hd));
}

// Split conv5 weights (1024x512) into bf16 hi/lo: dst = [hi | lo].
// When inputs are bf16 the lo plane is identically zero and never read.
__device__ __forceinline__ void w5split_body(const void* __restrict__ W, int isb,
                                             bf16* __restrict__ dst, int i) {
    if (i >= 1024 * 512) return;
    float w = isb ? b2f(((const bf16*)W)[i]) : ((const float*)W)[i];
    bf16 h = __float2bfloat16(w);
    dst[i] = h;
    if (!isb) dst[1024 * 512 + i] = __float2bfloat16(w - b2f(h));
}

// points (B,N,3) -> x0 (B,3,N) fp32, dtype-dynamic.
__device__ __forceinline__ void transpose_body(const void* __restrict__ pts, int isb,
                                               float* __restrict__ x0, int i) {
    if (i >= B_SZ * N_PTS) return;
    int b = i / N_PTS, n = i % N_PTS;
    for (int c = 0; c < 3; ++c) {
        size_t s = ((size_t)b * N_PTS + n) * 3 + c;
        float v = isb ? b2f(((const bf16*)pts)[s]) : ((const float*)pts)[s];
        x0[((size_t)b * 3 + c) * N_PTS + n] = v;
    }
}

// Merged prep (gram path): self-sniff + repack + 3x wsplit + w5split +
// transpose in one launch, dispatched by blockIdx range.
__global__ void k_prep(WPack wp, float* __restrict__ wf, int rlimit,
                       const void* __restrict__ w2s, bf16* __restrict__ wsp2,
                       const void* __restrict__ w3s, bf16* __restrict__ wsp3,
                       const void* __restrict__ w4s, bf16* __restrict__ wsp4,
                       const void* __restrict__ w5s, bf16* __restrict__ w5sp,
                       const void* __restrict__ pts, float* __restrict__ x0,
                       int* __restrict__ flagout) {
    __shared__ int sfl;
    if (threadIdx.x == 0) {
        int f = sniff_body((const unsigned short*)pts);
        sfl = f;
        if (blockIdx.x == 0) *flagout = f;
    }
    __syncthreads();
    const int isb = sfl;
    const int nbrep = (rlimit + 255) >> 8;
    int ib = blockIdx.x, t = threadIdx.x;
    if (ib < nbrep) { repack_body(wp, isb, wf, ib * 256 + t, rlimit, 1); return; }
    ib -= nbrep;
    if (ib < 16)   { wsplit_body<64, 64>(w2s, isb, wsp2, ib * 256 + t); return; }
    ib -= 16;
    if (ib < 32)   { wsplit_body<64, 128>(w3s, isb, wsp3, ib * 256 + t); return; }
    ib -= 32;
    if (ib < 128)  { wsplit_body<128, 256>(w4s, isb, wsp4, ib * 256 + t); return; }
    ib -= 128;
    if (ib < 2048) { w5split_body(w5s, isb, w5sp, ib * 256 + t); return; }
    ib -= 2048;
    transpose_body(pts, isb, x0, ib * 256 + t);
}

// Standalone versions for the fallback path.
__global__ void k_repack(WPack wp, const int* __restrict__ flag, float* __restrict__ dst, int limit) {
    repack_body(wp, *flag, dst, blockIdx.x * blockDim.x + threadIdx.x, limit, 0);
}
__global__ void k_transpose(const void* __restrict__ pts, const int* __restrict__ flag,
                            float* __restrict__ x0) {
    transpose_body(pts, *flag, x0, blockIdx.x * blockDim.x + threadIdx.x);
}

// ---------------------------------------------------------------------------
// 32-candidate row loads (lane chunk), fp32 out.
__device__ __forceinline__ void load32(const float* row, int mbase, float* r) {
    const float4* p = (const float4*)(row + mbase);
#pragma unroll
    for (int i = 0; i < 8; ++i) {
        float4 f = p[i];
        r[4 * i + 0] = f.x; r[4 * i + 1] = f.y; r[4 * i + 2] = f.z; r[4 * i + 3] = f.w;
    }
}
__device__ __forceinline__ void load32(const bf16* row, int mbase, float* r) {
    const uint4* p = (const uint4*)(row + mbase);
#pragma unroll
    for (int i = 0; i < 4; ++i) {
        uint4 u = p[i];
        r[8 * i + 0] = __uint_as_float(u.x << 16);
        r[8 * i + 1] = __uint_as_float(u.x & 0xFFFF0000u);
        r[8 * i + 2] = __uint_as_float(u.y << 16);
        r[8 * i + 3] = __uint_as_float(u.y & 0xFFFF0000u);
        r[8 * i + 4] = __uint_as_float(u.z << 16);
        r[8 * i + 5] = __uint_as_float(u.z & 0xFFFF0000u);
        r[8 * i + 6] = __uint_as_float(u.w << 16);
        r[8 * i + 7] = __uint_as_float(u.w & 0xFFFF0000u);
    }
}

// ---------------------------------------------------------------------------
// Packed-key top-20 for two queries per wave, cached per-lane sorted top-2.
__device__ __forceinline__ void s2ins(unsigned k, unsigned& m1, unsigned& m2) {
    unsigned lo = umin(m1, k);
    unsigned hi = (m1 < k) ? k : m1;
    m1 = lo;
    m2 = umin(m2, hi);
}

__device__ __forceinline__ void select20x2(const unsigned* ka, const unsigned* kb,
                                           int* outA, int* outB, int lane) {
    const unsigned SENT = 0xFFFFFFFFu;
    unsigned a1 = SENT, a2 = SENT, b1 = SENT, b2 = SENT;
#pragma unroll
    for (int j = 0; j < 32; ++j) {
        s2ins(ka[j], a1, a2);
        s2ins(kb[j], b1, b2);
    }
#pragma unroll 1
    for (int k = 0; k < KNN; ++k) {
        unsigned va = a1, vb = b1;
#pragma unroll
        for (int off = 32; off >= 1; off >>= 1) {
            va = umin(va, (unsigned)__shfl_xor((int)va, off));
            vb = umin(vb, (unsigned)__shfl_xor((int)vb, off));
        }
        if (lane == 0) { outA[k] = (int)(va & 2047u); outB[k] = (int)(vb & 2047u); }
        if (a1 == va) { a1 = a2; a2 = SENT; }
        if (b1 == vb) { b1 = b2; b2 = SENT; }
        if (a1 == SENT) {
#pragma unroll
            for (int j = 0; j < 32; ++j) {
                unsigned t = (ka[j] > va) ? ka[j] : SENT;
                s2ins(t, a1, a2);
            }
        }
        if (b1 == SENT) {
#pragma unroll
            for (int j = 0; j < 32; ++j) {
                unsigned t = (kb[j] > vb) ? kb[j] : SENT;
                s2ins(t, b1, b2);
            }
        }
    }
}

// ---------------------------------------------------------------------------
// Fused layer-1: kNN (C=3, fp32, packed keys) + EdgeConv (C=3 -> 64) for the
// same 8 points. Select into LDS sidx, cooperative neighbor staging into LDS,
// then 2 points/wave, lane = channel.
__global__ __launch_bounds__(256) void k_knn3ec(const float* __restrict__ x0,
        const float* __restrict__ Wt, const float* __restrict__ gam,
        const float* __restrict__ bet, bf16* __restrict__ featT,
        float* __restrict__ xxout) {
    __shared__ float qf[8][3];
    __shared__ int sidx[8][KNN];
    __shared__ float sh[8][KNN][3];
    int ib = blockIdx.x;
    int b  = ib / (N_PTS / 8);
    int q0 = (ib % (N_PTS / 8)) * 8;
    const float* xb = x0 + (size_t)b * 3 * N_PTS;

    if (threadIdx.x < 24) {
        int q = threadIdx.x / 3, c = threadIdx.x % 3;
        qf[q][c] = xb[(size_t)c * N_PTS + q0 + q];
    }
    __syncthreads();

    int w = threadIdx.x >> 6, lane = threadIdx.x & 63;
    int mbase = lane * 32;

    float da[32], db[32];
#pragma unroll
    for (int j = 0; j < 32; ++j) { da[j] = 0.f; db[j] = 0.f; }
#pragma unroll
    for (int c = 0; c < 3; ++c) {
        float r[32];
        load32(xb + (size_t)c * N_PTS, mbase, r);
        float qac = qf[2 * w][c], qbc = qf[2 * w + 1][c];
#pragma unroll
        for (int j = 0; j < 32; ++j) {
            float ta = r[j] - qac; da[j] = fmaf(ta, ta, da[j]);
            float tb = r[j] - qbc; db[j] = fmaf(tb, tb, db[j]);
        }
    }
    unsigned ka[32], kb[32];
#pragma unroll
    for (int j = 0; j < 32; ++j) {
        ka[j] = (__float_as_uint(da[j]) & 0xFFFFF800u) | (unsigned)(mbase + j);
        kb[j] = (__float_as_uint(db[j]) & 0xFFFFF800u) | (unsigned)(mbase + j);
    }
    select20x2(ka, kb, &sidx[2 * w][0], &sidx[2 * w + 1][0], lane);
    __syncthreads();

    // ---- cooperative neighbor staging: 480 parallel loads (2/thread) ----
    for (int t = threadIdx.x; t < 8 * KNN * 3; t += 256) {
        int pt = t / (KNN * 3);
        int r  = t % (KNN * 3);
        int k = r / 3, c = r % 3;
        int m = sidx[pt][k] & (N_PTS - 1);
        sh[pt][k][c] = xb[(size_t)c * N_PTS + m];
    }
    __syncthreads();

    // ---- EdgeConv phase: points q0+2w, q0+2w+1; lane owns channel `lane` ----
    const float inv = rsqrtf(1.0f + 1e-5f);
    float scale = gam[lane] * inv, bias = bet[lane];
    float w1v[3], w2v[3];
#pragma unroll
    for (int c = 0; c < 3; ++c) {
        w1v[c] = Wt[(size_t)c * 64 + lane];
        w2v[c] = Wt[(size_t)(3 + c) * 64 + lane];
    }
#pragma unroll
    for (int p = 0; p < 2; ++p) {
        int pt = 2 * w + p;
        float base = 0.f;
#pragma unroll
        for (int c = 0; c < 3; ++c) base = fmaf(w1v[c] - w2v[c], qf[pt][c], base);
        float mx = -FLT_MAX;
#pragma unroll
        for (int k = 0; k < KNN; ++k) {
            float acc = 0.f;
#pragma unroll
            for (int c = 0; c < 3; ++c) acc = fmaf(w2v[c], sh[pt][k][c], acc);
            float h = (base + acc) * scale + bias;
            h = h > 0.f ? h : LRELU_S * h;
            mx = fmaxf(mx, h);
        }
        bf16 bv = __float2bfloat16(mx);
        size_t i = (size_t)b * N_PTS + q0 + pt;
        featT[i * FT + lane] = bv;
        float qv = b2f(bv);
        float s = qv * qv;
#pragma unroll
        for (int off = 32; off >= 1; off >>= 1) s += __shfl_xor(s, off);
        if (lane == 0) xxout[i] = s;
    }
}

// ---------------------------------------------------------------------------
// kNN (direct, fallback path): wave-per-query.
template<typename T, int C>
__global__ __launch_bounds__(256) void k_knn(const T* __restrict__ x, int bstride,
                                             int* __restrict__ idx) {
    __shared__ float qf[4][C];
    int ib = blockIdx.x;
    int b  = ib / (N_PTS / 4);
    int q0 = (ib % (N_PTS / 4)) * 4;
    const T* xb = x + (size_t)b * bstride;

    for (int t = threadIdx.x; t < 4 * C; t += 256) {
        int pt = t / C, c = t % C;
        qf[pt][c] = ldf(&xb[(size_t)c * N_PTS + (q0 + pt)]);
    }
    __syncthreads();

    int w = threadIdx.x >> 6, lane = threadIdx.x & 63;
    int q = q0 + w;
    int mbase = lane * 32;

    float v[32];
#pragma unroll
    for (int j = 0; j < 32; ++j) v[j] = 0.f;

    for (int c = 0; c < C; ++c) {
        float qc = qf[w][c];
        float r[32];
        load32(xb + (size_t)c * N_PTS, mbase, r);
#pragma unroll
        for (int j = 0; j < 32; ++j) { float t = r[j] - qc; v[j] = fmaf(t, t, v[j]); }
    }

    for (int k = 0; k < KNN; ++k) {
        float bv = FLT_MAX; int bi = 0x7FFFFFFF;
#pragma unroll
        for (int j = 0; j < 32; ++j)
            if (v[j] < bv) { bv = v[j]; bi = mbase + j; }
#pragma unroll
        for (int off = 32; off >= 1; off >>= 1) {
            float ov = __shfl_xor(bv, off);
            int   oi = __shfl_xor(bi, off);
            if (ov < bv || (ov == bv && oi < bi)) { bv = ov; bi = oi; }
        }
        if (lane == 0) idx[((size_t)b * N_PTS + q) * KNN + k] = bi;
        int wl = bi >> 5, wj = bi & 31;
        if (lane == wl) {
#pragma unroll
            for (int j = 0; j < 32; ++j) if (j == wj) v[j] = FLT_MAX;
        }
    }
}

// ---------------------------------------------------------------------------
// Gram body via MFMA: G[b][n][m] = sum_c X[c][n]*X[c][m], X = featT slice.
template<int C>
__device__ __forceinline__ void gram_body(const bf16* __restrict__ featT, int c0,
                                          float* __restrict__ G,
                                          short* At, short* Bt, int ib) {
    const int KC = 64;
    int b  = ib >> 8;
    int t  = ib & 255;
    int n0 = (t >> 4) << 7;
    int m0 = (t & 15) << 7;

    int tid = threadIdx.x;
    int w = tid >> 6, lane = tid & 63;
    int rw = (w & 1) * 64, cw = (w >> 1) * 64;
    int lrow = lane & 15, quad = lane >> 4;

    floatx4 acc[4][4];
#pragma unroll
    for (int ri = 0; ri < 4; ++ri)
#pragma unroll
        for (int ci = 0; ci < 4; ++ci) acc[ri][ci] = (floatx4){0.f, 0.f, 0.f, 0.f};

    for (int ck = 0; ck < C; ck += KC) {
        __syncthreads();
#pragma unroll
        for (int it = 0; it < 4; ++it) {
            int s = tid + it * 256;
            int row = s >> 3, seg = s & 7;
            int gseg = seg ^ (row & 7);
            gload16(featT + ((size_t)(b * N_PTS + n0 + row) * FT) + c0 + ck + gseg * 8,
                    &At[(s & ~63) * 8]);
            gload16(featT + ((size_t)(b * N_PTS + m0 + row) * FT) + c0 + ck + gseg * 8,
                    &Bt[(s & ~63) * 8]);
        }
        __syncthreads();
#pragma unroll
        for (int kk = 0; kk < KC; kk += 32) {
            int ks = kk >> 3;
            short8v a[4], bb[4];
#pragma unroll
            for (int ri = 0; ri < 4; ++ri) {
                int row = rw + ri * 16 + lrow;
                int seg = (ks + quad) ^ (row & 7);
                a[ri] = *(const short8v*)&At[row * 64 + seg * 8];
            }
#pragma unroll
            for (int ci = 0; ci < 4; ++ci) {
                int row = cw + ci * 16 + lrow;
                int seg = (ks + quad) ^ (row & 7);
                bb[ci] = *(const short8v*)&Bt[row * 64 + seg * 8];
            }
#pragma unroll
            for (int ri = 0; ri < 4; ++ri)
#pragma unroll
                for (int ci = 0; ci < 4; ++ci)
                    acc[ri][ci] = __builtin_amdgcn_mfma_f32_16x16x32_bf16(a[ri], bb[ci], acc[ri][ci], 0, 0, 0);
        }
    }

#pragma unroll
    for (int ri = 0; ri < 4; ++ri)
#pragma unroll
        for (int ci = 0; ci < 4; ++ci) {
            int n = n0 + rw + ri * 16 + quad * 4;
            int m = m0 + cw + ci * 16 + lrow;
            float* gp = G + ((size_t)b * N_PTS + n) * N_PTS + m;
#pragma unroll
            for (int reg = 0; reg < 4; ++reg)
                gp[(size_t)reg * N_PTS] = acc[ri][ci][reg];
        }
}

// ---------------------------------------------------------------------------
// Xform body via MFMA, bf16 output. When inputs are bf16 (isb), the W2
// lo-correction is identically zero -> skip those MFMAs (exact).
template<int COUT, int C>
__device__ __forceinline__ void xform_body(const bf16* __restrict__ featT, int c0,
                                           const bf16* __restrict__ Wsp,
                                           bf16* __restrict__ Yh, int isb,
                                           short* Bt, int ib2) {
    const int M2 = 2 * COUT;
    const int KC = 64;
    int nt = ib2 & 63;
    int mt = ib2 >> 6;
    int tid = threadIdx.x;
    int w = tid >> 6, lane = tid & 63;
    int rw = (w & 1) * 64, cw = (w >> 1) * 64;
    int l15 = lane & 15, quad = lane >> 4;

    floatx4 acc[4][4];
#pragma unroll
    for (int ri = 0; ri < 4; ++ri)
#pragma unroll
        for (int ci = 0; ci < 4; ++ci) acc[ri][ci] = (floatx4){0.f, 0.f, 0.f, 0.f};

    for (int ck = 0; ck < C; ck += KC) {
        __syncthreads();
#pragma unroll
        for (int it = 0; it < 4; ++it) {
            int s = tid + it * 256;
            int row = s >> 3, seg = s & 7;
            int gseg = seg ^ (row & 7);
            gload16(featT + (size_t)(nt * 128 + row) * FT + c0 + ck + gseg * 8,
                    &Bt[(s & ~63) * 8]);
        }
        __syncthreads();
#pragma unroll
        for (int kk = 0; kk < KC; kk += 32) {
            int ks = kk >> 3;
            short8v bfr[4];
#pragma unroll
            for (int ci = 0; ci < 4; ++ci) {
                int row = cw + ci * 16 + l15;
                int seg = (ks + quad) ^ (row & 7);
                bfr[ci] = *(const short8v*)&Bt[row * 64 + seg * 8];
            }
#pragma unroll
            for (int ri = 0; ri < 4; ++ri) {
                int rbase = mt * 128 + rw + ri * 16;          // band-aligned, lane-uniform
                bool uselo = (!isb) || (rbase >= COUT);       // W2 lo==0 when bf16 input
                int mrow = rbase + l15;
                int base = (mrow < COUT) ? mrow : (mrow + COUT);
                const bf16* hi = Wsp + (size_t)base * C + ck + kk + quad * 8;
                short8v ah = ld8(hi);
                short8v al;
                if (uselo) al = ld8(hi + (size_t)COUT * C);
#pragma unroll
                for (int ci = 0; ci < 4; ++ci) {
                    acc[ri][ci] = __builtin_amdgcn_mfma_f32_16x16x32_bf16(ah, bfr[ci], acc[ri][ci], 0, 0, 0);
                    if (uselo)
                        acc[ri][ci] = __builtin_amdgcn_mfma_f32_16x16x32_bf16(al, bfr[ci], acc[ri][ci], 0, 0, 0);
                }
            }
        }
    }

#pragma unroll
    for (int ri = 0; ri < 4; ++ri)
#pragma unroll
        for (int ci = 0; ci < 4; ++ci) {
            int n = nt * 128 + cw + ci * 16 + l15;
            int m = mt * 128 + rw + ri * 16 + quad * 4;
            short4v o4;
            o4[0] = bfbits(acc[ri][ci][0]);
            o4[1] = bfbits(acc[ri][ci][1]);
            o4[2] = bfbits(acc[ri][ci][2]);
            o4[3] = bfbits(acc[ri][ci][3]);
            *(short4v*)(Yh + (size_t)n * M2 + m) = o4;
        }
}

// ---------------------------------------------------------------------------
// Merged gram + xform: first B_SZ*256 blocks do the gram tile, the trailing
// COUT blocks do the dense point transform (fills otherwise-idle CUs).
template<int C, int COUT>
__global__ __launch_bounds__(256) void k_gx(const bf16* __restrict__ featT, int c0,
        const bf16* __restrict__ Wsp, float* __restrict__ G, bf16* __restrict__ Yh,
        const int* __restrict__ flag) {
    __shared__ __align__(16) short lds[2 * 128 * 64];   // 32 KB
    int ib = blockIdx.x;
    if (ib < B_SZ * 256) {
        gram_body<C>(featT, c0, G, lds, lds + 128 * 64, ib);
    } else {
        xform_body<COUT, C>(featT, c0, Wsp, Yh, *flag, lds, ib - B_SZ * 256);
    }
}

// ---------------------------------------------------------------------------
// Merged select + gather-max: block = 8 queries. Phase 1 computes top-20
// into LDS; phase 2 does the gather-max epilogue (2 pts/wave) reading bf16 Y,
// writes featT and next-layer xx. xxin/xxout are distinct (ping-pong).
template<int COUT>
__global__ __launch_bounds__(256) void k_selgmax(const float* __restrict__ G,
        const float* __restrict__ xxin, const bf16* __restrict__ Yh,
        const float* __restrict__ gam, const float* __restrict__ bet,
        bf16* __restrict__ featT, int c0f, float* __restrict__ xxout) {
    const int M2 = 2 * COUT;
    const int OT = COUT / 64;
    __shared__ int sidx[8][KNN];

    int ib = blockIdx.x;
    int b  = ib / (N_PTS / 8);
    int q0 = (ib % (N_PTS / 8)) * 8;
    int w = threadIdx.x >> 6, lane = threadIdx.x & 63;
    int qa = q0 + 2 * w;
    const float* gA = G + ((size_t)b * N_PTS + qa) * N_PTS;
    const float* gB = gA + N_PTS;
    const float* xr = xxin + (size_t)b * N_PTS;
    float xqa = xr[qa], xqb = xr[qa + 1];

    unsigned ka[32], kb[32];
#pragma unroll
    for (int r = 0; r < 8; ++r) {
        int m0 = r * 256 + (lane << 2);
        float4 x4 = *(const float4*)(xr + m0);
        float4 a4 = *(const float4*)(gA + m0);
        float4 b4 = *(const float4*)(gB + m0);
        float s;
        s = fmaf(-2.f, a4.x, x4.x) + xqa; s = fmaxf(s, 0.f);
        ka[4 * r + 0] = (__float_as_uint(s) & 0xFFFFF800u) | (unsigned)(m0 + 0);
        s = fmaf(-2.f, a4.y, x4.y) + xqa; s = fmaxf(s, 0.f);
        ka[4 * r + 1] = (__float_as_uint(s) & 0xFFFFF800u) | (unsigned)(m0 + 1);
        s = fmaf(-2.f, a4.z, x4.z) + xqa; s = fmaxf(s, 0.f);
        ka[4 * r + 2] = (__float_as_uint(s) & 0xFFFFF800u) | (unsigned)(m0 + 2);
        s = fmaf(-2.f, a4.w, x4.w) + xqa; s = fmaxf(s, 0.f);
        ka[4 * r + 3] = (__float_as_uint(s) & 0xFFFFF800u) | (unsigned)(m0 + 3);
        s = fmaf(-2.f, b4.x, x4.x) + xqb; s = fmaxf(s, 0.f);
        kb[4 * r + 0] = (__float_as_uint(s) & 0xFFFFF800u) | (unsigned)(m0 + 0);
        s = fmaf(-2.f, b4.y, x4.y) + xqb; s = fmaxf(s, 0.f);
        kb[4 * r + 1] = (__float_as_uint(s) & 0xFFFFF800u) | (unsigned)(m0 + 1);
        s = fmaf(-2.f, b4.z, x4.z) + xqb; s = fmaxf(s, 0.f);
        kb[4 * r + 2] = (__float_as_uint(s) & 0xFFFFF800u) | (unsigned)(m0 + 2);
        s = fmaf(-2.f, b4.w, x4.w) + xqb; s = fmaxf(s, 0.f);
        kb[4 * r + 3] = (__float_as_uint(s) & 0xFFFFF800u) | (unsigned)(m0 + 3);
    }
    select20x2(ka, kb, &sidx[2 * w][0], &sidx[2 * w + 1][0], lane);
    __syncthreads();

    // ---- gather-max for points qa, qa+1 ----
    size_t iA = (size_t)b * N_PTS + qa;
    const float inv = rsqrtf(1.0f + 1e-5f);
    float yda[OT], ydb[OT], scl[OT], bis[OT], mxa[OT], mxb[OT];
#pragma unroll
    for (int j = 0; j < OT; ++j) {
        int o = lane + 64 * j;
        yda[j] = b2f(Yh[iA * M2 + COUT + o]);
        ydb[j] = b2f(Yh[(iA + 1) * M2 + COUT + o]);
        scl[j] = gam[o] * inv;
        bis[j] = bet[o];
        mxa[j] = -FLT_MAX; mxb[j] = -FLT_MAX;
    }
    const bf16* Yb = Yh + (size_t)b * N_PTS * M2;
#pragma unroll
    for (int k = 0; k < KNN; ++k) {
        int m0 = sidx[2 * w][k] & (N_PTS - 1);
        int m1 = sidx[2 * w + 1][k] & (N_PTS - 1);
        const bf16* r0 = Yb + (size_t)m0 * M2;
        const bf16* r1 = Yb + (size_t)m1 * M2;
#pragma unroll
        for (int j = 0; j < OT; ++j) {
            int o = lane + 64 * j;
            float ha = (yda[j] + b2f(r0[o])) * scl[j] + bis[j];
            ha = ha > 0.f ? ha : LRELU_S * ha;
            mxa[j] = fmaxf(mxa[j], ha);
            float hb = (ydb[j] + b2f(r1[o])) * scl[j] + bis[j];
            hb = hb > 0.f ? hb : LRELU_S * hb;
            mxb[j] = fmaxf(mxb[j], hb);
        }
    }
    float sa = 0.f, sb = 0.f;
#pragma unroll
    for (int j = 0; j < OT; ++j) {
        bf16 va = __float2bfloat16(mxa[j]);
        bf16 vb = __float2bfloat16(mxb[j]);
        featT[iA * FT + c0f + lane + 64 * j] = va;
        featT[(iA + 1) * FT + c0f + lane + 64 * j] = vb;
        if (xxout) {
            float pa = b2f(va); sa = fmaf(pa, pa, sa);
            float pb = b2f(vb); sb = fmaf(pb, pb, sb);
        }
    }
    if (xxout) {
#pragma unroll
        for (int off = 32; off >= 1; off >>= 1) {
            sa += __shfl_xor(sa, off);
            sb += __shfl_xor(sb, off);
        }
        if (lane == 0) { xxout[iA] = sa; xxout[iA + 1] = sb; }
    }
}

// ---------------------------------------------------------------------------
// EdgeConv (VALU): fallback path.
template<typename T, int C, int COUT, bool WF>
__global__ __launch_bounds__(256) void k_edgeconv(const T* __restrict__ x, int bstride,
                           const int* __restrict__ idx,
                           const float* __restrict__ Wt,
                           const float* __restrict__ gam,
                           const float* __restrict__ bet,
                           bf16* __restrict__ out, int ostride,
                           bf16* __restrict__ featT, int c0f,
                           float* __restrict__ xxout) {
    const int PT = 4;
    const int OT = COUT / 64;
    const int CP = (C + 3) & ~3;
    __shared__ float sh[PT][KNN + 1][CP];

    int ib = blockIdx.x;
    int b  = ib / (N_PTS / PT);
    int n0 = (ib % (N_PTS / PT)) * PT;
    const T* xb = x + (size_t)b * bstride;

    const int TOT = PT * (KNN + 1) * C;
    for (int t = threadIdx.x; t < TOT; t += 256) {
        int pt = t / ((KNN + 1) * C);
        int r  = t % ((KNN + 1) * C);
        int row = r / C, c = r % C;
        int n = n0 + pt;
        int m = (row == 0) ? n
                           : (idx[((size_t)b * N_PTS + n) * KNN + (row - 1)] & (N_PTS - 1));
        sh[pt][row][c] = ldf(&xb[(size_t)c * N_PTS + m]);
    }
    __syncthreads();

    int w = threadIdx.x >> 6, lane = threadIdx.x & 63;
    int n = n0 + w;

    constexpr int KT = (OT >= 4) ? 10 : 20;
    constexpr int NPASS = KNN / KT;

    float base[OT];
    float mx[OT];
#pragma unroll
    for (int j = 0; j < OT; ++j) { base[j] = 0.f; mx[j] = -FLT_MAX; }

    const float inv = rsqrtf(1.0f + 1e-5f);

#pragma unroll
    for (int pass = 0; pass < NPASS; ++pass) {
        float acc[OT][KT];
#pragma unroll
        for (int j = 0; j < OT; ++j)
#pragma unroll
            for (int k = 0; k < KT; ++k) acc[j][k] = 0.f;

        for (int c = 0; c < C; ++c) {
            float xq = sh[w][0][c];
            float w2v[OT];
#pragma unroll
            for (int j = 0; j < OT; ++j)
                w2v[j] = Wt[(size_t)(C + c) * COUT + lane + 64 * j];
            if (pass == 0) {
#pragma unroll
                for (int j = 0; j < OT; ++j) {
                    float w1v = Wt[(size_t)c * COUT + lane + 64 * j];
                    base[j] = fmaf(w1v - w2v[j], xq, base[j]);
                }
            }
#pragma unroll
            for (int k = 0; k < KT; ++k) {
                float nv = sh[w][1 + pass * KT + k][c];
#pragma unroll
                for (int j = 0; j < OT; ++j) acc[j][k] = fmaf(w2v[j], nv, acc[j][k]);
            }
        }

#pragma unroll
        for (int j = 0; j < OT; ++j) {
            int o = lane + 64 * j;
            float scale = gam[o] * inv, bias = bet[o];
#pragma unroll
            for (int k = 0; k < KT; ++k) {
                float h = (base[j] + acc[j][k]) * scale + bias;
                h = h > 0.f ? h : LRELU_S * h;
                mx[j] = fmaxf(mx[j], h);
            }
        }
    }

    float s = 0.f;
#pragma unroll
    for (int j = 0; j < OT; ++j) {
        int o = lane + 64 * j;
        bf16 bv = __float2bfloat16(mx[j]);
        if (!WF) out[(size_t)b * ostride + (size_t)o * N_PTS + n] = bv;
        if (WF) {
            featT[((size_t)b * N_PTS + n) * FT + c0f + o] = bv;
            float q = b2f(bv);
            s = fmaf(q, q, s);
        }
    }
    if (WF && xxout) {
#pragma unroll
        for (int off = 32; off >= 1; off >>= 1) s += __shfl_xor(s, off);
        if (lane == 0) xxout[(size_t)b * N_PTS + n] = s;
    }
}

// ---------------------------------------------------------------------------
// conv5 via MFMA. Block: 64o x 128n, 4 waves (wave owns 32 n-rows), NPOOL=16
// n-chunks -> 1024 blocks, ~34 KB LDS -> 4 blocks/CU. When inputs are bf16
// (isb), the lo-correction MFMAs and Al staging are skipped (exact).
__global__ __launch_bounds__(256) void k_conv5mfma(
        const bf16* __restrict__ featT, const bf16* __restrict__ w5sp,
        const float* __restrict__ g5, const float* __restrict__ b5,
        float* __restrict__ fmxp, float* __restrict__ fsmp,
        const int* __restrict__ flag) {
    __shared__ __align__(16) short Bt[128 * 64];   // 16 KB
    __shared__ __align__(16) short Ah[64 * 64];    //  8 KB
    __shared__ __align__(16) short Al[64 * 64];    //  8 KB
    __shared__ float rmx[4][64];
    __shared__ float rsm[4][64];

    const int isb = *flag;
    int ib = blockIdx.x;                 // B * 16 * 16
    int b  = ib / 256;
    int rem = ib % 256;
    int o0 = (rem >> 4) * 64;
    int nt = rem & 15;
    int tid = threadIdx.x;
    int w = tid >> 6, lane = tid & 63;
    int l15 = lane & 15, quad = lane >> 4;

    const bf16* Whi = w5sp;
    const bf16* Wlo = w5sp + 1024 * 512;
    const bf16* fb  = featT + (size_t)b * N_PTS * FT;
    const int nbase0 = nt * 128;

    floatx4 acc[4][2];
#pragma unroll
    for (int mi = 0; mi < 4; ++mi)
#pragma unroll
        for (int ni = 0; ni < 2; ++ni) acc[mi][ni] = (floatx4){0.f, 0.f, 0.f, 0.f};

    for (int ck = 0; ck < 512; ck += 64) {
        __syncthreads();
#pragma unroll
        for (int it = 0; it < 4; ++it) {                 // B: 128 rows x 64k
            int s = tid + it * 256;
            int row = s >> 3, seg = s & 7;
            int gseg = seg ^ (row & 7);
            gload16(fb + (size_t)(nbase0 + row) * FT + ck + gseg * 8,
                    &Bt[(s & ~63) * 8]);
        }
#pragma unroll
        for (int it = 0; it < 2; ++it) {                 // A hi(/lo): 64 rows x 64k
            int s = tid + it * 256;
            int row = s >> 3, seg = s & 7;
            int gseg = seg ^ (row & 7);
            gload16(Whi + (size_t)(o0 + row) * 512 + ck + gseg * 8, &Ah[(s & ~63) * 8]);
            if (!isb)
                gload16(Wlo + (size_t)(o0 + row) * 512 + ck + gseg * 8, &Al[(s & ~63) * 8]);
        }
        __syncthreads();
#pragma unroll
        for (int kk = 0; kk < 64; kk += 32) {
            int ks = kk >> 3;
            short8v bfr[2], ah[4], al[4];
#pragma unroll
            for (int ni = 0; ni < 2; ++ni) {
                int row = w * 32 + ni * 16 + l15;
                int seg = (ks + quad) ^ (row & 7);
                bfr[ni] = *(const short8v*)&Bt[row * 64 + seg * 8];
            }
#pragma unroll
            for (int mi = 0; mi < 4; ++mi) {
                int row = mi * 16 + l15;
                int seg = (ks + quad) ^ (row & 7);
                ah[mi] = *(const short8v*)&Ah[row * 64 + seg * 8];
                if (!isb) al[mi] = *(const short8v*)&Al[row * 64 + seg * 8];
            }
#pragma unroll
            for (int mi = 0; mi < 4; ++mi)
#pragma unroll
                for (int ni = 0; ni < 2; ++ni) {
                    acc[mi][ni] = __builtin_amdgcn_mfma_f32_16x16x32_bf16(ah[mi], bfr[ni], acc[mi][ni], 0, 0, 0);
                    if (!isb)
                        acc[mi][ni] = __builtin_amdgcn_mfma_f32_16x16x32_bf16(al[mi], bfr[ni], acc[mi][ni], 0, 0, 0);
                }
        }
    }

    const float inv = rsqrtf(1.0f + 1e-5f);
#pragma unroll
    for (int mi = 0; mi < 4; ++mi) {
#pragma unroll
        for (int r = 0; r < 4; ++r) {
            int o = o0 + mi * 16 + quad * 4 + r;
            float scale = g5[o] * inv, bias = b5[o];
            float mx = -FLT_MAX, sm = 0.f;
#pragma unroll
            for (int ni = 0; ni < 2; ++ni) {
                float h = acc[mi][ni][r] * scale + bias;
                h = h > 0.f ? h : LRELU_S * h;
                mx = fmaxf(mx, h);
                sm += h;
            }
#pragma unroll
            for (int off = 1; off <= 8; off <<= 1) {
                mx = fmaxf(mx, __shfl_xor(mx, off));
                sm += __shfl_xor(sm, off);
            }
            if (l15 == 0) {
                rmx[w][mi * 16 + quad * 4 + r] = mx;
                rsm[w][mi * 16 + quad * 4 + r] = sm;
            }
        }
    }
    __syncthreads();
    if (tid < 64) {
        float mx = -FLT_MAX, sm = 0.f;
#pragma unroll
        for (int ww = 0; ww < 4; ++ww) { mx = fmaxf(mx, rmx[ww][tid]); sm += rsm[ww][tid]; }
        fmxp[((size_t)b * 1024 + o0 + tid) * NPOOL + nt] = mx;
        fsmp[((size_t)b * 1024 + o0 + tid) * NPOOL + nt] = sm;
    }
}

// ---------------------------------------------------------------------------
// Pool partial reduce -> fvec (B, 2048) = [max(1024) | mean(1024)].
__global__ void k_pool(const float* __restrict__ fmxp, const float* __restrict__ fsmp,
                       float* __restrict__ fvec) {
    int i = blockIdx.x * blockDim.x + threadIdx.x;
    if (i >= B_SZ * 1024) return;
    int b = i >> 10, o = i & 1023;
    float mx = -FLT_MAX, sm = 0.f;
    for (int ch = 0; ch < NPOOL; ++ch) {
        mx = fmaxf(mx, fmxp[(size_t)i * NPOOL + ch]);
        sm += fsmp[(size_t)i * NPOOL + ch];
    }
    fvec[(size_t)b * 2048 + o] = mx;
    fvec[(size_t)b * 2048 + 1024 + o] = sm * (1.0f / N_PTS);
}

// ---------------------------------------------------------------------------
// fc1 (raw-dtype weights): block per (b,o).
__global__ __launch_bounds__(256) void k_fc1(const float* __restrict__ fvec,
        const void* __restrict__ fw1, const void* __restrict__ fb1,
        const void* __restrict__ g6,  const void* __restrict__ b6,
        const int* __restrict__ flag, float* __restrict__ tbuf) {
    __shared__ float red[4];
    int ib = blockIdx.x;
    int b = ib >> 9, o = ib & 511;
    const float* fv = fvec + (size_t)b * 2048;
    int tid = threadIdx.x;
    const int isb = *flag;
    float s = 0.f;
    if (isb) {
        const bf16* wr = (const bf16*)fw1 + (size_t)o * 2048;
        for (int j = tid; j < 2048; j += 256) s = fmaf(b2f(wr[j]), fv[j], s);
    } else {
        const float* wr = (const float*)fw1 + (size_t)o * 2048;
        for (int j = tid; j < 2048; j += 256) s = fmaf(wr[j], fv[j], s);
    }
#pragma unroll
    for (int off = 32; off >= 1; off >>= 1) s += __shfl_xor(s, off);
    if ((tid & 63) == 0) red[tid >> 6] = s;
    __syncthreads();
    if (tid == 0) {
        float fb = isb ? b2f(((const bf16*)fb1)[o]) : ((const float*)fb1)[o];
        float gg = isb ? b2f(((const bf16*)g6)[o])  : ((const float*)g6)[o];
        float bb = isb ? b2f(((const bf16*)b6)[o])  : ((const float*)b6)[o];
        float acc = fb + red[0] + red[1] + red[2] + red[3];
        float h = acc * gg * rsqrtf(1.0f + 1e-5f) + bb;
        tbuf[(size_t)b * 512 + o] = h > 0.f ? h : LRELU_S * h;
    }
}

// ---------------------------------------------------------------------------
// fc2 (raw-dtype weights): block per (b,o).
__global__ __launch_bounds__(256) void k_fc2(const float* __restrict__ tbuf,
        const void* __restrict__ fw2, const void* __restrict__ fb2,
        const void* __restrict__ g7,  const void* __restrict__ b7,
        const int* __restrict__ flag, void* __restrict__ out) {
    __shared__ float red[4];
    int ib = blockIdx.x;
    int b = ib >> 8, o = ib & 255;
    const float* tv = tbuf + (size_t)b * 512;
    int tid = threadIdx.x;
    const int isb = *flag;
    float s;
    if (isb) {
        const bf16* wr = (const bf16*)fw2 + (size_t)o * 512;
        s = fmaf(b2f(wr[tid]), tv[tid], b2f(wr[tid + 256]) * tv[tid + 256]);
    } else {
        const float* wr = (const float*)fw2 + (size_t)o * 512;
        s = fmaf(wr[tid], tv[tid], wr[tid + 256] * tv[tid + 256]);
    }
#pragma unroll
    for (int off = 32; off >= 1; off >>= 1) s += __shfl_xor(s, off);
    if ((tid & 63) == 0) red[tid >> 6] = s;
    __syncthreads();
    if (tid == 0) {
        float fb = isb ? b2f(((const bf16*)fb2)[o]) : ((const float*)fb2)[o];
        float gg = isb ? b2f(((const bf16*)g7)[o])  : ((const float*)g7)[o];
        float bb = isb ? b2f(((const bf16*)b7)[o])  : ((const float*)b7)[o];
        float acc = fb + red[0] + red[1] + red[2] + red[3];
        float h = acc * gg * rsqrtf(1.0f + 1e-5f) + bb;
        if (isb) ((bf16*)out)[(size_t)b * 256 + o] = __float2bfloat16(h);
        else     ((float*)out)[(size_t)b * 256 + o] = h;
    }
}

// ---------------------------------------------------------------------------
// Fallback conv5 (VALU) + head, used when ws too small for the gram path.
#define NCH 2
__global__ __launch_bounds__(256) void k_conv5pool(const bf16* __restrict__ feat,
                            const float* __restrict__ w5,
                            const float* __restrict__ g5,
                            const float* __restrict__ b5,
                            float* __restrict__ fmxp, float* __restrict__ fsmp) {
    const int OT = 8;
    const int NT = 4;
    const int CHN = N_PTS / NCH;
    __shared__ float wl[OT][512];
    __shared__ float rmx[4][OT];
    __shared__ float rsm[4][OT];

    int ib = blockIdx.x;
    int ch = ib % NCH;
    int ot = (ib / NCH) % (1024 / OT);
    int b  = ib / (NCH * (1024 / OT));
    int o0 = ot * OT;
    const bf16* fb = feat + (size_t)b * 512 * N_PTS;

    for (int t = threadIdx.x; t < OT * 512; t += 256) {
        int o = t >> 9, c = t & 511;
        wl[o][c] = w5[(size_t)(o0 + o) * 512 + c];
    }
    __syncthreads();

    const int n0 = ch * CHN + threadIdx.x * NT;

    float acc[OT][NT];
#pragma unroll
    for (int o = 0; o < OT; ++o)
#pragma unroll
        for (int t = 0; t < NT; ++t) acc[o][t] = 0.f;

    for (int c = 0; c < 512; c += 4) {
        float fv[4][NT];
#pragma unroll
        for (int j = 0; j < 4; ++j) {
            uint2 u = *(const uint2*)(fb + (size_t)(c + j) * N_PTS + n0);
            fv[j][0] = __uint_as_float(u.x << 16);
            fv[j][1] = __uint_as_float(u.x & 0xFFFF0000u);
            fv[j][2] = __uint_as_float(u.y << 16);
            fv[j][3] = __uint_as_float(u.y & 0xFFFF0000u);
        }
#pragma unroll
        for (int o = 0; o < OT; ++o) {
            float4 wv = *(const float4*)&wl[o][c];
#pragma unroll
            for (int t = 0; t < NT; ++t) {
                acc[o][t] = fmaf(wv.x, fv[0][t], acc[o][t]);
                acc[o][t] = fmaf(wv.y, fv[1][t], acc[o][t]);
                acc[o][t] = fmaf(wv.z, fv[2][t], acc[o][t]);
                acc[o][t] = fmaf(wv.w, fv[3][t], acc[o][t]);
            }
        }
    }

    const float inv = rsqrtf(1.0f + 1e-5f);
    int w = threadIdx.x >> 6, lane = threadIdx.x & 63;
#pragma unroll
    for (int o = 0; o < OT; ++o) {
        float scale = g5[o0 + o] * inv, bias = b5[o0 + o];
        float mx = -FLT_MAX, sm = 0.f;
#pragma unroll
        for (int t = 0; t < NT; ++t) {
            float h = acc[o][t] * scale + bias;
            h = h > 0.f ? h : LRELU_S * h;
            mx = fmaxf(mx, h);
            sm += h;
        }
#pragma unroll
        for (int off = 32; off >= 1; off >>= 1) {
            mx = fmaxf(mx, __shfl_xor(mx, off));
            sm += __shfl_xor(sm, off);
        }
        if (lane == 0) { rmx[w][o] = mx; rsm[w][o] = sm; }
    }
    __syncthreads();
    if (threadIdx.x < OT) {
        int o = threadIdx.x;
        float mx = -FLT_MAX, sm = 0.f;
#pragma unroll
        for (int ww = 0; ww < 4; ++ww) { mx = fmaxf(mx, rmx[ww][o]); sm += rsm[ww][o]; }
        fmxp[((size_t)b * 1024 + o0 + o) * NCH + ch] = mx;
        fsmp[((size_t)b * 1024 + o0 + o) * NCH + ch] = sm;
    }
}

__global__ void k_head(const float* __restrict__ fmxp, const float* __restrict__ fsmp,
                       const float* __restrict__ fw1, const float* __restrict__ fb1,
                       const float* __restrict__ g6,  const float* __restrict__ b6,
                       const float* __restrict__ fw2, const float* __restrict__ fb2,
                       const float* __restrict__ g7,  const float* __restrict__ b7,
                       const int* __restrict__ flag, void* __restrict__ out) {
    __shared__ float f[2048];
    __shared__ float t[512];
    int b = blockIdx.x;
    for (int i = threadIdx.x; i < 1024; i += 256) {
        float mx = -FLT_MAX, sm = 0.f;
        for (int ch = 0; ch < NCH; ++ch) {
            mx = fmaxf(mx, fmxp[((size_t)b * 1024 + i) * NCH + ch]);
            sm += fsmp[((size_t)b * 1024 + i) * NCH + ch];
        }
        f[i]        = mx;
        f[1024 + i] = sm * (1.0f / N_PTS);
    }
    __syncthreads();
    const float inv = rsqrtf(1.0f + 1e-5f);
    for (int o = threadIdx.x; o < 512; o += 256) {
        const float* wr = fw1 + (size_t)o * 2048;
        float acc = fb1[o];
        for (int j = 0; j < 2048; ++j) acc += wr[j] * f[j];
        float h = acc * g6[o] * inv + b6[o];
        t[o] = h > 0.f ? h : LRELU_S * h;
    }
    __syncthreads();
    {
        int o = threadIdx.x;
        const float* wr = fw2 + (size_t)o * 512;
        float acc = fb2[o];
        for (int j = 0; j < 512; ++j) acc += wr[j] * t[j];
        float h = acc * g7[o] * inv + b7[o];
        if (*flag) ((bf16*)out)[(size_t)b * 256 + o] = __float2bfloat16(h);
        else       ((float*)out)[(size_t)b * 256 + o] = h;
    }
}

// ---------------------------------------------------------------------------
extern "C" void kernel_launch(void* const* d_in, const int* in_sizes, int n_in,
                              void* d_out, int out_size, void* d_ws, size_t ws_size,
                              hipStream_t stream) {
    static const int wsz[23] = {
        384, 64, 64,   8192, 64, 64,   16384, 128, 128,   65536, 256, 256,
        524288, 1024, 1024,   1048576, 512,   512, 512,   131072, 256,   256, 256
    };
    static const int trows[23] = {64,0,0, 64,0,0, 128,0,0, 256,0,0, 0,0,0, 0,0, 0,0, 0,0, 0,0};
    static const int tcols[23] = { 6,0,0,128,0,0, 128,0,0, 256,0,0, 0,0,0, 0,0, 0,0, 0,0, 0,0};

    WPack wp;
    int total = 0;
    for (int i = 0; i < 23; ++i) {
        wp.src[i] = d_in[i + 1]; wp.off[i] = total; total += wsz[i];
        wp.rows[i] = trows[i]; wp.cols[i] = tcols[i];
    }
    wp.off[23] = total;

    const size_t flag_bytes = 16;
    const size_t x0_bytes   = (size_t)B_SZ * 3 * N_PTS * 4;
    const size_t feat_bytes = (size_t)B_SZ * 512 * N_PTS * 2;
    const size_t idx_bytes  = (size_t)B_SZ * N_PTS * KNN * 4;
    const size_t pool_bytes = (size_t)B_SZ * 1024 * 4 * 2;
    const size_t wf_bytes   = (size_t)total * 4;
    const size_t base_need  = flag_bytes + x0_bytes + feat_bytes + idx_bytes + pool_bytes + wf_bytes;

    const size_t featT_bytes = (size_t)B_SZ * N_PTS * FT * 2;           //  8 MB
    const size_t xx_bytes    = (size_t)B_SZ * N_PTS * 4;
    const size_t wsp2_elems  = 4 * 64 * 64;
    const size_t wsp3_elems  = 4 * 128 * 64;
    const size_t wsp4_elems  = 4 * 256 * 128;
    const size_t w5sp_elems  = 2 * 1024 * 512;
    const size_t wsp_bytes   = (wsp2_elems + wsp3_elems + wsp4_elems + w5sp_elems) * 2;
    const size_t Yh_bytes    = (size_t)B_SZ * N_PTS * 512 * 2;          //  8 MB (max M2)
    const size_t S_bytes     = (size_t)B_SZ * N_PTS * N_PTS * 4;        // 64 MB fp32 gram
    const size_t full_need   = base_need + featT_bytes + 2 * xx_bytes + wsp_bytes
                             + Yh_bytes + S_bytes;

    if (ws_size < base_need) return;   // graceful fail
    const bool use_gram = (ws_size >= full_need);

    char* w = (char*)d_ws;
    int*   flag = (int*)w;              w += flag_bytes;
    float* x0   = (float*)w;            w += x0_bytes;
    bf16*  feat = (bf16*)w;             w += feat_bytes;
    int*   idx  = (int*)w;              w += idx_bytes;
    w += pool_bytes;
    float* wf   = (float*)w;            w += wf_bytes;
    bf16*  featT = (bf16*)w;            w += featT_bytes;
    float* xxA   = (float*)w;           w += xx_bytes;
    float* xxB   = (float*)w;           w += xx_bytes;
    bf16*  wsp2  = (bf16*)w;            w += wsp2_elems * 2;
    bf16*  wsp3  = (bf16*)w;            w += wsp3_elems * 2;
    bf16*  wsp4  = (bf16*)w;            w += wsp4_elems * 2;
    bf16*  w5sp  = (bf16*)w;            w += w5sp_elems * 2;
    bf16*  Yh    = (bf16*)w;            w += Yh_bytes;
    float* S     = (float*)w;           // gram scores (fp32)

    // overlays in the idx region (idx unused in gram path):
    // fmxp+fsmp (512K) + fvec (32K) + tbuf (8K) <= idx_bytes (640K)
    float* fmxp = (float*)idx;                               // B*1024*NPOOL
    float* fsmp = fmxp + (size_t)B_SZ * 1024 * NPOOL;        // B*1024*NPOOL
    float* fvec = fsmp + (size_t)B_SZ * 1024 * NPOOL;        // B*2048
    float* tbuf = fvec + (size_t)B_SZ * 2048;                // B*512

    const int FBS = 512 * N_PTS;

    const float* w1t = wf + wp.off[0],  *g1 = wf + wp.off[1],  *b1 = wf + wp.off[2];
    const float* w2t = wf + wp.off[3],  *g2 = wf + wp.off[4],  *b2 = wf + wp.off[5];
    const float* w3t = wf + wp.off[6],  *g3 = wf + wp.off[7],  *b3 = wf + wp.off[8];
    const float* w4t = wf + wp.off[9],  *g4 = wf + wp.off[10], *b4 = wf + wp.off[11];
    const float* w5  = wf + wp.off[12], *g5 = wf + wp.off[13], *b5 = wf + wp.off[14];
    const float* fw1 = wf + wp.off[15], *fb1 = wf + wp.off[16];
    const float* g6  = wf + wp.off[17], *b6 = wf + wp.off[18];
    const float* fw2 = wf + wp.off[19], *fb2 = wf + wp.off[20];
    const float* g7  = wf + wp.off[21], *b7 = wf + wp.off[22];

    const int GK = B_SZ * N_PTS / 4;    // 2048 blocks
    const int G8 = B_SZ * N_PTS / 8;    // 1024 blocks (2 queries/wave kernels)
    const int NG = B_SZ * 256;          // gram blocks in k_gx

    if (use_gram) {
        const int rlimit = wp.off[15];
        const int nbrep = (rlimit + 255) / 256;
        const int prep_grid = nbrep + 16 + 32 + 128 + 2048 + 32;
        k_prep<<<prep_grid, 256, 0, stream>>>(wp, wf, rlimit,
                                              d_in[4], wsp2, d_in[7], wsp3,
                                              d_in[10], wsp4, d_in[13], w5sp,
                                              d_in[0], x0, flag);

        // layer 1: fused kNN + EdgeConv (writes featT[0:64) + xxA)
        k_knn3ec<<<G8, 256, 0, stream>>>(x0, w1t, g1, b1, featT, xxA);
        // layer 2
        k_gx<64, 64><<<NG + 64, 256, 0, stream>>>(featT, 0, wsp2, S, Yh, flag);
        k_selgmax<64><<<G8, 256, 0, stream>>>(S, xxA, Yh, g2, b2, featT, 64, xxB);
        // layer 3
        k_gx<64, 128><<<NG + 128, 256, 0, stream>>>(featT, 64, wsp3, S, Yh, flag);
        k_selgmax<128><<<G8, 256, 0, stream>>>(S, xxB, Yh, g3, b3, featT, 128, xxA);
        // layer 4 (writes featT channels [256,512) for conv5)
        k_gx<128, 256><<<NG + 256, 256, 0, stream>>>(featT, 128, wsp4, S, Yh, flag);
        k_selgmax<256><<<G8, 256, 0, stream>>>(S, xxA, Yh, g4, b4, featT, 256, nullptr);

        // conv5 MFMA + pooling partials, then head GEMVs (raw fc weights)
        k_conv5mfma<<<B_SZ * 256, 256, 0, stream>>>(featT, w5sp, g5, b5, fmxp, fsmp, flag);
        k_pool<<<(B_SZ * 1024 + 255) / 256, 256, 0, stream>>>(fmxp, fsmp, fvec);
        k_fc1<<<B_SZ * 512, 256, 0, stream>>>(fvec, d_in[16], d_in[17], d_in[18], d_in[19],
                                              flag, tbuf);
        k_fc2<<<B_SZ * 256, 256, 0, stream>>>(tbuf, d_in[20], d_in[21], d_in[22], d_in[23],
                                              flag, d_out);
    } else {
        k_sniff<<<1, 64, 0, stream>>>((const unsigned short*)d_in[0], flag);
        k_repack<<<(total + 255) / 256, 256, 0, stream>>>(wp, flag, wf, total);
        k_transpose<<<(B_SZ * N_PTS + 255) / 256, 256, 0, stream>>>(d_in[0], flag, x0);

        k_knn<float, 3><<<GK, 256, 0, stream>>>(x0, 3 * N_PTS, idx);
        k_edgeconv<float, 3, 64, false><<<GK, 256, 0, stream>>>(
            x0, 3 * N_PTS, idx, w1t, g1, b1, feat + 0 * N_PTS, FBS, nullptr, 0, nullptr);
        k_knn<bf16, 64><<<GK, 256, 0, stream>>>(feat + 0 * N_PTS, FBS, idx);
        k_edgeconv<bf16, 64, 64, false><<<GK, 256, 0, stream>>>(
            feat + 0 * N_PTS, FBS, idx, w2t, g2, b2, feat + 64 * N_PTS, FBS, nullptr, 0, nullptr);
        k_knn<bf16, 64><<<GK, 256, 0, stream>>>(feat + 64 * N_PTS, FBS, idx);
        k_edgeconv<bf16, 64, 128, false><<<GK, 256, 0, stream>>>(
            feat + 64 * N_PTS, FBS, idx, w3t, g3, b3, feat + 128 * N_PTS, FBS, nullptr, 0, nullptr);
        k_knn<bf16, 128><<<GK, 256, 0, stream>>>(feat + 128 * N_PTS, FBS, idx);
        k_edgeconv<bf16, 128, 256, false><<<GK, 256, 0, stream>>>(
            feat + 128 * N_PTS, FBS, idx, w4t, g4, b4, feat + 256 * N_PTS, FBS, nullptr, 0, nullptr);

        k_conv5pool<<<B_SZ * (1024 / 8) * NCH, 256, 0, stream>>>(feat, w5, g5, b5, fmxp, fsmp);
        k_head<<<B_SZ, 256, 0, stream>>>(fmxp, fsmp, fw1, fb1, g6, b6, fw2, fb2, g7, b7,
                                         flag, d_out);
    }
}

// Round 10
// 332.301 us; speedup vs baseline: 1.0612x; 1.0612x over previous
//
#include <hip/hip_runtime.h>
#include <hip/hip_bf16.h>
#include <float.h>

#define N_PTS 2048
#define B_SZ  4
#define KNN   20
#define LRELU_S 0.2f
#define FT    512          // featT row stride (channels)
#define NPOOL 16           // conv5 n-chunk partials (128 rows each)

typedef __hip_bfloat16 bf16;
typedef __attribute__((ext_vector_type(8))) short short8v;   // 8 bf16 (4 VGPRs)
typedef __attribute__((ext_vector_type(4))) short short4v;   // 4 bf16
typedef __attribute__((ext_vector_type(4))) float floatx4;

__device__ __forceinline__ float b2f(const bf16 v) { return __bfloat162float(v); }
__device__ __forceinline__ float ldf(const float* p) { return *p; }
__device__ __forceinline__ float ldf(const bf16* p)  { return __bfloat162float(*p); }
__device__ __forceinline__ short8v ld8(const bf16* p) { return *(const short8v*)p; }
__device__ __forceinline__ unsigned umin(unsigned a, unsigned b) { return a < b ? a : b; }
__device__ __forceinline__ short bfbits(float f) {
    bf16 t = __float2bfloat16(f);
    return *reinterpret_cast<short*>(&t);
}
// fp16 <-> fp32 via _Float16 (RNE convert, single v_cvt instruction).
__device__ __forceinline__ unsigned short f2h(float f) {
    _Float16 h = (_Float16)f;
    return *reinterpret_cast<unsigned short*>(&h);
}
__device__ __forceinline__ float h2f(unsigned short u) {
    _Float16 h;
    *reinterpret_cast<unsigned short*>(&h) = u;
    return (float)h;
}

// Direct global->LDS DMA, 16 B per lane. LDS dest is wave-uniform base +
// lane*16 (linear); swizzling is achieved by pre-swizzling the GLOBAL source
// address (rule: both-sides-or-neither).
__device__ __forceinline__ void gload16(const void* g, void* l) {
    __builtin_amdgcn_global_load_lds(
        (const __attribute__((address_space(1))) void*)g,
        (__attribute__((address_space(3))) void*)l, 16, 0, 0);
}

// ---------------------------------------------------------------------------
// Dtype sniffer: bf16 (flag=1) vs fp32 (flag=0). Reads 256 B.
__device__ __forceinline__ int sniff_body(const unsigned short* pts_hw) {
    int sane = 0;
    for (int j = 0; j < 64; ++j) {
        unsigned short v = pts_hw[2 * j];
        int e = (v >> 7) & 0xFF;
        if (e >= 100 && e <= 140) ++sane;
    }
    return (sane >= 32) ? 1 : 0;
}

__global__ void k_sniff(const unsigned short* __restrict__ pts_hw, int* __restrict__ flag) {
    if (threadIdx.x != 0 || blockIdx.x != 0) return;
    *flag = sniff_body(pts_hw);
}

// ---------------------------------------------------------------------------
// Weight repack metadata.
struct WPack {
    const void* src[23];
    int off[24];
    int rows[23];
    int cols[23];
};

__device__ __forceinline__ void repack_body(const WPack& wp, int isb,
                                            float* __restrict__ dst, int i, int limit,
                                            int skip12) {
    if (i >= limit) return;
    int lo = 0, hi = 23;
    while (lo + 1 < hi) { int mid = (lo + hi) >> 1; if (i >= wp.off[mid]) lo = mid; else hi = mid; }
    if (skip12 && lo == 12) return;    // gram path reads w5 only via w5sp
    int j = i - wp.off[lo];
    float v = isb ? b2f(((const bf16*)wp.src[lo])[j]) : ((const float*)wp.src[lo])[j];
    int dj = j;
    int cols = wp.cols[lo];
    if (cols) dj = (j % cols) * wp.rows[lo] + (j / cols);
    dst[wp.off[lo] + dj] = v;
}

// Split EdgeConv weights into bf16 hi/lo pairs for MFMA:
// dst = [W2hi | W2lo | Wdhi | Wdlo], each (COUT, C) row-major, Wd = W1 - W2.
template<int C, int COUT>
__device__ __forceinline__ void wsplit_body(const void* __restrict__ W, int isb,
                                            bf16* __restrict__ dst, int i) {
    if (i >= COUT * C) return;
    int o = i / C, c = i % C;
    float w1 = isb ? b2f(((const bf16*)W)[(size_t)o * 2 * C + c])
                   : ((const float*)W)[(size_t)o * 2 * C + c];
    float w2 = isb ? b2f(((const bf16*)W)[(size_t)o * 2 * C + C + c])
                   : ((const float*)W)[(size_t)o * 2 * C + C + c];
    float wd = w1 - w2;
    bf16 h2 = __float2bfloat16(w2);
    bf16 hd = __float2bfloat16(wd);
    dst[i]                = h2;
    dst[COUT * C + i]     = __float2bfloat16(w2 - b2f(h2));
    dst[2 * COUT * C + i] = hd;
    dst[3 * COUT * C + i] = __float2bfloat16(wd - b2f(hd));
}

// Split conv5 weights (1024x512) into bf16 hi/lo: dst = [hi | lo].
// When inputs are bf16 the lo plane is identically zero and never read.
__device__ __forceinline__ void w5split_body(const void* __restrict__ W, int isb,
                                             bf16* __restrict__ dst, int i) {
    if (i >= 1024 * 512) return;
    float w = isb ? b2f(((const bf16*)W)[i]) : ((const float*)W)[i];
    bf16 h = __float2bfloat16(w);
    dst[i] = h;
    if (!isb) dst[1024 * 512 + i] = __float2bfloat16(w - b2f(h));
}

// points (B,N,3) -> x0 (B,3,N) fp32, dtype-dynamic.
__device__ __forceinline__ void transpose_body(const void* __restrict__ pts, int isb,
                                               float* __restrict__ x0, int i) {
    if (i >= B_SZ * N_PTS) return;
    int b = i / N_PTS, n = i % N_PTS;
    for (int c = 0; c < 3; ++c) {
        size_t s = ((size_t)b * N_PTS + n) * 3 + c;
        float v = isb ? b2f(((const bf16*)pts)[s]) : ((const float*)pts)[s];
        x0[((size_t)b * 3 + c) * N_PTS + n] = v;
    }
}

// Merged prep (gram path): self-sniff + repack + 3x wsplit + w5split +
// transpose in one launch, dispatched by blockIdx range.
__global__ void k_prep(WPack wp, float* __restrict__ wf, int rlimit,
                       const void* __restrict__ w2s, bf16* __restrict__ wsp2,
                       const void* __restrict__ w3s, bf16* __restrict__ wsp3,
                       const void* __restrict__ w4s, bf16* __restrict__ wsp4,
                       const void* __restrict__ w5s, bf16* __restrict__ w5sp,
                       const void* __restrict__ pts, float* __restrict__ x0,
                       int* __restrict__ flagout) {
    __shared__ int sfl;
    if (threadIdx.x == 0) {
        int f = sniff_body((const unsigned short*)pts);
        sfl = f;
        if (blockIdx.x == 0) *flagout = f;
    }
    __syncthreads();
    const int isb = sfl;
    const int nbrep = (rlimit + 255) >> 8;
    int ib = blockIdx.x, t = threadIdx.x;
    if (ib < nbrep) { repack_body(wp, isb, wf, ib * 256 + t, rlimit, 1); return; }
    ib -= nbrep;
    if (ib < 16)   { wsplit_body<64, 64>(w2s, isb, wsp2, ib * 256 + t); return; }
    ib -= 16;
    if (ib < 32)   { wsplit_body<64, 128>(w3s, isb, wsp3, ib * 256 + t); return; }
    ib -= 32;
    if (ib < 128)  { wsplit_body<128, 256>(w4s, isb, wsp4, ib * 256 + t); return; }
    ib -= 128;
    if (ib < 2048) { w5split_body(w5s, isb, w5sp, ib * 256 + t); return; }
    ib -= 2048;
    transpose_body(pts, isb, x0, ib * 256 + t);
}

// Standalone versions for the fallback path.
__global__ void k_repack(WPack wp, const int* __restrict__ flag, float* __restrict__ dst, int limit) {
    repack_body(wp, *flag, dst, blockIdx.x * blockDim.x + threadIdx.x, limit, 0);
}
__global__ void k_transpose(const void* __restrict__ pts, const int* __restrict__ flag,
                            float* __restrict__ x0) {
    transpose_body(pts, *flag, x0, blockIdx.x * blockDim.x + threadIdx.x);
}

// ---------------------------------------------------------------------------
// 32-candidate row loads (lane chunk), fp32 out.
__device__ __forceinline__ void load32(const float* row, int mbase, float* r) {
    const float4* p = (const float4*)(row + mbase);
#pragma unroll
    for (int i = 0; i < 8; ++i) {
        float4 f = p[i];
        r[4 * i + 0] = f.x; r[4 * i + 1] = f.y; r[4 * i + 2] = f.z; r[4 * i + 3] = f.w;
    }
}
__device__ __forceinline__ void load32(const bf16* row, int mbase, float* r) {
    const uint4* p = (const uint4*)(row + mbase);
#pragma unroll
    for (int i = 0; i < 4; ++i) {
        uint4 u = p[i];
        r[8 * i + 0] = __uint_as_float(u.x << 16);
        r[8 * i + 1] = __uint_as_float(u.x & 0xFFFF0000u);
        r[8 * i + 2] = __uint_as_float(u.y << 16);
        r[8 * i + 3] = __uint_as_float(u.y & 0xFFFF0000u);
        r[8 * i + 4] = __uint_as_float(u.z << 16);
        r[8 * i + 5] = __uint_as_float(u.z & 0xFFFF0000u);
        r[8 * i + 6] = __uint_as_float(u.w << 16);
        r[8 * i + 7] = __uint_as_float(u.w & 0xFFFF0000u);
    }
}

// ---------------------------------------------------------------------------
// Packed-key top-20 for two queries per wave, cached per-lane sorted top-2.
__device__ __forceinline__ void s2ins(unsigned k, unsigned& m1, unsigned& m2) {
    unsigned lo = umin(m1, k);
    unsigned hi = (m1 < k) ? k : m1;
    m1 = lo;
    m2 = umin(m2, hi);
}

__device__ __forceinline__ void select20x2(const unsigned* ka, const unsigned* kb,
                                           int* outA, int* outB, int lane) {
    const unsigned SENT = 0xFFFFFFFFu;
    unsigned a1 = SENT, a2 = SENT, b1 = SENT, b2 = SENT;
#pragma unroll
    for (int j = 0; j < 32; ++j) {
        s2ins(ka[j], a1, a2);
        s2ins(kb[j], b1, b2);
    }
#pragma unroll 1
    for (int k = 0; k < KNN; ++k) {
        unsigned va = a1, vb = b1;
#pragma unroll
        for (int off = 32; off >= 1; off >>= 1) {
            va = umin(va, (unsigned)__shfl_xor((int)va, off));
            vb = umin(vb, (unsigned)__shfl_xor((int)vb, off));
        }
        if (lane == 0) { outA[k] = (int)(va & 2047u); outB[k] = (int)(vb & 2047u); }
        if (a1 == va) { a1 = a2; a2 = SENT; }
        if (b1 == vb) { b1 = b2; b2 = SENT; }
        if (a1 == SENT) {
#pragma unroll
            for (int j = 0; j < 32; ++j) {
                unsigned t = (ka[j] > va) ? ka[j] : SENT;
                s2ins(t, a1, a2);
            }
        }
        if (b1 == SENT) {
#pragma unroll
            for (int j = 0; j < 32; ++j) {
                unsigned t = (kb[j] > vb) ? kb[j] : SENT;
                s2ins(t, b1, b2);
            }
        }
    }
}

// ---------------------------------------------------------------------------
// Fused layer-1: kNN (C=3, fp32, packed keys) + EdgeConv (C=3 -> 64) for the
// same 8 points. Select into LDS sidx, cooperative neighbor staging into LDS,
// then 2 points/wave, lane = channel.
__global__ __launch_bounds__(256) void k_knn3ec(const float* __restrict__ x0,
        const float* __restrict__ Wt, const float* __restrict__ gam,
        const float* __restrict__ bet, bf16* __restrict__ featT,
        float* __restrict__ xxout) {
    __shared__ float qf[8][3];
    __shared__ int sidx[8][KNN];
    __shared__ float sh[8][KNN][3];
    int ib = blockIdx.x;
    int b  = ib / (N_PTS / 8);
    int q0 = (ib % (N_PTS / 8)) * 8;
    const float* xb = x0 + (size_t)b * 3 * N_PTS;

    if (threadIdx.x < 24) {
        int q = threadIdx.x / 3, c = threadIdx.x % 3;
        qf[q][c] = xb[(size_t)c * N_PTS + q0 + q];
    }
    __syncthreads();

    int w = threadIdx.x >> 6, lane = threadIdx.x & 63;
    int mbase = lane * 32;

    float da[32], db[32];
#pragma unroll
    for (int j = 0; j < 32; ++j) { da[j] = 0.f; db[j] = 0.f; }
#pragma unroll
    for (int c = 0; c < 3; ++c) {
        float r[32];
        load32(xb + (size_t)c * N_PTS, mbase, r);
        float qac = qf[2 * w][c], qbc = qf[2 * w + 1][c];
#pragma unroll
        for (int j = 0; j < 32; ++j) {
            float ta = r[j] - qac; da[j] = fmaf(ta, ta, da[j]);
            float tb = r[j] - qbc; db[j] = fmaf(tb, tb, db[j]);
        }
    }
    unsigned ka[32], kb[32];
#pragma unroll
    for (int j = 0; j < 32; ++j) {
        ka[j] = (__float_as_uint(da[j]) & 0xFFFFF800u) | (unsigned)(mbase + j);
        kb[j] = (__float_as_uint(db[j]) & 0xFFFFF800u) | (unsigned)(mbase + j);
    }
    select20x2(ka, kb, &sidx[2 * w][0], &sidx[2 * w + 1][0], lane);
    __syncthreads();

    // ---- cooperative neighbor staging: 480 parallel loads (2/thread) ----
    for (int t = threadIdx.x; t < 8 * KNN * 3; t += 256) {
        int pt = t / (KNN * 3);
        int r  = t % (KNN * 3);
        int k = r / 3, c = r % 3;
        int m = sidx[pt][k] & (N_PTS - 1);
        sh[pt][k][c] = xb[(size_t)c * N_PTS + m];
    }
    __syncthreads();

    // ---- EdgeConv phase: points q0+2w, q0+2w+1; lane owns channel `lane` ----
    const float inv = rsqrtf(1.0f + 1e-5f);
    float scale = gam[lane] * inv, bias = bet[lane];
    float w1v[3], w2v[3];
#pragma unroll
    for (int c = 0; c < 3; ++c) {
        w1v[c] = Wt[(size_t)c * 64 + lane];
        w2v[c] = Wt[(size_t)(3 + c) * 64 + lane];
    }
#pragma unroll
    for (int p = 0; p < 2; ++p) {
        int pt = 2 * w + p;
        float base = 0.f;
#pragma unroll
        for (int c = 0; c < 3; ++c) base = fmaf(w1v[c] - w2v[c], qf[pt][c], base);
        float mx = -FLT_MAX;
#pragma unroll
        for (int k = 0; k < KNN; ++k) {
            float acc = 0.f;
#pragma unroll
            for (int c = 0; c < 3; ++c) acc = fmaf(w2v[c], sh[pt][k][c], acc);
            float h = (base + acc) * scale + bias;
            h = h > 0.f ? h : LRELU_S * h;
            mx = fmaxf(mx, h);
        }
        bf16 bv = __float2bfloat16(mx);
        size_t i = (size_t)b * N_PTS + q0 + pt;
        featT[i * FT + lane] = bv;
        float qv = b2f(bv);
        float s = qv * qv;
#pragma unroll
        for (int off = 32; off >= 1; off >>= 1) s += __shfl_xor(s, off);
        if (lane == 0) xxout[i] = s;
    }
}

// ---------------------------------------------------------------------------
// kNN (direct, fallback path): wave-per-query.
template<typename T, int C>
__global__ __launch_bounds__(256) void k_knn(const T* __restrict__ x, int bstride,
                                             int* __restrict__ idx) {
    __shared__ float qf[4][C];
    int ib = blockIdx.x;
    int b  = ib / (N_PTS / 4);
    int q0 = (ib % (N_PTS / 4)) * 4;
    const T* xb = x + (size_t)b * bstride;

    for (int t = threadIdx.x; t < 4 * C; t += 256) {
        int pt = t / C, c = t % C;
        qf[pt][c] = ldf(&xb[(size_t)c * N_PTS + (q0 + pt)]);
    }
    __syncthreads();

    int w = threadIdx.x >> 6, lane = threadIdx.x & 63;
    int q = q0 + w;
    int mbase = lane * 32;

    float v[32];
#pragma unroll
    for (int j = 0; j < 32; ++j) v[j] = 0.f;

    for (int c = 0; c < C; ++c) {
        float qc = qf[w][c];
        float r[32];
        load32(xb + (size_t)c * N_PTS, mbase, r);
#pragma unroll
        for (int j = 0; j < 32; ++j) { float t = r[j] - qc; v[j] = fmaf(t, t, v[j]); }
    }

    for (int k = 0; k < KNN; ++k) {
        float bv = FLT_MAX; int bi = 0x7FFFFFFF;
#pragma unroll
        for (int j = 0; j < 32; ++j)
            if (v[j] < bv) { bv = v[j]; bi = mbase + j; }
#pragma unroll
        for (int off = 32; off >= 1; off >>= 1) {
            float ov = __shfl_xor(bv, off);
            int   oi = __shfl_xor(bi, off);
            if (ov < bv || (ov == bv && oi < bi)) { bv = ov; bi = oi; }
        }
        if (lane == 0) idx[((size_t)b * N_PTS + q) * KNN + k] = bi;
        int wl = bi >> 5, wj = bi & 31;
        if (lane == wl) {
#pragma unroll
            for (int j = 0; j < 32; ++j) if (j == wj) v[j] = FLT_MAX;
        }
    }
}

// ---------------------------------------------------------------------------
// Gram body via MFMA, with fused distance epilogue: instead of storing the
// raw gram value, compute dist = xx[n] - 2*G + xx[m] in fp32 (identical fmaf
// order to the old selgmax), clamp >=0, and store as fp16. fp16 keeps 11
// significant bits (the key packing already truncated to 12) and the fp32
// subtraction avoids the catastrophic cancellation that sank bf16-G.
template<int C>
__device__ __forceinline__ void gram_body(const bf16* __restrict__ featT, int c0,
                                          const float* __restrict__ xx,
                                          unsigned short* __restrict__ D,
                                          short* At, short* Bt, int ib) {
    const int KC = 64;
    int b  = ib >> 8;
    int t  = ib & 255;
    int n0 = (t >> 4) << 7;
    int m0 = (t & 15) << 7;

    int tid = threadIdx.x;
    int w = tid >> 6, lane = tid & 63;
    int rw = (w & 1) * 64, cw = (w >> 1) * 64;
    int lrow = lane & 15, quad = lane >> 4;

    floatx4 acc[4][4];
#pragma unroll
    for (int ri = 0; ri < 4; ++ri)
#pragma unroll
        for (int ci = 0; ci < 4; ++ci) acc[ri][ci] = (floatx4){0.f, 0.f, 0.f, 0.f};

    for (int ck = 0; ck < C; ck += KC) {
        __syncthreads();
#pragma unroll
        for (int it = 0; it < 4; ++it) {
            int s = tid + it * 256;
            int row = s >> 3, seg = s & 7;
            int gseg = seg ^ (row & 7);
            gload16(featT + ((size_t)(b * N_PTS + n0 + row) * FT) + c0 + ck + gseg * 8,
                    &At[(s & ~63) * 8]);
            gload16(featT + ((size_t)(b * N_PTS + m0 + row) * FT) + c0 + ck + gseg * 8,
                    &Bt[(s & ~63) * 8]);
        }
        __syncthreads();
#pragma unroll
        for (int kk = 0; kk < KC; kk += 32) {
            int ks = kk >> 3;
            short8v a[4], bb[4];
#pragma unroll
            for (int ri = 0; ri < 4; ++ri) {
                int row = rw + ri * 16 + lrow;
                int seg = (ks + quad) ^ (row & 7);
                a[ri] = *(const short8v*)&At[row * 64 + seg * 8];
            }
#pragma unroll
            for (int ci = 0; ci < 4; ++ci) {
                int row = cw + ci * 16 + lrow;
                int seg = (ks + quad) ^ (row & 7);
                bb[ci] = *(const short8v*)&Bt[row * 64 + seg * 8];
            }
#pragma unroll
            for (int ri = 0; ri < 4; ++ri)
#pragma unroll
                for (int ci = 0; ci < 4; ++ci)
                    acc[ri][ci] = __builtin_amdgcn_mfma_f32_16x16x32_bf16(a[ri], bb[ci], acc[ri][ci], 0, 0, 0);
        }
    }

    const float* xr = xx + (size_t)b * N_PTS;
    float xmv[4];
#pragma unroll
    for (int ci = 0; ci < 4; ++ci)
        xmv[ci] = xr[m0 + cw + ci * 16 + lrow];
    float xnv[4][4];
#pragma unroll
    for (int ri = 0; ri < 4; ++ri)
#pragma unroll
        for (int reg = 0; reg < 4; ++reg)
            xnv[ri][reg] = xr[n0 + rw + ri * 16 + quad * 4 + reg];

#pragma unroll
    for (int ri = 0; ri < 4; ++ri)
#pragma unroll
        for (int ci = 0; ci < 4; ++ci) {
            int n = n0 + rw + ri * 16 + quad * 4;
            int m = m0 + cw + ci * 16 + lrow;
            unsigned short* gp = D + ((size_t)b * N_PTS + n) * N_PTS + m;
#pragma unroll
            for (int reg = 0; reg < 4; ++reg) {
                float d = fmaf(-2.f, acc[ri][ci][reg], xmv[ci]) + xnv[ri][reg];
                d = fmaxf(d, 0.f);
                gp[(size_t)reg * N_PTS] = f2h(d);
            }
        }
}

// ---------------------------------------------------------------------------
// Xform body via MFMA, bf16 output. When inputs are bf16 (isb), the W2
// lo-correction is identically zero -> skip those MFMAs (exact).
template<int COUT, int C>
__device__ __forceinline__ void xform_body(const bf16* __restrict__ featT, int c0,
                                           const bf16* __restrict__ Wsp,
                                           bf16* __restrict__ Yh, int isb,
                                           short* Bt, int ib2) {
    const int M2 = 2 * COUT;
    const int KC = 64;
    int nt = ib2 & 63;
    int mt = ib2 >> 6;
    int tid = threadIdx.x;
    int w = tid >> 6, lane = tid & 63;
    int rw = (w & 1) * 64, cw = (w >> 1) * 64;
    int l15 = lane & 15, quad = lane >> 4;

    floatx4 acc[4][4];
#pragma unroll
    for (int ri = 0; ri < 4; ++ri)
#pragma unroll
        for (int ci = 0; ci < 4; ++ci) acc[ri][ci] = (floatx4){0.f, 0.f, 0.f, 0.f};

    for (int ck = 0; ck < C; ck += KC) {
        __syncthreads();
#pragma unroll
        for (int it = 0; it < 4; ++it) {
            int s = tid + it * 256;
            int row = s >> 3, seg = s & 7;
            int gseg = seg ^ (row & 7);
            gload16(featT + (size_t)(nt * 128 + row) * FT + c0 + ck + gseg * 8,
                    &Bt[(s & ~63) * 8]);
        }
        __syncthreads();
#pragma unroll
        for (int kk = 0; kk < KC; kk += 32) {
            int ks = kk >> 3;
            short8v bfr[4];
#pragma unroll
            for (int ci = 0; ci < 4; ++ci) {
                int row = cw + ci * 16 + l15;
                int seg = (ks + quad) ^ (row & 7);
                bfr[ci] = *(const short8v*)&Bt[row * 64 + seg * 8];
            }
#pragma unroll
            for (int ri = 0; ri < 4; ++ri) {
                int rbase = mt * 128 + rw + ri * 16;          // band-aligned, lane-uniform
                bool uselo = (!isb) || (rbase >= COUT);       // W2 lo==0 when bf16 input
                int mrow = rbase + l15;
                int base = (mrow < COUT) ? mrow : (mrow + COUT);
                const bf16* hi = Wsp + (size_t)base * C + ck + kk + quad * 8;
                short8v ah = ld8(hi);
                short8v al;
                if (uselo) al = ld8(hi + (size_t)COUT * C);
#pragma unroll
                for (int ci = 0; ci < 4; ++ci) {
                    acc[ri][ci] = __builtin_amdgcn_mfma_f32_16x16x32_bf16(ah, bfr[ci], acc[ri][ci], 0, 0, 0);
                    if (uselo)
                        acc[ri][ci] = __builtin_amdgcn_mfma_f32_16x16x32_bf16(al, bfr[ci], acc[ri][ci], 0, 0, 0);
                }
            }
        }
    }

#pragma unroll
    for (int ri = 0; ri < 4; ++ri)
#pragma unroll
        for (int ci = 0; ci < 4; ++ci) {
            int n = nt * 128 + cw + ci * 16 + l15;
            int m = mt * 128 + rw + ri * 16 + quad * 4;
            short4v o4;
            o4[0] = bfbits(acc[ri][ci][0]);
            o4[1] = bfbits(acc[ri][ci][1]);
            o4[2] = bfbits(acc[ri][ci][2]);
            o4[3] = bfbits(acc[ri][ci][3]);
            *(short4v*)(Yh + (size_t)n * M2 + m) = o4;
        }
}

// ---------------------------------------------------------------------------
// Merged gram + xform: first B_SZ*256 blocks do the gram tile, the trailing
// COUT blocks do the dense point transform (fills otherwise-idle CUs).
template<int C, int COUT>
__global__ __launch_bounds__(256) void k_gx(const bf16* __restrict__ featT, int c0,
        const bf16* __restrict__ Wsp, const float* __restrict__ xx,
        unsigned short* __restrict__ D, bf16* __restrict__ Yh,
        const int* __restrict__ flag) {
    __shared__ __align__(16) short lds[2 * 128 * 64];   // 32 KB
    int ib = blockIdx.x;
    if (ib < B_SZ * 256) {
        gram_body<C>(featT, c0, xx, D, lds, lds + 128 * 64, ib);
    } else {
        xform_body<COUT, C>(featT, c0, Wsp, Yh, *flag, lds, ib - B_SZ * 256);
    }
}

// ---------------------------------------------------------------------------
// Merged select + gather-max: block = 8 queries. Phase 1 builds top-20 keys
// straight from the precomputed fp16 distance rows (no xx loads, no fmaf);
// phase 2 does the gather-max epilogue (2 pts/wave) reading bf16 Y, writes
// featT and next-layer xx.
template<int COUT>
__global__ __launch_bounds__(256) void k_selgmax(const unsigned short* __restrict__ D,
        const bf16* __restrict__ Yh,
        const float* __restrict__ gam, const float* __restrict__ bet,
        bf16* __restrict__ featT, int c0f, float* __restrict__ xxout) {
    const int M2 = 2 * COUT;
    const int OT = COUT / 64;
    __shared__ int sidx[8][KNN];

    int ib = blockIdx.x;
    int b  = ib / (N_PTS / 8);
    int q0 = (ib % (N_PTS / 8)) * 8;
    int w = threadIdx.x >> 6, lane = threadIdx.x & 63;
    int qa = q0 + 2 * w;
    const unsigned short* gA = D + ((size_t)b * N_PTS + qa) * N_PTS;
    const unsigned short* gB = gA + N_PTS;

    unsigned ka[32], kb[32];
#pragma unroll
    for (int r = 0; r < 4; ++r) {
        int m0 = r * 512 + (lane << 3);
        uint4 ua = *(const uint4*)(gA + m0);
        uint4 ub = *(const uint4*)(gB + m0);
        unsigned uw[4] = {ua.x, ua.y, ua.z, ua.w};
        unsigned vw[4] = {ub.x, ub.y, ub.z, ub.w};
#pragma unroll
        for (int h = 0; h < 4; ++h) {
            float a0 = h2f((unsigned short)(uw[h] & 0xFFFFu));
            float a1 = h2f((unsigned short)(uw[h] >> 16));
            ka[8 * r + 2 * h]     = (__float_as_uint(a0) & 0xFFFFF800u) | (unsigned)(m0 + 2 * h);
            ka[8 * r + 2 * h + 1] = (__float_as_uint(a1) & 0xFFFFF800u) | (unsigned)(m0 + 2 * h + 1);
            float c0v = h2f((unsigned short)(vw[h] & 0xFFFFu));
            float c1v = h2f((unsigned short)(vw[h] >> 16));
            kb[8 * r + 2 * h]     = (__float_as_uint(c0v) & 0xFFFFF800u) | (unsigned)(m0 + 2 * h);
            kb[8 * r + 2 * h + 1] = (__float_as_uint(c1v) & 0xFFFFF800u) | (unsigned)(m0 + 2 * h + 1);
        }
    }
    select20x2(ka, kb, &sidx[2 * w][0], &sidx[2 * w + 1][0], lane);
    __syncthreads();

    // ---- gather-max for points qa, qa+1 ----
    size_t iA = (size_t)b * N_PTS + qa;
    const float inv = rsqrtf(1.0f + 1e-5f);
    float yda[OT], ydb[OT], scl[OT], bis[OT], mxa[OT], mxb[OT];
#pragma unroll
    for (int j = 0; j < OT; ++j) {
        int o = lane + 64 * j;
        yda[j] = b2f(Yh[iA * M2 + COUT + o]);
        ydb[j] = b2f(Yh[(iA + 1) * M2 + COUT + o]);
        scl[j] = gam[o] * inv;
        bis[j] = bet[o];
        mxa[j] = -FLT_MAX; mxb[j] = -FLT_MAX;
    }
    const bf16* Yb = Yh + (size_t)b * N_PTS * M2;
#pragma unroll
    for (int k = 0; k < KNN; ++k) {
        int m0 = sidx[2 * w][k] & (N_PTS - 1);
        int m1 = sidx[2 * w + 1][k] & (N_PTS - 1);
        const bf16* r0 = Yb + (size_t)m0 * M2;
        const bf16* r1 = Yb + (size_t)m1 * M2;
#pragma unroll
        for (int j = 0; j < OT; ++j) {
            int o = lane + 64 * j;
            float ha = (yda[j] + b2f(r0[o])) * scl[j] + bis[j];
            ha = ha > 0.f ? ha : LRELU_S * ha;
            mxa[j] = fmaxf(mxa[j], ha);
            float hb = (ydb[j] + b2f(r1[o])) * scl[j] + bis[j];
            hb = hb > 0.f ? hb : LRELU_S * hb;
            mxb[j] = fmaxf(mxb[j], hb);
        }
    }
    float sa = 0.f, sb = 0.f;
#pragma unroll
    for (int j = 0; j < OT; ++j) {
        bf16 va = __float2bfloat16(mxa[j]);
        bf16 vb = __float2bfloat16(mxb[j]);
        featT[iA * FT + c0f + lane + 64 * j] = va;
        featT[(iA + 1) * FT + c0f + lane + 64 * j] = vb;
        if (xxout) {
            float pa = b2f(va); sa = fmaf(pa, pa, sa);
            float pb = b2f(vb); sb = fmaf(pb, pb, sb);
        }
    }
    if (xxout) {
#pragma unroll
        for (int off = 32; off >= 1; off >>= 1) {
            sa += __shfl_xor(sa, off);
            sb += __shfl_xor(sb, off);
        }
        if (lane == 0) { xxout[iA] = sa; xxout[iA + 1] = sb; }
    }
}

// ---------------------------------------------------------------------------
// EdgeConv (VALU): fallback path.
template<typename T, int C, int COUT, bool WF>
__global__ __launch_bounds__(256) void k_edgeconv(const T* __restrict__ x, int bstride,
                           const int* __restrict__ idx,
                           const float* __restrict__ Wt,
                           const float* __restrict__ gam,
                           const float* __restrict__ bet,
                           bf16* __restrict__ out, int ostride,
                           bf16* __restrict__ featT, int c0f,
                           float* __restrict__ xxout) {
    const int PT = 4;
    const int OT = COUT / 64;
    const int CP = (C + 3) & ~3;
    __shared__ float sh[PT][KNN + 1][CP];

    int ib = blockIdx.x;
    int b  = ib / (N_PTS / PT);
    int n0 = (ib % (N_PTS / PT)) * PT;
    const T* xb = x + (size_t)b * bstride;

    const int TOT = PT * (KNN + 1) * C;
    for (int t = threadIdx.x; t < TOT; t += 256) {
        int pt = t / ((KNN + 1) * C);
        int r  = t % ((KNN + 1) * C);
        int row = r / C, c = r % C;
        int n = n0 + pt;
        int m = (row == 0) ? n
                           : (idx[((size_t)b * N_PTS + n) * KNN + (row - 1)] & (N_PTS - 1));
        sh[pt][row][c] = ldf(&xb[(size_t)c * N_PTS + m]);
    }
    __syncthreads();

    int w = threadIdx.x >> 6, lane = threadIdx.x & 63;
    int n = n0 + w;

    constexpr int KT = (OT >= 4) ? 10 : 20;
    constexpr int NPASS = KNN / KT;

    float base[OT];
    float mx[OT];
#pragma unroll
    for (int j = 0; j < OT; ++j) { base[j] = 0.f; mx[j] = -FLT_MAX; }

    const float inv = rsqrtf(1.0f + 1e-5f);

#pragma unroll
    for (int pass = 0; pass < NPASS; ++pass) {
        float acc[OT][KT];
#pragma unroll
        for (int j = 0; j < OT; ++j)
#pragma unroll
            for (int k = 0; k < KT; ++k) acc[j][k] = 0.f;

        for (int c = 0; c < C; ++c) {
            float xq = sh[w][0][c];
            float w2v[OT];
#pragma unroll
            for (int j = 0; j < OT; ++j)
                w2v[j] = Wt[(size_t)(C + c) * COUT + lane + 64 * j];
            if (pass == 0) {
#pragma unroll
                for (int j = 0; j < OT; ++j) {
                    float w1v = Wt[(size_t)c * COUT + lane + 64 * j];
                    base[j] = fmaf(w1v - w2v[j], xq, base[j]);
                }
            }
#pragma unroll
            for (int k = 0; k < KT; ++k) {
                float nv = sh[w][1 + pass * KT + k][c];
#pragma unroll
                for (int j = 0; j < OT; ++j) acc[j][k] = fmaf(w2v[j], nv, acc[j][k]);
            }
        }

#pragma unroll
        for (int j = 0; j < OT; ++j) {
            int o = lane + 64 * j;
            float scale = gam[o] * inv, bias = bet[o];
#pragma unroll
            for (int k = 0; k < KT; ++k) {
                float h = (base[j] + acc[j][k]) * scale + bias;
                h = h > 0.f ? h : LRELU_S * h;
                mx[j] = fmaxf(mx[j], h);
            }
        }
    }

    float s = 0.f;
#pragma unroll
    for (int j = 0; j < OT; ++j) {
        int o = lane + 64 * j;
        bf16 bv = __float2bfloat16(mx[j]);
        if (!WF) out[(size_t)b * ostride + (size_t)o * N_PTS + n] = bv;
        if (WF) {
            featT[((size_t)b * N_PTS + n) * FT + c0f + o] = bv;
            float q = b2f(bv);
            s = fmaf(q, q, s);
        }
    }
    if (WF && xxout) {
#pragma unroll
        for (int off = 32; off >= 1; off >>= 1) s += __shfl_xor(s, off);
        if (lane == 0) xxout[(size_t)b * N_PTS + n] = s;
    }
}

// ---------------------------------------------------------------------------
// conv5 via MFMA. Block: 64o x 128n, 4 waves (wave owns 32 n-rows), NPOOL=16
// n-chunks -> 1024 blocks, ~34 KB LDS -> 4 blocks/CU. When inputs are bf16
// (isb), the lo-correction MFMAs and Al staging are skipped (exact).
__global__ __launch_bounds__(256) void k_conv5mfma(
        const bf16* __restrict__ featT, const bf16* __restrict__ w5sp,
        const float* __restrict__ g5, const float* __restrict__ b5,
        float* __restrict__ fmxp, float* __restrict__ fsmp,
        const int* __restrict__ flag) {
    __shared__ __align__(16) short Bt[128 * 64];   // 16 KB
    __shared__ __align__(16) short Ah[64 * 64];    //  8 KB
    __shared__ __align__(16) short Al[64 * 64];    //  8 KB
    __shared__ float rmx[4][64];
    __shared__ float rsm[4][64];

    const int isb = *flag;
    int ib = blockIdx.x;                 // B * 16 * 16
    int b  = ib / 256;
    int rem = ib % 256;
    int o0 = (rem >> 4) * 64;
    int nt = rem & 15;
    int tid = threadIdx.x;
    int w = tid >> 6, lane = tid & 63;
    int l15 = lane & 15, quad = lane >> 4;

    const bf16* Whi = w5sp;
    const bf16* Wlo = w5sp + 1024 * 512;
    const bf16* fb  = featT + (size_t)b * N_PTS * FT;
    const int nbase0 = nt * 128;

    floatx4 acc[4][2];
#pragma unroll
    for (int mi = 0; mi < 4; ++mi)
#pragma unroll
        for (int ni = 0; ni < 2; ++ni) acc[mi][ni] = (floatx4){0.f, 0.f, 0.f, 0.f};

    for (int ck = 0; ck < 512; ck += 64) {
        __syncthreads();
#pragma unroll
        for (int it = 0; it < 4; ++it) {                 // B: 128 rows x 64k
            int s = tid + it * 256;
            int row = s >> 3, seg = s & 7;
            int gseg = seg ^ (row & 7);
            gload16(fb + (size_t)(nbase0 + row) * FT + ck + gseg * 8,
                    &Bt[(s & ~63) * 8]);
        }
#pragma unroll
        for (int it = 0; it < 2; ++it) {                 // A hi(/lo): 64 rows x 64k
            int s = tid + it * 256;
            int row = s >> 3, seg = s & 7;
            int gseg = seg ^ (row & 7);
            gload16(Whi + (size_t)(o0 + row) * 512 + ck + gseg * 8, &Ah[(s & ~63) * 8]);
            if (!isb)
                gload16(Wlo + (size_t)(o0 + row) * 512 + ck + gseg * 8, &Al[(s & ~63) * 8]);
        }
        __syncthreads();
#pragma unroll
        for (int kk = 0; kk < 64; kk += 32) {
            int ks = kk >> 3;
            short8v bfr[2], ah[4], al[4];
#pragma unroll
            for (int ni = 0; ni < 2; ++ni) {
                int row = w * 32 + ni * 16 + l15;
                int seg = (ks + quad) ^ (row & 7);
                bfr[ni] = *(const short8v*)&Bt[row * 64 + seg * 8];
            }
#pragma unroll
            for (int mi = 0; mi < 4; ++mi) {
                int row = mi * 16 + l15;
                int seg = (ks + quad) ^ (row & 7);
                ah[mi] = *(const short8v*)&Ah[row * 64 + seg * 8];
                if (!isb) al[mi] = *(const short8v*)&Al[row * 64 + seg * 8];
            }
#pragma unroll
            for (int mi = 0; mi < 4; ++mi)
#pragma unroll
                for (int ni = 0; ni < 2; ++ni) {
                    acc[mi][ni] = __builtin_amdgcn_mfma_f32_16x16x32_bf16(ah[mi], bfr[ni], acc[mi][ni], 0, 0, 0);
                    if (!isb)
                        acc[mi][ni] = __builtin_amdgcn_mfma_f32_16x16x32_bf16(al[mi], bfr[ni], acc[mi][ni], 0, 0, 0);
                }
        }
    }

    const float inv = rsqrtf(1.0f + 1e-5f);
#pragma unroll
    for (int mi = 0; mi < 4; ++mi) {
#pragma unroll
        for (int r = 0; r < 4; ++r) {
            int o = o0 + mi * 16 + quad * 4 + r;
            float scale = g5[o] * inv, bias = b5[o];
            float mx = -FLT_MAX, sm = 0.f;
#pragma unroll
            for (int ni = 0; ni < 2; ++ni) {
                float h = acc[mi][ni][r] * scale + bias;
                h = h > 0.f ? h : LRELU_S * h;
                mx = fmaxf(mx, h);
                sm += h;
            }
#pragma unroll
            for (int off = 1; off <= 8; off <<= 1) {
                mx = fmaxf(mx, __shfl_xor(mx, off));
                sm += __shfl_xor(sm, off);
            }
            if (l15 == 0) {
                rmx[w][mi * 16 + quad * 4 + r] = mx;
                rsm[w][mi * 16 + quad * 4 + r] = sm;
            }
        }
    }
    __syncthreads();
    if (tid < 64) {
        float mx = -FLT_MAX, sm = 0.f;
#pragma unroll
        for (int ww = 0; ww < 4; ++ww) { mx = fmaxf(mx, rmx[ww][tid]); sm += rsm[ww][tid]; }
        fmxp[((size_t)b * 1024 + o0 + tid) * NPOOL + nt] = mx;
        fsmp[((size_t)b * 1024 + o0 + tid) * NPOOL + nt] = sm;
    }
}

// ---------------------------------------------------------------------------
// Pool partial reduce -> fvec (B, 2048) = [max(1024) | mean(1024)].
__global__ void k_pool(const float* __restrict__ fmxp, const float* __restrict__ fsmp,
                       float* __restrict__ fvec) {
    int i = blockIdx.x * blockDim.x + threadIdx.x;
    if (i >= B_SZ * 1024) return;
    int b = i >> 10, o = i & 1023;
    float mx = -FLT_MAX, sm = 0.f;
    for (int ch = 0; ch < NPOOL; ++ch) {
        mx = fmaxf(mx, fmxp[(size_t)i * NPOOL + ch]);
        sm += fsmp[(size_t)i * NPOOL + ch];
    }
    fvec[(size_t)b * 2048 + o] = mx;
    fvec[(size_t)b * 2048 + 1024 + o] = sm * (1.0f / N_PTS);
}

// ---------------------------------------------------------------------------
// fc1 (raw-dtype weights): block per (b,o).
__global__ __launch_bounds__(256) void k_fc1(const float* __restrict__ fvec,
        const void* __restrict__ fw1, const void* __restrict__ fb1,
        const void* __restrict__ g6,  const void* __restrict__ b6,
        const int* __restrict__ flag, float* __restrict__ tbuf) {
    __shared__ float red[4];
    int ib = blockIdx.x;
    int b = ib >> 9, o = ib & 511;
    const float* fv = fvec + (size_t)b * 2048;
    int tid = threadIdx.x;
    const int isb = *flag;
    float s = 0.f;
    if (isb) {
        const bf16* wr = (const bf16*)fw1 + (size_t)o * 2048;
        for (int j = tid; j < 2048; j += 256) s = fmaf(b2f(wr[j]), fv[j], s);
    } else {
        const float* wr = (const float*)fw1 + (size_t)o * 2048;
        for (int j = tid; j < 2048; j += 256) s = fmaf(wr[j], fv[j], s);
    }
#pragma unroll
    for (int off = 32; off >= 1; off >>= 1) s += __shfl_xor(s, off);
    if ((tid & 63) == 0) red[tid >> 6] = s;
    __syncthreads();
    if (tid == 0) {
        float fb = isb ? b2f(((const bf16*)fb1)[o]) : ((const float*)fb1)[o];
        float gg = isb ? b2f(((const bf16*)g6)[o])  : ((const float*)g6)[o];
        float bb = isb ? b2f(((const bf16*)b6)[o])  : ((const float*)b6)[o];
        float acc = fb + red[0] + red[1] + red[2] + red[3];
        float h = acc * gg * rsqrtf(1.0f + 1e-5f) + bb;
        tbuf[(size_t)b * 512 + o] = h > 0.f ? h : LRELU_S * h;
    }
}

// ---------------------------------------------------------------------------
// fc2 (raw-dtype weights): block per (b,o).
__global__ __launch_bounds__(256) void k_fc2(const float* __restrict__ tbuf,
        const void* __restrict__ fw2, const void* __restrict__ fb2,
        const void* __restrict__ g7,  const void* __restrict__ b7,
        const int* __restrict__ flag, void* __restrict__ out) {
    __shared__ float red[4];
    int ib = blockIdx.x;
    int b = ib >> 8, o = ib & 255;
    const float* tv = tbuf + (size_t)b * 512;
    int tid = threadIdx.x;
    const int isb = *flag;
    float s;
    if (isb) {
        const bf16* wr = (const bf16*)fw2 + (size_t)o * 512;
        s = fmaf(b2f(wr[tid]), tv[tid], b2f(wr[tid + 256]) * tv[tid + 256]);
    } else {
        const float* wr = (const float*)fw2 + (size_t)o * 512;
        s = fmaf(wr[tid], tv[tid], wr[tid + 256] * tv[tid + 256]);
    }
#pragma unroll
    for (int off = 32; off >= 1; off >>= 1) s += __shfl_xor(s, off);
    if ((tid & 63) == 0) red[tid >> 6] = s;
    __syncthreads();
    if (tid == 0) {
        float fb = isb ? b2f(((const bf16*)fb2)[o]) : ((const float*)fb2)[o];
        float gg = isb ? b2f(((const bf16*)g7)[o])  : ((const float*)g7)[o];
        float bb = isb ? b2f(((const bf16*)b7)[o])  : ((const float*)b7)[o];
        float acc = fb + red[0] + red[1] + red[2] + red[3];
        float h = acc * gg * rsqrtf(1.0f + 1e-5f) + bb;
        if (isb) ((bf16*)out)[(size_t)b * 256 + o] = __float2bfloat16(h);
        else     ((float*)out)[(size_t)b * 256 + o] = h;
    }
}

// ---------------------------------------------------------------------------
// Fallback conv5 (VALU) + head, used when ws too small for the gram path.
#define NCH 2
__global__ __launch_bounds__(256) void k_conv5pool(const bf16* __restrict__ feat,
                            const float* __restrict__ w5,
                            const float* __restrict__ g5,
                            const float* __restrict__ b5,
                            float* __restrict__ fmxp, float* __restrict__ fsmp) {
    const int OT = 8;
    const int NT = 4;
    const int CHN = N_PTS / NCH;
    __shared__ float wl[OT][512];
    __shared__ float rmx[4][OT];
    __shared__ float rsm[4][OT];

    int ib = blockIdx.x;
    int ch = ib % NCH;
    int ot = (ib / NCH) % (1024 / OT);
    int b  = ib / (NCH * (1024 / OT));
    int o0 = ot * OT;
    const bf16* fb = feat + (size_t)b * 512 * N_PTS;

    for (int t = threadIdx.x; t < OT * 512; t += 256) {
        int o = t >> 9, c = t & 511;
        wl[o][c] = w5[(size_t)(o0 + o) * 512 + c];
    }
    __syncthreads();

    const int n0 = ch * CHN + threadIdx.x * NT;

    float acc[OT][NT];
#pragma unroll
    for (int o = 0; o < OT; ++o)
#pragma unroll
        for (int t = 0; t < NT; ++t) acc[o][t] = 0.f;

    for (int c = 0; c < 512; c += 4) {
        float fv[4][NT];
#pragma unroll
        for (int j = 0; j < 4; ++j) {
            uint2 u = *(const uint2*)(fb + (size_t)(c + j) * N_PTS + n0);
            fv[j][0] = __uint_as_float(u.x << 16);
            fv[j][1] = __uint_as_float(u.x & 0xFFFF0000u);
            fv[j][2] = __uint_as_float(u.y << 16);
            fv[j][3] = __uint_as_float(u.y & 0xFFFF0000u);
        }
#pragma unroll
        for (int o = 0; o < OT; ++o) {
            float4 wv = *(const float4*)&wl[o][c];
#pragma unroll
            for (int t = 0; t < NT; ++t) {
                acc[o][t] = fmaf(wv.x, fv[0][t], acc[o][t]);
                acc[o][t] = fmaf(wv.y, fv[1][t], acc[o][t]);
                acc[o][t] = fmaf(wv.z, fv[2][t], acc[o][t]);
                acc[o][t] = fmaf(wv.w, fv[3][t], acc[o][t]);
            }
        }
    }

    const float inv = rsqrtf(1.0f + 1e-5f);
    int w = threadIdx.x >> 6, lane = threadIdx.x & 63;
#pragma unroll
    for (int o = 0; o < OT; ++o) {
        float scale = g5[o0 + o] * inv, bias = b5[o0 + o];
        float mx = -FLT_MAX, sm = 0.f;
#pragma unroll
        for (int t = 0; t < NT; ++t) {
            float h = acc[o][t] * scale + bias;
            h = h > 0.f ? h : LRELU_S * h;
            mx = fmaxf(mx, h);
            sm += h;
        }
#pragma unroll
        for (int off = 32; off >= 1; off >>= 1) {
            mx = fmaxf(mx, __shfl_xor(mx, off));
            sm += __shfl_xor(sm, off);
        }
        if (lane == 0) { rmx[w][o] = mx; rsm[w][o] = sm; }
    }
    __syncthreads();
    if (threadIdx.x < OT) {
        int o = threadIdx.x;
        float mx = -FLT_MAX, sm = 0.f;
#pragma unroll
        for (int ww = 0; ww < 4; ++ww) { mx = fmaxf(mx, rmx[ww][o]); sm += rsm[ww][o]; }
        fmxp[((size_t)b * 1024 + o0 + o) * NCH + ch] = mx;
        fsmp[((size_t)b * 1024 + o0 + o) * NCH + ch] = sm;
    }
}

__global__ void k_head(const float* __restrict__ fmxp, const float* __restrict__ fsmp,
                       const float* __restrict__ fw1, const float* __restrict__ fb1,
                       const float* __restrict__ g6,  const float* __restrict__ b6,
                       const float* __restrict__ fw2, const float* __restrict__ fb2,
                       const float* __restrict__ g7,  const float* __restrict__ b7,
                       const int* __restrict__ flag, void* __restrict__ out) {
    __shared__ float f[2048];
    __shared__ float t[512];
    int b = blockIdx.x;
    for (int i = threadIdx.x; i < 1024; i += 256) {
        float mx = -FLT_MAX, sm = 0.f;
        for (int ch = 0; ch < NCH; ++ch) {
            mx = fmaxf(mx, fmxp[((size_t)b * 1024 + i) * NCH + ch]);
            sm += fsmp[((size_t)b * 1024 + i) * NCH + ch];
        }
        f[i]        = mx;
        f[1024 + i] = sm * (1.0f / N_PTS);
    }
    __syncthreads();
    const float inv = rsqrtf(1.0f + 1e-5f);
    for (int o = threadIdx.x; o < 512; o += 256) {
        const float* wr = fw1 + (size_t)o * 2048;
        float acc = fb1[o];
        for (int j = 0; j < 2048; ++j) acc += wr[j] * f[j];
        float h = acc * g6[o] * inv + b6[o];
        t[o] = h > 0.f ? h : LRELU_S * h;
    }
    __syncthreads();
    {
        int o = threadIdx.x;
        const float* wr = fw2 + (size_t)o * 512;
        float acc = fb2[o];
        for (int j = 0; j < 512; ++j) acc += wr[j] * t[j];
        float h = acc * g7[o] * inv + b7[o];
        if (*flag) ((bf16*)out)[(size_t)b * 256 + o] = __float2bfloat16(h);
        else       ((float*)out)[(size_t)b * 256 + o] = h;
    }
}

// ---------------------------------------------------------------------------
extern "C" void kernel_launch(void* const* d_in, const int* in_sizes, int n_in,
                              void* d_out, int out_size, void* d_ws, size_t ws_size,
                              hipStream_t stream) {
    static const int wsz[23] = {
        384, 64, 64,   8192, 64, 64,   16384, 128, 128,   65536, 256, 256,
        524288, 1024, 1024,   1048576, 512,   512, 512,   131072, 256,   256, 256
    };
    static const int trows[23] = {64,0,0, 64,0,0, 128,0,0, 256,0,0, 0,0,0, 0,0, 0,0, 0,0, 0,0};
    static const int tcols[23] = { 6,0,0,128,0,0, 128,0,0, 256,0,0, 0,0,0, 0,0, 0,0, 0,0, 0,0};

    WPack wp;
    int total = 0;
    for (int i = 0; i < 23; ++i) {
        wp.src[i] = d_in[i + 1]; wp.off[i] = total; total += wsz[i];
        wp.rows[i] = trows[i]; wp.cols[i] = tcols[i];
    }
    wp.off[23] = total;

    const size_t flag_bytes = 16;
    const size_t x0_bytes   = (size_t)B_SZ * 3 * N_PTS * 4;
    const size_t feat_bytes = (size_t)B_SZ * 512 * N_PTS * 2;
    const size_t idx_bytes  = (size_t)B_SZ * N_PTS * KNN * 4;
    const size_t pool_bytes = (size_t)B_SZ * 1024 * 4 * 2;
    const size_t wf_bytes   = (size_t)total * 4;
    const size_t base_need  = flag_bytes + x0_bytes + feat_bytes + idx_bytes + pool_bytes + wf_bytes;

    const size_t featT_bytes = (size_t)B_SZ * N_PTS * FT * 2;           //  8 MB
    const size_t xx_bytes    = (size_t)B_SZ * N_PTS * 4;
    const size_t wsp2_elems  = 4 * 64 * 64;
    const size_t wsp3_elems  = 4 * 128 * 64;
    const size_t wsp4_elems  = 4 * 256 * 128;
    const size_t w5sp_elems  = 2 * 1024 * 512;
    const size_t wsp_bytes   = (wsp2_elems + wsp3_elems + wsp4_elems + w5sp_elems) * 2;
    const size_t Yh_bytes    = (size_t)B_SZ * N_PTS * 512 * 2;          //  8 MB (max M2)
    const size_t S_bytes     = (size_t)B_SZ * N_PTS * N_PTS * 2;        // 32 MB fp16 dist
    const size_t full_need   = base_need + featT_bytes + 2 * xx_bytes + wsp_bytes
                             + Yh_bytes + S_bytes;

    if (ws_size < base_need) return;   // graceful fail
    const bool use_gram = (ws_size >= full_need);

    char* w = (char*)d_ws;
    int*   flag = (int*)w;              w += flag_bytes;
    float* x0   = (float*)w;            w += x0_bytes;
    bf16*  feat = (bf16*)w;             w += feat_bytes;
    int*   idx  = (int*)w;              w += idx_bytes;
    w += pool_bytes;
    float* wf   = (float*)w;            w += wf_bytes;
    bf16*  featT = (bf16*)w;            w += featT_bytes;
    float* xxA   = (float*)w;           w += xx_bytes;
    float* xxB   = (float*)w;           w += xx_bytes;
    bf16*  wsp2  = (bf16*)w;            w += wsp2_elems * 2;
    bf16*  wsp3  = (bf16*)w;            w += wsp3_elems * 2;
    bf16*  wsp4  = (bf16*)w;            w += wsp4_elems * 2;
    bf16*  w5sp  = (bf16*)w;            w += w5sp_elems * 2;
    bf16*  Yh    = (bf16*)w;            w += Yh_bytes;
    unsigned short* D = (unsigned short*)w;   // fp16 distance matrix

    // overlays in the idx region (idx unused in gram path):
    // fmxp+fsmp (512K) + fvec (32K) + tbuf (8K) <= idx_bytes (640K)
    float* fmxp = (float*)idx;                               // B*1024*NPOOL
    float* fsmp = fmxp + (size_t)B_SZ * 1024 * NPOOL;        // B*1024*NPOOL
    float* fvec = fsmp + (size_t)B_SZ * 1024 * NPOOL;        // B*2048
    float* tbuf = fvec + (size_t)B_SZ * 2048;                // B*512

    const int FBS = 512 * N_PTS;

    const float* w1t = wf + wp.off[0],  *g1 = wf + wp.off[1],  *b1 = wf + wp.off[2];
    const float* w2t = wf + wp.off[3],  *g2 = wf + wp.off[4],  *b2 = wf + wp.off[5];
    const float* w3t = wf + wp.off[6],  *g3 = wf + wp.off[7],  *b3 = wf + wp.off[8];
    const float* w4t = wf + wp.off[9],  *g4 = wf + wp.off[10], *b4 = wf + wp.off[11];
    const float* w5  = wf + wp.off[12], *g5 = wf + wp.off[13], *b5 = wf + wp.off[14];
    const float* fw1 = wf + wp.off[15], *fb1 = wf + wp.off[16];
    const float* g6  = wf + wp.off[17], *b6 = wf + wp.off[18];
    const float* fw2 = wf + wp.off[19], *fb2 = wf + wp.off[20];
    const float* g7  = wf + wp.off[21], *b7 = wf + wp.off[22];

    const int GK = B_SZ * N_PTS / 4;    // 2048 blocks
    const int G8 = B_SZ * N_PTS / 8;    // 1024 blocks (2 queries/wave kernels)
    const int NG = B_SZ * 256;          // gram blocks in k_gx

    if (use_gram) {
        const int rlimit = wp.off[15];
        const int nbrep = (rlimit + 255) / 256;
        const int prep_grid = nbrep + 16 + 32 + 128 + 2048 + 32;
        k_prep<<<prep_grid, 256, 0, stream>>>(wp, wf, rlimit,
                                              d_in[4], wsp2, d_in[7], wsp3,
                                              d_in[10], wsp4, d_in[13], w5sp,
                                              d_in[0], x0, flag);

        // layer 1: fused kNN + EdgeConv (writes featT[0:64) + xxA)
        k_knn3ec<<<G8, 256, 0, stream>>>(x0, w1t, g1, b1, featT, xxA);
        // layer 2
        k_gx<64, 64><<<NG + 64, 256, 0, stream>>>(featT, 0, wsp2, xxA, D, Yh, flag);
        k_selgmax<64><<<G8, 256, 0, stream>>>(D, Yh, g2, b2, featT, 64, xxB);
        // layer 3
        k_gx<64, 128><<<NG + 128, 256, 0, stream>>>(featT, 64, wsp3, xxB, D, Yh, flag);
        k_selgmax<128><<<G8, 256, 0, stream>>>(D, Yh, g3, b3, featT, 128, xxA);
        // layer 4 (writes featT channels [256,512) for conv5)
        k_gx<128, 256><<<NG + 256, 256, 0, stream>>>(featT, 128, wsp4, xxA, D, Yh, flag);
        k_selgmax<256><<<G8, 256, 0, stream>>>(D, Yh, g4, b4, featT, 256, nullptr);

        // conv5 MFMA + pooling partials, then head GEMVs (raw fc weights)
        k_conv5mfma<<<B_SZ * 256, 256, 0, stream>>>(featT, w5sp, g5, b5, fmxp, fsmp, flag);
        k_pool<<<(B_SZ * 1024 + 255) / 256, 256, 0, stream>>>(fmxp, fsmp, fvec);
        k_fc1<<<B_SZ * 512, 256, 0, stream>>>(fvec, d_in[16], d_in[17], d_in[18], d_in[19],
                                              flag, tbuf);
        k_fc2<<<B_SZ * 256, 256, 0, stream>>>(tbuf, d_in[20], d_in[21], d_in[22], d_in[23],
                                              flag, d_out);
    } else {
        k_sniff<<<1, 64, 0, stream>>>((const unsigned short*)d_in[0], flag);
        k_repack<<<(total + 255) / 256, 256, 0, stream>>>(wp, flag, wf, total);
        k_transpose<<<(B_SZ * N_PTS + 255) / 256, 256, 0, stream>>>(d_in[0], flag, x0);

        k_knn<float, 3><<<GK, 256, 0, stream>>>(x0, 3 * N_PTS, idx);
        k_edgeconv<float, 3, 64, false><<<GK, 256, 0, stream>>>(
            x0, 3 * N_PTS, idx, w1t, g1, b1, feat + 0 * N_PTS, FBS, nullptr, 0, nullptr);
        k_knn<bf16, 64><<<GK, 256, 0, stream>>>(feat + 0 * N_PTS, FBS, idx);
        k_edgeconv<bf16, 64, 64, false><<<GK, 256, 0, stream>>>(
            feat + 0 * N_PTS, FBS, idx, w2t, g2, b2, feat + 64 * N_PTS, FBS, nullptr, 0, nullptr);
        k_knn<bf16, 64><<<GK, 256, 0, stream>>>(feat + 64 * N_PTS, FBS, idx);
        k_edgeconv<bf16, 64, 128, false><<<GK, 256, 0, stream>>>(
            feat + 64 * N_PTS, FBS, idx, w3t, g3, b3, feat + 128 * N_PTS, FBS, nullptr, 0, nullptr);
        k_knn<bf16, 128><<<GK, 256, 0, stream>>>(feat + 128 * N_PTS, FBS, idx);
        k_edgeconv<bf16, 128, 256, false><<<GK, 256, 0, stream>>>(
            feat + 128 * N_PTS, FBS, idx, w4t, g4, b4, feat + 256 * N_PTS, FBS, nullptr, 0, nullptr);

        k_conv5pool<<<B_SZ * (1024 / 8) * NCH, 256, 0, stream>>>(feat, w5, g5, b5, fmxp, fsmp);
        k_head<<<B_SZ, 256, 0, stream>>>(fmxp, fsmp, fw1, fb1, g6, b6, fw2, fb2, g7, b7,
                                         flag, d_out);
    }
}

// Round 11
// 326.456 us; speedup vs baseline: 1.0802x; 1.0179x over previous
//
#include <hip/hip_runtime.h>
#include <hip/hip_bf16.h>
#include <float.h>

#define N_PTS 2048
#define B_SZ  4
#define KNN   20
#define LRELU_S 0.2f
#define FT    512          // featT row stride (channels)
#define NPOOL 16           // conv5 n-chunk partials (128 rows each)

typedef __hip_bfloat16 bf16;
typedef __attribute__((ext_vector_type(8))) short short8v;   // 8 bf16 (4 VGPRs)
typedef __attribute__((ext_vector_type(4))) short short4v;   // 4 bf16
typedef __attribute__((ext_vector_type(4))) float floatx4;

__device__ __forceinline__ float b2f(const bf16 v) { return __bfloat162float(v); }
__device__ __forceinline__ float ldf(const float* p) { return *p; }
__device__ __forceinline__ float ldf(const bf16* p)  { return __bfloat162float(*p); }
__device__ __forceinline__ short8v ld8(const bf16* p) { return *(const short8v*)p; }
__device__ __forceinline__ unsigned umin(unsigned a, unsigned b) { return a < b ? a : b; }
__device__ __forceinline__ short bfbits(float f) {
    bf16 t = __float2bfloat16(f);
    return *reinterpret_cast<short*>(&t);
}
// fp16 <-> fp32 via _Float16 (RNE convert, single v_cvt instruction).
__device__ __forceinline__ unsigned short f2h(float f) {
    _Float16 h = (_Float16)f;
    return *reinterpret_cast<unsigned short*>(&h);
}
__device__ __forceinline__ float h2f(unsigned short u) {
    _Float16 h;
    *reinterpret_cast<unsigned short*>(&h) = u;
    return (float)h;
}

// Direct global->LDS DMA, 16 B per lane. LDS dest is wave-uniform base +
// lane*16 (linear); swizzling is achieved by pre-swizzling the GLOBAL source
// address (rule: both-sides-or-neither).
__device__ __forceinline__ void gload16(const void* g, void* l) {
    __builtin_amdgcn_global_load_lds(
        (const __attribute__((address_space(1))) void*)g,
        (__attribute__((address_space(3))) void*)l, 16, 0, 0);
}

// ---------------------------------------------------------------------------
// Dtype sniffer: bf16 (flag=1) vs fp32 (flag=0). Reads 256 B.
__device__ __forceinline__ int sniff_body(const unsigned short* pts_hw) {
    int sane = 0;
    for (int j = 0; j < 64; ++j) {
        unsigned short v = pts_hw[2 * j];
        int e = (v >> 7) & 0xFF;
        if (e >= 100 && e <= 140) ++sane;
    }
    return (sane >= 32) ? 1 : 0;
}

__global__ void k_sniff(const unsigned short* __restrict__ pts_hw, int* __restrict__ flag) {
    if (threadIdx.x != 0 || blockIdx.x != 0) return;
    *flag = sniff_body(pts_hw);
}

// ---------------------------------------------------------------------------
// Weight repack metadata.
struct WPack {
    const void* src[23];
    int off[24];
    int rows[23];
    int cols[23];
};

__device__ __forceinline__ void repack_body(const WPack& wp, int isb,
                                            float* __restrict__ dst, int i, int limit,
                                            int skip12) {
    if (i >= limit) return;
    int lo = 0, hi = 23;
    while (lo + 1 < hi) { int mid = (lo + hi) >> 1; if (i >= wp.off[mid]) lo = mid; else hi = mid; }
    if (skip12 && lo == 12) return;    // gram path reads w5 only via w5sp
    int j = i - wp.off[lo];
    float v = isb ? b2f(((const bf16*)wp.src[lo])[j]) : ((const float*)wp.src[lo])[j];
    int dj = j;
    int cols = wp.cols[lo];
    if (cols) dj = (j % cols) * wp.rows[lo] + (j / cols);
    dst[wp.off[lo] + dj] = v;
}

// Split EdgeConv weights into bf16 hi/lo pairs for MFMA:
// dst = [W2hi | W2lo | Wdhi | Wdlo], each (COUT, C) row-major, Wd = W1 - W2.
template<int C, int COUT>
__device__ __forceinline__ void wsplit_body(const void* __restrict__ W, int isb,
                                            bf16* __restrict__ dst, int i) {
    if (i >= COUT * C) return;
    int o = i / C, c = i % C;
    float w1 = isb ? b2f(((const bf16*)W)[(size_t)o * 2 * C + c])
                   : ((const float*)W)[(size_t)o * 2 * C + c];
    float w2 = isb ? b2f(((const bf16*)W)[(size_t)o * 2 * C + C + c])
                   : ((const float*)W)[(size_t)o * 2 * C + C + c];
    float wd = w1 - w2;
    bf16 h2 = __float2bfloat16(w2);
    bf16 hd = __float2bfloat16(wd);
    dst[i]                = h2;
    dst[COUT * C + i]     = __float2bfloat16(w2 - b2f(h2));
    dst[2 * COUT * C + i] = hd;
    dst[3 * COUT * C + i] = __float2bfloat16(wd - b2f(hd));
}

// Split conv5 weights (1024x512) into bf16 hi/lo: dst = [hi | lo].
// When inputs are bf16 the lo plane is identically zero and never read.
__device__ __forceinline__ void w5split_body(const void* __restrict__ W, int isb,
                                             bf16* __restrict__ dst, int i) {
    if (i >= 1024 * 512) return;
    float w = isb ? b2f(((const bf16*)W)[i]) : ((const float*)W)[i];
    bf16 h = __float2bfloat16(w);
    dst[i] = h;
    if (!isb) dst[1024 * 512 + i] = __float2bfloat16(w - b2f(h));
}

// points (B,N,3) -> x0 (B,3,N) fp32, dtype-dynamic.
__device__ __forceinline__ void transpose_body(const void* __restrict__ pts, int isb,
                                               float* __restrict__ x0, int i) {
    if (i >= B_SZ * N_PTS) return;
    int b = i / N_PTS, n = i % N_PTS;
    for (int c = 0; c < 3; ++c) {
        size_t s = ((size_t)b * N_PTS + n) * 3 + c;
        float v = isb ? b2f(((const bf16*)pts)[s]) : ((const float*)pts)[s];
        x0[((size_t)b * 3 + c) * N_PTS + n] = v;
    }
}

// Merged prep (gram path): self-sniff + repack + 3x wsplit + w5split +
// transpose in one launch, dispatched by blockIdx range.
__global__ void k_prep(WPack wp, float* __restrict__ wf, int rlimit,
                       const void* __restrict__ w2s, bf16* __restrict__ wsp2,
                       const void* __restrict__ w3s, bf16* __restrict__ wsp3,
                       const void* __restrict__ w4s, bf16* __restrict__ wsp4,
                       const void* __restrict__ w5s, bf16* __restrict__ w5sp,
                       const void* __restrict__ pts, float* __restrict__ x0,
                       int* __restrict__ flagout) {
    __shared__ int sfl;
    if (threadIdx.x == 0) {
        int f = sniff_body((const unsigned short*)pts);
        sfl = f;
        if (blockIdx.x == 0) *flagout = f;
    }
    __syncthreads();
    const int isb = sfl;
    const int nbrep = (rlimit + 255) >> 8;
    int ib = blockIdx.x, t = threadIdx.x;
    if (ib < nbrep) { repack_body(wp, isb, wf, ib * 256 + t, rlimit, 1); return; }
    ib -= nbrep;
    if (ib < 16)   { wsplit_body<64, 64>(w2s, isb, wsp2, ib * 256 + t); return; }
    ib -= 16;
    if (ib < 32)   { wsplit_body<64, 128>(w3s, isb, wsp3, ib * 256 + t); return; }
    ib -= 32;
    if (ib < 128)  { wsplit_body<128, 256>(w4s, isb, wsp4, ib * 256 + t); return; }
    ib -= 128;
    if (ib < 2048) { w5split_body(w5s, isb, w5sp, ib * 256 + t); return; }
    ib -= 2048;
    transpose_body(pts, isb, x0, ib * 256 + t);
}

// Standalone versions for the fallback path.
__global__ void k_repack(WPack wp, const int* __restrict__ flag, float* __restrict__ dst, int limit) {
    repack_body(wp, *flag, dst, blockIdx.x * blockDim.x + threadIdx.x, limit, 0);
}
__global__ void k_transpose(const void* __restrict__ pts, const int* __restrict__ flag,
                            float* __restrict__ x0) {
    transpose_body(pts, *flag, x0, blockIdx.x * blockDim.x + threadIdx.x);
}

// ---------------------------------------------------------------------------
// 32-candidate row loads (lane chunk), fp32 out.
__device__ __forceinline__ void load32(const float* row, int mbase, float* r) {
    const float4* p = (const float4*)(row + mbase);
#pragma unroll
    for (int i = 0; i < 8; ++i) {
        float4 f = p[i];
        r[4 * i + 0] = f.x; r[4 * i + 1] = f.y; r[4 * i + 2] = f.z; r[4 * i + 3] = f.w;
    }
}
__device__ __forceinline__ void load32(const bf16* row, int mbase, float* r) {
    const uint4* p = (const uint4*)(row + mbase);
#pragma unroll
    for (int i = 0; i < 4; ++i) {
        uint4 u = p[i];
        r[8 * i + 0] = __uint_as_float(u.x << 16);
        r[8 * i + 1] = __uint_as_float(u.x & 0xFFFF0000u);
        r[8 * i + 2] = __uint_as_float(u.y << 16);
        r[8 * i + 3] = __uint_as_float(u.y & 0xFFFF0000u);
        r[8 * i + 4] = __uint_as_float(u.z << 16);
        r[8 * i + 5] = __uint_as_float(u.z & 0xFFFF0000u);
        r[8 * i + 6] = __uint_as_float(u.w << 16);
        r[8 * i + 7] = __uint_as_float(u.w & 0xFFFF0000u);
    }
}

// ---------------------------------------------------------------------------
// Packed-key top-20 for two queries per wave, cached per-lane sorted top-2.
__device__ __forceinline__ void s2ins(unsigned k, unsigned& m1, unsigned& m2) {
    unsigned lo = umin(m1, k);
    unsigned hi = (m1 < k) ? k : m1;
    m1 = lo;
    m2 = umin(m2, hi);
}

__device__ __forceinline__ void select20x2(const unsigned* ka, const unsigned* kb,
                                           int* outA, int* outB, int lane) {
    const unsigned SENT = 0xFFFFFFFFu;
    unsigned a1 = SENT, a2 = SENT, b1 = SENT, b2 = SENT;
#pragma unroll
    for (int j = 0; j < 32; ++j) {
        s2ins(ka[j], a1, a2);
        s2ins(kb[j], b1, b2);
    }
#pragma unroll 1
    for (int k = 0; k < KNN; ++k) {
        unsigned va = a1, vb = b1;
#pragma unroll
        for (int off = 32; off >= 1; off >>= 1) {
            va = umin(va, (unsigned)__shfl_xor((int)va, off));
            vb = umin(vb, (unsigned)__shfl_xor((int)vb, off));
        }
        if (lane == 0) { outA[k] = (int)(va & 2047u); outB[k] = (int)(vb & 2047u); }
        if (a1 == va) { a1 = a2; a2 = SENT; }
        if (b1 == vb) { b1 = b2; b2 = SENT; }
        if (a1 == SENT) {
#pragma unroll
            for (int j = 0; j < 32; ++j) {
                unsigned t = (ka[j] > va) ? ka[j] : SENT;
                s2ins(t, a1, a2);
            }
        }
        if (b1 == SENT) {
#pragma unroll
            for (int j = 0; j < 32; ++j) {
                unsigned t = (kb[j] > vb) ? kb[j] : SENT;
                s2ins(t, b1, b2);
            }
        }
    }
}

// ---------------------------------------------------------------------------
// Fused layer-1: kNN (C=3, fp32, packed keys) + EdgeConv (C=3 -> 64) for the
// same 8 points. Select into LDS sidx, cooperative neighbor staging into LDS,
// then 2 points/wave, lane = channel.
__global__ __launch_bounds__(256) void k_knn3ec(const float* __restrict__ x0,
        const float* __restrict__ Wt, const float* __restrict__ gam,
        const float* __restrict__ bet, bf16* __restrict__ featT,
        float* __restrict__ xxout) {
    __shared__ float qf[8][3];
    __shared__ int sidx[8][KNN];
    __shared__ float sh[8][KNN][3];
    int ib = blockIdx.x;
    int b  = ib / (N_PTS / 8);
    int q0 = (ib % (N_PTS / 8)) * 8;
    const float* xb = x0 + (size_t)b * 3 * N_PTS;

    if (threadIdx.x < 24) {
        int q = threadIdx.x / 3, c = threadIdx.x % 3;
        qf[q][c] = xb[(size_t)c * N_PTS + q0 + q];
    }
    __syncthreads();

    int w = threadIdx.x >> 6, lane = threadIdx.x & 63;
    int mbase = lane * 32;

    float da[32], db[32];
#pragma unroll
    for (int j = 0; j < 32; ++j) { da[j] = 0.f; db[j] = 0.f; }
#pragma unroll
    for (int c = 0; c < 3; ++c) {
        float r[32];
        load32(xb + (size_t)c * N_PTS, mbase, r);
        float qac = qf[2 * w][c], qbc = qf[2 * w + 1][c];
#pragma unroll
        for (int j = 0; j < 32; ++j) {
            float ta = r[j] - qac; da[j] = fmaf(ta, ta, da[j]);
            float tb = r[j] - qbc; db[j] = fmaf(tb, tb, db[j]);
        }
    }
    unsigned ka[32], kb[32];
#pragma unroll
    for (int j = 0; j < 32; ++j) {
        ka[j] = (__float_as_uint(da[j]) & 0xFFFFF800u) | (unsigned)(mbase + j);
        kb[j] = (__float_as_uint(db[j]) & 0xFFFFF800u) | (unsigned)(mbase + j);
    }
    select20x2(ka, kb, &sidx[2 * w][0], &sidx[2 * w + 1][0], lane);
    __syncthreads();

    // ---- cooperative neighbor staging: 480 parallel loads (2/thread) ----
    for (int t = threadIdx.x; t < 8 * KNN * 3; t += 256) {
        int pt = t / (KNN * 3);
        int r  = t % (KNN * 3);
        int k = r / 3, c = r % 3;
        int m = sidx[pt][k] & (N_PTS - 1);
        sh[pt][k][c] = xb[(size_t)c * N_PTS + m];
    }
    __syncthreads();

    // ---- EdgeConv phase: points q0+2w, q0+2w+1; lane owns channel `lane` ----
    const float inv = rsqrtf(1.0f + 1e-5f);
    float scale = gam[lane] * inv, bias = bet[lane];
    float w1v[3], w2v[3];
#pragma unroll
    for (int c = 0; c < 3; ++c) {
        w1v[c] = Wt[(size_t)c * 64 + lane];
        w2v[c] = Wt[(size_t)(3 + c) * 64 + lane];
    }
#pragma unroll
    for (int p = 0; p < 2; ++p) {
        int pt = 2 * w + p;
        float base = 0.f;
#pragma unroll
        for (int c = 0; c < 3; ++c) base = fmaf(w1v[c] - w2v[c], qf[pt][c], base);
        float mx = -FLT_MAX;
#pragma unroll
        for (int k = 0; k < KNN; ++k) {
            float acc = 0.f;
#pragma unroll
            for (int c = 0; c < 3; ++c) acc = fmaf(w2v[c], sh[pt][k][c], acc);
            float h = (base + acc) * scale + bias;
            h = h > 0.f ? h : LRELU_S * h;
            mx = fmaxf(mx, h);
        }
        bf16 bv = __float2bfloat16(mx);
        size_t i = (size_t)b * N_PTS + q0 + pt;
        featT[i * FT + lane] = bv;
        float qv = b2f(bv);
        float s = qv * qv;
#pragma unroll
        for (int off = 32; off >= 1; off >>= 1) s += __shfl_xor(s, off);
        if (lane == 0) xxout[i] = s;
    }
}

// ---------------------------------------------------------------------------
// kNN (direct, fallback path): wave-per-query.
template<typename T, int C>
__global__ __launch_bounds__(256) void k_knn(const T* __restrict__ x, int bstride,
                                             int* __restrict__ idx) {
    __shared__ float qf[4][C];
    int ib = blockIdx.x;
    int b  = ib / (N_PTS / 4);
    int q0 = (ib % (N_PTS / 4)) * 4;
    const T* xb = x + (size_t)b * bstride;

    for (int t = threadIdx.x; t < 4 * C; t += 256) {
        int pt = t / C, c = t % C;
        qf[pt][c] = ldf(&xb[(size_t)c * N_PTS + (q0 + pt)]);
    }
    __syncthreads();

    int w = threadIdx.x >> 6, lane = threadIdx.x & 63;
    int q = q0 + w;
    int mbase = lane * 32;

    float v[32];
#pragma unroll
    for (int j = 0; j < 32; ++j) v[j] = 0.f;

    for (int c = 0; c < C; ++c) {
        float qc = qf[w][c];
        float r[32];
        load32(xb + (size_t)c * N_PTS, mbase, r);
#pragma unroll
        for (int j = 0; j < 32; ++j) { float t = r[j] - qc; v[j] = fmaf(t, t, v[j]); }
    }

    for (int k = 0; k < KNN; ++k) {
        float bv = FLT_MAX; int bi = 0x7FFFFFFF;
#pragma unroll
        for (int j = 0; j < 32; ++j)
            if (v[j] < bv) { bv = v[j]; bi = mbase + j; }
#pragma unroll
        for (int off = 32; off >= 1; off >>= 1) {
            float ov = __shfl_xor(bv, off);
            int   oi = __shfl_xor(bi, off);
            if (ov < bv || (ov == bv && oi < bi)) { bv = ov; bi = oi; }
        }
        if (lane == 0) idx[((size_t)b * N_PTS + q) * KNN + k] = bi;
        int wl = bi >> 5, wj = bi & 31;
        if (lane == wl) {
#pragma unroll
            for (int j = 0; j < 32; ++j) if (j == wj) v[j] = FLT_MAX;
        }
    }
}

// ---------------------------------------------------------------------------
// Gram body via MFMA with fused distance epilogue. dist = xx[n] - 2*G + xx[m]
// computed in fp32 (identical fmaf order to the reference path), clamped >=0,
// quantized to fp16. The fp16 tile is staged in the (now dead) staging LDS
// with a 16B-granule XOR swizzle, then streamed out with coalesced 16B
// stores (8 per thread vs the previous 64 scalar 2B scatter stores).
template<int C>
__device__ __forceinline__ void gram_body(const bf16* __restrict__ featT, int c0,
                                          const float* __restrict__ xx,
                                          unsigned short* __restrict__ D,
                                          short* lds, int ib) {
    const int KC = 64;
    short* At = lds;
    short* Bt = lds + 128 * 64;
    int b  = ib >> 8;
    int t  = ib & 255;
    int n0 = (t >> 4) << 7;
    int m0 = (t & 15) << 7;

    int tid = threadIdx.x;
    int w = tid >> 6, lane = tid & 63;
    int rw = (w & 1) * 64, cw = (w >> 1) * 64;
    int lrow = lane & 15, quad = lane >> 4;

    floatx4 acc[4][4];
#pragma unroll
    for (int ri = 0; ri < 4; ++ri)
#pragma unroll
        for (int ci = 0; ci < 4; ++ci) acc[ri][ci] = (floatx4){0.f, 0.f, 0.f, 0.f};

    for (int ck = 0; ck < C; ck += KC) {
        __syncthreads();
#pragma unroll
        for (int it = 0; it < 4; ++it) {
            int s = tid + it * 256;
            int row = s >> 3, seg = s & 7;
            int gseg = seg ^ (row & 7);
            gload16(featT + ((size_t)(b * N_PTS + n0 + row) * FT) + c0 + ck + gseg * 8,
                    &At[(s & ~63) * 8]);
            gload16(featT + ((size_t)(b * N_PTS + m0 + row) * FT) + c0 + ck + gseg * 8,
                    &Bt[(s & ~63) * 8]);
        }
        __syncthreads();
#pragma unroll
        for (int kk = 0; kk < KC; kk += 32) {
            int ks = kk >> 3;
            short8v a[4], bb[4];
#pragma unroll
            for (int ri = 0; ri < 4; ++ri) {
                int row = rw + ri * 16 + lrow;
                int seg = (ks + quad) ^ (row & 7);
                a[ri] = *(const short8v*)&At[row * 64 + seg * 8];
            }
#pragma unroll
            for (int ci = 0; ci < 4; ++ci) {
                int row = cw + ci * 16 + lrow;
                int seg = (ks + quad) ^ (row & 7);
                bb[ci] = *(const short8v*)&Bt[row * 64 + seg * 8];
            }
#pragma unroll
            for (int ri = 0; ri < 4; ++ri)
#pragma unroll
                for (int ci = 0; ci < 4; ++ci)
                    acc[ri][ci] = __builtin_amdgcn_mfma_f32_16x16x32_bf16(a[ri], bb[ci], acc[ri][ci], 0, 0, 0);
        }
    }

    const float* xr = xx + (size_t)b * N_PTS;
    float xmv[4];
#pragma unroll
    for (int ci = 0; ci < 4; ++ci)
        xmv[ci] = xr[m0 + cw + ci * 16 + lrow];
    float xnv[4][4];
#pragma unroll
    for (int ri = 0; ri < 4; ++ri)
#pragma unroll
        for (int reg = 0; reg < 4; ++reg)
            xnv[ri][reg] = xr[n0 + rw + ri * 16 + quad * 4 + reg];

    // stage the fp16 tile in LDS (swizzled), then coalesced stream-out
    __syncthreads();                       // staging LDS is dead now
    unsigned short* dl = (unsigned short*)lds;   // 128x128 fp16 = 32 KB
#pragma unroll
    for (int ri = 0; ri < 4; ++ri)
#pragma unroll
        for (int ci = 0; ci < 4; ++ci) {
            int ml = cw + ci * 16 + lrow;
#pragma unroll
            for (int reg = 0; reg < 4; ++reg) {
                int nl = rw + ri * 16 + quad * 4 + reg;
                float d = fmaf(-2.f, acc[ri][ci][reg], xmv[ci]) + xnv[ri][reg];
                d = fmaxf(d, 0.f);
                int col = (((ml >> 3) ^ (nl & 15)) << 3) + (ml & 7);
                dl[nl * 128 + col] = f2h(d);
            }
        }
    __syncthreads();
    unsigned short* Drow = D + ((size_t)b * N_PTS + n0) * N_PTS + m0;
#pragma unroll
    for (int it = 0; it < 8; ++it) {
        int ch = tid + it * 256;
        int row = ch >> 4;
        int c8 = (ch & 15) * 8;
        int g  = (((c8 >> 3) ^ (row & 15)) << 3);
        *(uint4*)(Drow + (size_t)row * N_PTS + c8) = *(const uint4*)(dl + row * 128 + g);
    }
}

// ---------------------------------------------------------------------------
// Xform body via MFMA, bf16 output, LDS-staged coalesced writes (the direct
// short4v stores hit a different Y row per lane -> fully uncoalesced).
// When inputs are bf16 (isb), the W2 lo-correction is identically zero ->
// skip those MFMAs (exact).
template<int COUT, int C>
__device__ __forceinline__ void xform_body(const bf16* __restrict__ featT, int c0,
                                           const bf16* __restrict__ Wsp,
                                           bf16* __restrict__ Yh, int isb,
                                           short* lds, int ib2) {
    const int M2 = 2 * COUT;
    const int KC = 64;
    short* Bt = lds;
    int nt = ib2 & 63;
    int mt = ib2 >> 6;
    int tid = threadIdx.x;
    int w = tid >> 6, lane = tid & 63;
    int rw = (w & 1) * 64, cw = (w >> 1) * 64;
    int l15 = lane & 15, quad = lane >> 4;

    floatx4 acc[4][4];
#pragma unroll
    for (int ri = 0; ri < 4; ++ri)
#pragma unroll
        for (int ci = 0; ci < 4; ++ci) acc[ri][ci] = (floatx4){0.f, 0.f, 0.f, 0.f};

    for (int ck = 0; ck < C; ck += KC) {
        __syncthreads();
#pragma unroll
        for (int it = 0; it < 4; ++it) {
            int s = tid + it * 256;
            int row = s >> 3, seg = s & 7;
            int gseg = seg ^ (row & 7);
            gload16(featT + (size_t)(nt * 128 + row) * FT + c0 + ck + gseg * 8,
                    &Bt[(s & ~63) * 8]);
        }
        __syncthreads();
#pragma unroll
        for (int kk = 0; kk < KC; kk += 32) {
            int ks = kk >> 3;
            short8v bfr[4];
#pragma unroll
            for (int ci = 0; ci < 4; ++ci) {
                int row = cw + ci * 16 + l15;
                int seg = (ks + quad) ^ (row & 7);
                bfr[ci] = *(const short8v*)&Bt[row * 64 + seg * 8];
            }
#pragma unroll
            for (int ri = 0; ri < 4; ++ri) {
                int rbase = mt * 128 + rw + ri * 16;          // band-aligned, lane-uniform
                bool uselo = (!isb) || (rbase >= COUT);       // W2 lo==0 when bf16 input
                int mrow = rbase + l15;
                int base = (mrow < COUT) ? mrow : (mrow + COUT);
                const bf16* hi = Wsp + (size_t)base * C + ck + kk + quad * 8;
                short8v ah = ld8(hi);
                short8v al;
                if (uselo) al = ld8(hi + (size_t)COUT * C);
#pragma unroll
                for (int ci = 0; ci < 4; ++ci) {
                    acc[ri][ci] = __builtin_amdgcn_mfma_f32_16x16x32_bf16(ah, bfr[ci], acc[ri][ci], 0, 0, 0);
                    if (uselo)
                        acc[ri][ci] = __builtin_amdgcn_mfma_f32_16x16x32_bf16(al, bfr[ci], acc[ri][ci], 0, 0, 0);
                }
            }
        }
    }

    // stage bf16 tile (rows = n local, cols = m local) in LDS, swizzled
    __syncthreads();
#pragma unroll
    for (int ri = 0; ri < 4; ++ri)
#pragma unroll
        for (int ci = 0; ci < 4; ++ci) {
            int nl = cw + ci * 16 + l15;
            int ml = rw + ri * 16 + quad * 4;
            short4v o4;
            o4[0] = bfbits(acc[ri][ci][0]);
            o4[1] = bfbits(acc[ri][ci][1]);
            o4[2] = bfbits(acc[ri][ci][2]);
            o4[3] = bfbits(acc[ri][ci][3]);
            int col = (((ml >> 3) ^ (nl & 15)) << 3) + (ml & 7);
            *(short4v*)&lds[nl * 128 + col] = o4;
        }
    __syncthreads();
    short* Ybase = (short*)Yh + (size_t)(nt * 128) * M2 + mt * 128;
#pragma unroll
    for (int it = 0; it < 8; ++it) {
        int ch = tid + it * 256;
        int row = ch >> 4;
        int c8 = (ch & 15) * 8;
        int g  = (((c8 >> 3) ^ (row & 15)) << 3);
        *(uint4*)(Ybase + (size_t)row * M2 + c8) = *(const uint4*)(lds + row * 128 + g);
    }
}

// ---------------------------------------------------------------------------
// Merged gram + xform: first B_SZ*256 blocks do the gram tile, the trailing
// COUT blocks do the dense point transform (fills otherwise-idle CUs).
template<int C, int COUT>
__global__ __launch_bounds__(256) void k_gx(const bf16* __restrict__ featT, int c0,
        const bf16* __restrict__ Wsp, const float* __restrict__ xx,
        unsigned short* __restrict__ D, bf16* __restrict__ Yh,
        const int* __restrict__ flag) {
    __shared__ __align__(16) short lds[2 * 128 * 64];   // 32 KB
    int ib = blockIdx.x;
    if (ib < B_SZ * 256) {
        gram_body<C>(featT, c0, xx, D, lds, ib);
    } else {
        xform_body<COUT, C>(featT, c0, Wsp, Yh, *flag, lds, ib - B_SZ * 256);
    }
}

// ---------------------------------------------------------------------------
// Merged select + gather-max: block = 8 queries. Phase 1 builds top-20 keys
// straight from the precomputed fp16 distance rows (no xx loads, no fmaf);
// phase 2 does the gather-max epilogue (2 pts/wave) reading bf16 Y, writes
// featT and next-layer xx.
template<int COUT>
__global__ __launch_bounds__(256) void k_selgmax(const unsigned short* __restrict__ D,
        const bf16* __restrict__ Yh,
        const float* __restrict__ gam, const float* __restrict__ bet,
        bf16* __restrict__ featT, int c0f, float* __restrict__ xxout) {
    const int M2 = 2 * COUT;
    const int OT = COUT / 64;
    __shared__ int sidx[8][KNN];

    int ib = blockIdx.x;
    int b  = ib / (N_PTS / 8);
    int q0 = (ib % (N_PTS / 8)) * 8;
    int w = threadIdx.x >> 6, lane = threadIdx.x & 63;
    int qa = q0 + 2 * w;
    const unsigned short* gA = D + ((size_t)b * N_PTS + qa) * N_PTS;
    const unsigned short* gB = gA + N_PTS;

    unsigned ka[32], kb[32];
#pragma unroll
    for (int r = 0; r < 4; ++r) {
        int m0 = r * 512 + (lane << 3);
        uint4 ua = *(const uint4*)(gA + m0);
        uint4 ub = *(const uint4*)(gB + m0);
        unsigned uw[4] = {ua.x, ua.y, ua.z, ua.w};
        unsigned vw[4] = {ub.x, ub.y, ub.z, ub.w};
#pragma unroll
        for (int h = 0; h < 4; ++h) {
            float a0 = h2f((unsigned short)(uw[h] & 0xFFFFu));
            float a1 = h2f((unsigned short)(uw[h] >> 16));
            ka[8 * r + 2 * h]     = (__float_as_uint(a0) & 0xFFFFF800u) | (unsigned)(m0 + 2 * h);
            ka[8 * r + 2 * h + 1] = (__float_as_uint(a1) & 0xFFFFF800u) | (unsigned)(m0 + 2 * h + 1);
            float c0v = h2f((unsigned short)(vw[h] & 0xFFFFu));
            float c1v = h2f((unsigned short)(vw[h] >> 16));
            kb[8 * r + 2 * h]     = (__float_as_uint(c0v) & 0xFFFFF800u) | (unsigned)(m0 + 2 * h);
            kb[8 * r + 2 * h + 1] = (__float_as_uint(c1v) & 0xFFFFF800u) | (unsigned)(m0 + 2 * h + 1);
        }
    }
    select20x2(ka, kb, &sidx[2 * w][0], &sidx[2 * w + 1][0], lane);
    __syncthreads();

    // ---- gather-max for points qa, qa+1 ----
    size_t iA = (size_t)b * N_PTS + qa;
    const float inv = rsqrtf(1.0f + 1e-5f);
    float yda[OT], ydb[OT], scl[OT], bis[OT], mxa[OT], mxb[OT];
#pragma unroll
    for (int j = 0; j < OT; ++j) {
        int o = lane + 64 * j;
        yda[j] = b2f(Yh[iA * M2 + COUT + o]);
        ydb[j] = b2f(Yh[(iA + 1) * M2 + COUT + o]);
        scl[j] = gam[o] * inv;
        bis[j] = bet[o];
        mxa[j] = -FLT_MAX; mxb[j] = -FLT_MAX;
    }
    const bf16* Yb = Yh + (size_t)b * N_PTS * M2;
#pragma unroll
    for (int k = 0; k < KNN; ++k) {
        int m0 = sidx[2 * w][k] & (N_PTS - 1);
        int m1 = sidx[2 * w + 1][k] & (N_PTS - 1);
        const bf16* r0 = Yb + (size_t)m0 * M2;
        const bf16* r1 = Yb + (size_t)m1 * M2;
#pragma unroll
        for (int j = 0; j < OT; ++j) {
            int o = lane + 64 * j;
            float ha = (yda[j] + b2f(r0[o])) * scl[j] + bis[j];
            ha = ha > 0.f ? ha : LRELU_S * ha;
            mxa[j] = fmaxf(mxa[j], ha);
            float hb = (ydb[j] + b2f(r1[o])) * scl[j] + bis[j];
            hb = hb > 0.f ? hb : LRELU_S * hb;
            mxb[j] = fmaxf(mxb[j], hb);
        }
    }
    float sa = 0.f, sb = 0.f;
#pragma unroll
    for (int j = 0; j < OT; ++j) {
        bf16 va = __float2bfloat16(mxa[j]);
        bf16 vb = __float2bfloat16(mxb[j]);
        featT[iA * FT + c0f + lane + 64 * j] = va;
        featT[(iA + 1) * FT + c0f + lane + 64 * j] = vb;
        if (xxout) {
            float pa = b2f(va); sa = fmaf(pa, pa, sa);
            float pb = b2f(vb); sb = fmaf(pb, pb, sb);
        }
    }
    if (xxout) {
#pragma unroll
        for (int off = 32; off >= 1; off >>= 1) {
            sa += __shfl_xor(sa, off);
            sb += __shfl_xor(sb, off);
        }
        if (lane == 0) { xxout[iA] = sa; xxout[iA + 1] = sb; }
    }
}

// ---------------------------------------------------------------------------
// EdgeConv (VALU): fallback path.
template<typename T, int C, int COUT, bool WF>
__global__ __launch_bounds__(256) void k_edgeconv(const T* __restrict__ x, int bstride,
                           const int* __restrict__ idx,
                           const float* __restrict__ Wt,
                           const float* __restrict__ gam,
                           const float* __restrict__ bet,
                           bf16* __restrict__ out, int ostride,
                           bf16* __restrict__ featT, int c0f,
                           float* __restrict__ xxout) {
    const int PT = 4;
    const int OT = COUT / 64;
    const int CP = (C + 3) & ~3;
    __shared__ float sh[PT][KNN + 1][CP];

    int ib = blockIdx.x;
    int b  = ib / (N_PTS / PT);
    int n0 = (ib % (N_PTS / PT)) * PT;
    const T* xb = x + (size_t)b * bstride;

    const int TOT = PT * (KNN + 1) * C;
    for (int t = threadIdx.x; t < TOT; t += 256) {
        int pt = t / ((KNN + 1) * C);
        int r  = t % ((KNN + 1) * C);
        int row = r / C, c = r % C;
        int n = n0 + pt;
        int m = (row == 0) ? n
                           : (idx[((size_t)b * N_PTS + n) * KNN + (row - 1)] & (N_PTS - 1));
        sh[pt][row][c] = ldf(&xb[(size_t)c * N_PTS + m]);
    }
    __syncthreads();

    int w = threadIdx.x >> 6, lane = threadIdx.x & 63;
    int n = n0 + w;

    constexpr int KT = (OT >= 4) ? 10 : 20;
    constexpr int NPASS = KNN / KT;

    float base[OT];
    float mx[OT];
#pragma unroll
    for (int j = 0; j < OT; ++j) { base[j] = 0.f; mx[j] = -FLT_MAX; }

    const float inv = rsqrtf(1.0f + 1e-5f);

#pragma unroll
    for (int pass = 0; pass < NPASS; ++pass) {
        float acc[OT][KT];
#pragma unroll
        for (int j = 0; j < OT; ++j)
#pragma unroll
            for (int k = 0; k < KT; ++k) acc[j][k] = 0.f;

        for (int c = 0; c < C; ++c) {
            float xq = sh[w][0][c];
            float w2v[OT];
#pragma unroll
            for (int j = 0; j < OT; ++j)
                w2v[j] = Wt[(size_t)(C + c) * COUT + lane + 64 * j];
            if (pass == 0) {
#pragma unroll
                for (int j = 0; j < OT; ++j) {
                    float w1v = Wt[(size_t)c * COUT + lane + 64 * j];
                    base[j] = fmaf(w1v - w2v[j], xq, base[j]);
                }
            }
#pragma unroll
            for (int k = 0; k < KT; ++k) {
                float nv = sh[w][1 + pass * KT + k][c];
#pragma unroll
                for (int j = 0; j < OT; ++j) acc[j][k] = fmaf(w2v[j], nv, acc[j][k]);
            }
        }

#pragma unroll
        for (int j = 0; j < OT; ++j) {
            int o = lane + 64 * j;
            float scale = gam[o] * inv, bias = bet[o];
#pragma unroll
            for (int k = 0; k < KT; ++k) {
                float h = (base[j] + acc[j][k]) * scale + bias;
                h = h > 0.f ? h : LRELU_S * h;
                mx[j] = fmaxf(mx[j], h);
            }
        }
    }

    float s = 0.f;
#pragma unroll
    for (int j = 0; j < OT; ++j) {
        int o = lane + 64 * j;
        bf16 bv = __float2bfloat16(mx[j]);
        if (!WF) out[(size_t)b * ostride + (size_t)o * N_PTS + n] = bv;
        if (WF) {
            featT[((size_t)b * N_PTS + n) * FT + c0f + o] = bv;
            float q = b2f(bv);
            s = fmaf(q, q, s);
        }
    }
    if (WF && xxout) {
#pragma unroll
        for (int off = 32; off >= 1; off >>= 1) s += __shfl_xor(s, off);
        if (lane == 0) xxout[(size_t)b * N_PTS + n] = s;
    }
}

// ---------------------------------------------------------------------------
// conv5 via MFMA. Block: 64o x 128n, 4 waves (wave owns 32 n-rows), NPOOL=16
// n-chunks -> 1024 blocks, ~34 KB LDS -> 4 blocks/CU. When inputs are bf16
// (isb), the lo-correction MFMAs and Al staging are skipped (exact).
__global__ __launch_bounds__(256) void k_conv5mfma(
        const bf16* __restrict__ featT, const bf16* __restrict__ w5sp,
        const float* __restrict__ g5, const float* __restrict__ b5,
        float* __restrict__ fmxp, float* __restrict__ fsmp,
        const int* __restrict__ flag) {
    __shared__ __align__(16) short Bt[128 * 64];   // 16 KB
    __shared__ __align__(16) short Ah[64 * 64];    //  8 KB
    __shared__ __align__(16) short Al[64 * 64];    //  8 KB
    __shared__ float rmx[4][64];
    __shared__ float rsm[4][64];

    const int isb = *flag;
    int ib = blockIdx.x;                 // B * 16 * 16
    int b  = ib / 256;
    int rem = ib % 256;
    int o0 = (rem >> 4) * 64;
    int nt = rem & 15;
    int tid = threadIdx.x;
    int w = tid >> 6, lane = tid & 63;
    int l15 = lane & 15, quad = lane >> 4;

    const bf16* Whi = w5sp;
    const bf16* Wlo = w5sp + 1024 * 512;
    const bf16* fb  = featT + (size_t)b * N_PTS * FT;
    const int nbase0 = nt * 128;

    floatx4 acc[4][2];
#pragma unroll
    for (int mi = 0; mi < 4; ++mi)
#pragma unroll
        for (int ni = 0; ni < 2; ++ni) acc[mi][ni] = (floatx4){0.f, 0.f, 0.f, 0.f};

    for (int ck = 0; ck < 512; ck += 64) {
        __syncthreads();
#pragma unroll
        for (int it = 0; it < 4; ++it) {                 // B: 128 rows x 64k
            int s = tid + it * 256;
            int row = s >> 3, seg = s & 7;
            int gseg = seg ^ (row & 7);
            gload16(fb + (size_t)(nbase0 + row) * FT + ck + gseg * 8,
                    &Bt[(s & ~63) * 8]);
        }
#pragma unroll
        for (int it = 0; it < 2; ++it) {                 // A hi(/lo): 64 rows x 64k
            int s = tid + it * 256;
            int row = s >> 3, seg = s & 7;
            int gseg = seg ^ (row & 7);
            gload16(Whi + (size_t)(o0 + row) * 512 + ck + gseg * 8, &Ah[(s & ~63) * 8]);
            if (!isb)
                gload16(Wlo + (size_t)(o0 + row) * 512 + ck + gseg * 8, &Al[(s & ~63) * 8]);
        }
        __syncthreads();
#pragma unroll
        for (int kk = 0; kk < 64; kk += 32) {
            int ks = kk >> 3;
            short8v bfr[2], ah[4], al[4];
#pragma unroll
            for (int ni = 0; ni < 2; ++ni) {
                int row = w * 32 + ni * 16 + l15;
                int seg = (ks + quad) ^ (row & 7);
                bfr[ni] = *(const short8v*)&Bt[row * 64 + seg * 8];
            }
#pragma unroll
            for (int mi = 0; mi < 4; ++mi) {
                int row = mi * 16 + l15;
                int seg = (ks + quad) ^ (row & 7);
                ah[mi] = *(const short8v*)&Ah[row * 64 + seg * 8];
                if (!isb) al[mi] = *(const short8v*)&Al[row * 64 + seg * 8];
            }
#pragma unroll
            for (int mi = 0; mi < 4; ++mi)
#pragma unroll
                for (int ni = 0; ni < 2; ++ni) {
                    acc[mi][ni] = __builtin_amdgcn_mfma_f32_16x16x32_bf16(ah[mi], bfr[ni], acc[mi][ni], 0, 0, 0);
                    if (!isb)
                        acc[mi][ni] = __builtin_amdgcn_mfma_f32_16x16x32_bf16(al[mi], bfr[ni], acc[mi][ni], 0, 0, 0);
                }
        }
    }

    const float inv = rsqrtf(1.0f + 1e-5f);
#pragma unroll
    for (int mi = 0; mi < 4; ++mi) {
#pragma unroll
        for (int r = 0; r < 4; ++r) {
            int o = o0 + mi * 16 + quad * 4 + r;
            float scale = g5[o] * inv, bias = b5[o];
            float mx = -FLT_MAX, sm = 0.f;
#pragma unroll
            for (int ni = 0; ni < 2; ++ni) {
                float h = acc[mi][ni][r] * scale + bias;
                h = h > 0.f ? h : LRELU_S * h;
                mx = fmaxf(mx, h);
                sm += h;
            }
#pragma unroll
            for (int off = 1; off <= 8; off <<= 1) {
                mx = fmaxf(mx, __shfl_xor(mx, off));
                sm += __shfl_xor(sm, off);
            }
            if (l15 == 0) {
                rmx[w][mi * 16 + quad * 4 + r] = mx;
                rsm[w][mi * 16 + quad * 4 + r] = sm;
            }
        }
    }
    __syncthreads();
    if (tid < 64) {
        float mx = -FLT_MAX, sm = 0.f;
#pragma unroll
        for (int ww = 0; ww < 4; ++ww) { mx = fmaxf(mx, rmx[ww][tid]); sm += rsm[ww][tid]; }
        fmxp[((size_t)b * 1024 + o0 + tid) * NPOOL + nt] = mx;
        fsmp[((size_t)b * 1024 + o0 + tid) * NPOOL + nt] = sm;
    }
}

// ---------------------------------------------------------------------------
// Pool partial reduce -> fvec (B, 2048) = [max(1024) | mean(1024)].
__global__ void k_pool(const float* __restrict__ fmxp, const float* __restrict__ fsmp,
                       float* __restrict__ fvec) {
    int i = blockIdx.x * blockDim.x + threadIdx.x;
    if (i >= B_SZ * 1024) return;
    int b = i >> 10, o = i & 1023;
    float mx = -FLT_MAX, sm = 0.f;
    for (int ch = 0; ch < NPOOL; ++ch) {
        mx = fmaxf(mx, fmxp[(size_t)i * NPOOL + ch]);
        sm += fsmp[(size_t)i * NPOOL + ch];
    }
    fvec[(size_t)b * 2048 + o] = mx;
    fvec[(size_t)b * 2048 + 1024 + o] = sm * (1.0f / N_PTS);
}

// ---------------------------------------------------------------------------
// fc1 (raw-dtype weights): block per (b,o).
__global__ __launch_bounds__(256) void k_fc1(const float* __restrict__ fvec,
        const void* __restrict__ fw1, const void* __restrict__ fb1,
        const void* __restrict__ g6,  const void* __restrict__ b6,
        const int* __restrict__ flag, float* __restrict__ tbuf) {
    __shared__ float red[4];
    int ib = blockIdx.x;
    int b = ib >> 9, o = ib & 511;
    const float* fv = fvec + (size_t)b * 2048;
    int tid = threadIdx.x;
    const int isb = *flag;
    float s = 0.f;
    if (isb) {
        const bf16* wr = (const bf16*)fw1 + (size_t)o * 2048;
        for (int j = tid; j < 2048; j += 256) s = fmaf(b2f(wr[j]), fv[j], s);
    } else {
        const float* wr = (const float*)fw1 + (size_t)o * 2048;
        for (int j = tid; j < 2048; j += 256) s = fmaf(wr[j], fv[j], s);
    }
#pragma unroll
    for (int off = 32; off >= 1; off >>= 1) s += __shfl_xor(s, off);
    if ((tid & 63) == 0) red[tid >> 6] = s;
    __syncthreads();
    if (tid == 0) {
        float fb = isb ? b2f(((const bf16*)fb1)[o]) : ((const float*)fb1)[o];
        float gg = isb ? b2f(((const bf16*)g6)[o])  : ((const float*)g6)[o];
        float bb = isb ? b2f(((const bf16*)b6)[o])  : ((const float*)b6)[o];
        float acc = fb + red[0] + red[1] + red[2] + red[3];
        float h = acc * gg * rsqrtf(1.0f + 1e-5f) + bb;
        tbuf[(size_t)b * 512 + o] = h > 0.f ? h : LRELU_S * h;
    }
}

// ---------------------------------------------------------------------------
// fc2 (raw-dtype weights): block per (b,o).
__global__ __launch_bounds__(256) void k_fc2(const float* __restrict__ tbuf,
        const void* __restrict__ fw2, const void* __restrict__ fb2,
        const void* __restrict__ g7,  const void* __restrict__ b7,
        const int* __restrict__ flag, void* __restrict__ out) {
    __shared__ float red[4];
    int ib = blockIdx.x;
    int b = ib >> 8, o = ib & 255;
    const float* tv = tbuf + (size_t)b * 512;
    int tid = threadIdx.x;
    const int isb = *flag;
    float s;
    if (isb) {
        const bf16* wr = (const bf16*)fw2 + (size_t)o * 512;
        s = fmaf(b2f(wr[tid]), tv[tid], b2f(wr[tid + 256]) * tv[tid + 256]);
    } else {
        const float* wr = (const float*)fw2 + (size_t)o * 512;
        s = fmaf(wr[tid], tv[tid], wr[tid + 256] * tv[tid + 256]);
    }
#pragma unroll
    for (int off = 32; off >= 1; off >>= 1) s += __shfl_xor(s, off);
    if ((tid & 63) == 0) red[tid >> 6] = s;
    __syncthreads();
    if (tid == 0) {
        float fb = isb ? b2f(((const bf16*)fb2)[o]) : ((const float*)fb2)[o];
        float gg = isb ? b2f(((const bf16*)g7)[o])  : ((const float*)g7)[o];
        float bb = isb ? b2f(((const bf16*)b7)[o])  : ((const float*)b7)[o];
        float acc = fb + red[0] + red[1] + red[2] + red[3];
        float h = acc * gg * rsqrtf(1.0f + 1e-5f) + bb;
        if (isb) ((bf16*)out)[(size_t)b * 256 + o] = __float2bfloat16(h);
        else     ((float*)out)[(size_t)b * 256 + o] = h;
    }
}

// ---------------------------------------------------------------------------
// Fallback conv5 (VALU) + head, used when ws too small for the gram path.
#define NCH 2
__global__ __launch_bounds__(256) void k_conv5pool(const bf16* __restrict__ feat,
                            const float* __restrict__ w5,
                            const float* __restrict__ g5,
                            const float* __restrict__ b5,
                            float* __restrict__ fmxp, float* __restrict__ fsmp) {
    const int OT = 8;
    const int NT = 4;
    const int CHN = N_PTS / NCH;
    __shared__ float wl[OT][512];
    __shared__ float rmx[4][OT];
    __shared__ float rsm[4][OT];

    int ib = blockIdx.x;
    int ch = ib % NCH;
    int ot = (ib / NCH) % (1024 / OT);
    int b  = ib / (NCH * (1024 / OT));
    int o0 = ot * OT;
    const bf16* fb = feat + (size_t)b * 512 * N_PTS;

    for (int t = threadIdx.x; t < OT * 512; t += 256) {
        int o = t >> 9, c = t & 511;
        wl[o][c] = w5[(size_t)(o0 + o) * 512 + c];
    }
    __syncthreads();

    const int n0 = ch * CHN + threadIdx.x * NT;

    float acc[OT][NT];
#pragma unroll
    for (int o = 0; o < OT; ++o)
#pragma unroll
        for (int t = 0; t < NT; ++t) acc[o][t] = 0.f;

    for (int c = 0; c < 512; c += 4) {
        float fv[4][NT];
#pragma unroll
        for (int j = 0; j < 4; ++j) {
            uint2 u = *(const uint2*)(fb + (size_t)(c + j) * N_PTS + n0);
            fv[j][0] = __uint_as_float(u.x << 16);
            fv[j][1] = __uint_as_float(u.x & 0xFFFF0000u);
            fv[j][2] = __uint_as_float(u.y << 16);
            fv[j][3] = __uint_as_float(u.y & 0xFFFF0000u);
        }
#pragma unroll
        for (int o = 0; o < OT; ++o) {
            float4 wv = *(const float4*)&wl[o][c];
#pragma unroll
            for (int t = 0; t < NT; ++t) {
                acc[o][t] = fmaf(wv.x, fv[0][t], acc[o][t]);
                acc[o][t] = fmaf(wv.y, fv[1][t], acc[o][t]);
                acc[o][t] = fmaf(wv.z, fv[2][t], acc[o][t]);
                acc[o][t] = fmaf(wv.w, fv[3][t], acc[o][t]);
            }
        }
    }

    const float inv = rsqrtf(1.0f + 1e-5f);
    int w = threadIdx.x >> 6, lane = threadIdx.x & 63;
#pragma unroll
    for (int o = 0; o < OT; ++o) {
        float scale = g5[o0 + o] * inv, bias = b5[o0 + o];
        float mx = -FLT_MAX, sm = 0.f;
#pragma unroll
        for (int t = 0; t < NT; ++t) {
            float h = acc[o][t] * scale + bias;
            h = h > 0.f ? h : LRELU_S * h;
            mx = fmaxf(mx, h);
            sm += h;
        }
#pragma unroll
        for (int off = 32; off >= 1; off >>= 1) {
            mx = fmaxf(mx, __shfl_xor(mx, off));
            sm += __shfl_xor(sm, off);
        }
        if (lane == 0) { rmx[w][o] = mx; rsm[w][o] = sm; }
    }
    __syncthreads();
    if (threadIdx.x < OT) {
        int o = threadIdx.x;
        float mx = -FLT_MAX, sm = 0.f;
#pragma unroll
        for (int ww = 0; ww < 4; ++ww) { mx = fmaxf(mx, rmx[ww][o]); sm += rsm[ww][o]; }
        fmxp[((size_t)b * 1024 + o0 + o) * NCH + ch] = mx;
        fsmp[((size_t)b * 1024 + o0 + o) * NCH + ch] = sm;
    }
}

__global__ void k_head(const float* __restrict__ fmxp, const float* __restrict__ fsmp,
                       const float* __restrict__ fw1, const float* __restrict__ fb1,
                       const float* __restrict__ g6,  const float* __restrict__ b6,
                       const float* __restrict__ fw2, const float* __restrict__ fb2,
                       const float* __restrict__ g7,  const float* __restrict__ b7,
                       const int* __restrict__ flag, void* __restrict__ out) {
    __shared__ float f[2048];
    __shared__ float t[512];
    int b = blockIdx.x;
    for (int i = threadIdx.x; i < 1024; i += 256) {
        float mx = -FLT_MAX, sm = 0.f;
        for (int ch = 0; ch < NCH; ++ch) {
            mx = fmaxf(mx, fmxp[((size_t)b * 1024 + i) * NCH + ch]);
            sm += fsmp[((size_t)b * 1024 + i) * NCH + ch];
        }
        f[i]        = mx;
        f[1024 + i] = sm * (1.0f / N_PTS);
    }
    __syncthreads();
    const float inv = rsqrtf(1.0f + 1e-5f);
    for (int o = threadIdx.x; o < 512; o += 256) {
        const float* wr = fw1 + (size_t)o * 2048;
        float acc = fb1[o];
        for (int j = 0; j < 2048; ++j) acc += wr[j] * f[j];
        float h = acc * g6[o] * inv + b6[o];
        t[o] = h > 0.f ? h : LRELU_S * h;
    }
    __syncthreads();
    {
        int o = threadIdx.x;
        const float* wr = fw2 + (size_t)o * 512;
        float acc = fb2[o];
        for (int j = 0; j < 512; ++j) acc += wr[j] * t[j];
        float h = acc * g7[o] * inv + b7[o];
        if (*flag) ((bf16*)out)[(size_t)b * 256 + o] = __float2bfloat16(h);
        else       ((float*)out)[(size_t)b * 256 + o] = h;
    }
}

// ---------------------------------------------------------------------------
extern "C" void kernel_launch(void* const* d_in, const int* in_sizes, int n_in,
                              void* d_out, int out_size, void* d_ws, size_t ws_size,
                              hipStream_t stream) {
    static const int wsz[23] = {
        384, 64, 64,   8192, 64, 64,   16384, 128, 128,   65536, 256, 256,
        524288, 1024, 1024,   1048576, 512,   512, 512,   131072, 256,   256, 256
    };
    static const int trows[23] = {64,0,0, 64,0,0, 128,0,0, 256,0,0, 0,0,0, 0,0, 0,0, 0,0, 0,0};
    static const int tcols[23] = { 6,0,0,128,0,0, 128,0,0, 256,0,0, 0,0,0, 0,0, 0,0, 0,0, 0,0};

    WPack wp;
    int total = 0;
    for (int i = 0; i < 23; ++i) {
        wp.src[i] = d_in[i + 1]; wp.off[i] = total; total += wsz[i];
        wp.rows[i] = trows[i]; wp.cols[i] = tcols[i];
    }
    wp.off[23] = total;

    const size_t flag_bytes = 16;
    const size_t x0_bytes   = (size_t)B_SZ * 3 * N_PTS * 4;
    const size_t feat_bytes = (size_t)B_SZ * 512 * N_PTS * 2;
    const size_t idx_bytes  = (size_t)B_SZ * N_PTS * KNN * 4;
    const size_t pool_bytes = (size_t)B_SZ * 1024 * 4 * 2;
    const size_t wf_bytes   = (size_t)total * 4;
    const size_t base_need  = flag_bytes + x0_bytes + feat_bytes + idx_bytes + pool_bytes + wf_bytes;

    const size_t featT_bytes = (size_t)B_SZ * N_PTS * FT * 2;           //  8 MB
    const size_t xx_bytes    = (size_t)B_SZ * N_PTS * 4;
    const size_t wsp2_elems  = 4 * 64 * 64;
    const size_t wsp3_elems  = 4 * 128 * 64;
    const size_t wsp4_elems  = 4 * 256 * 128;
    const size_t w5sp_elems  = 2 * 1024 * 512;
    const size_t wsp_bytes   = (wsp2_elems + wsp3_elems + wsp4_elems + w5sp_elems) * 2;
    const size_t Yh_bytes    = (size_t)B_SZ * N_PTS * 512 * 2;          //  8 MB (max M2)
    const size_t S_bytes     = (size_t)B_SZ * N_PTS * N_PTS * 2;        // 32 MB fp16 dist
    const size_t full_need   = base_need + featT_bytes + 2 * xx_bytes + wsp_bytes
                             + Yh_bytes + S_bytes;

    if (ws_size < base_need) return;   // graceful fail
    const bool use_gram = (ws_size >= full_need);

    char* w = (char*)d_ws;
    int*   flag = (int*)w;              w += flag_bytes;
    float* x0   = (float*)w;            w += x0_bytes;
    bf16*  feat = (bf16*)w;             w += feat_bytes;
    int*   idx  = (int*)w;              w += idx_bytes;
    w += pool_bytes;
    float* wf   = (float*)w;            w += wf_bytes;
    bf16*  featT = (bf16*)w;            w += featT_bytes;
    float* xxA   = (float*)w;           w += xx_bytes;
    float* xxB   = (float*)w;           w += xx_bytes;
    bf16*  wsp2  = (bf16*)w;            w += wsp2_elems * 2;
    bf16*  wsp3  = (bf16*)w;            w += wsp3_elems * 2;
    bf16*  wsp4  = (bf16*)w;            w += wsp4_elems * 2;
    bf16*  w5sp  = (bf16*)w;            w += w5sp_elems * 2;
    bf16*  Yh    = (bf16*)w;            w += Yh_bytes;
    unsigned short* D = (unsigned short*)w;   // fp16 distance matrix

    // overlays in the idx region (idx unused in gram path):
    // fmxp+fsmp (512K) + fvec (32K) + tbuf (8K) <= idx_bytes (640K)
    float* fmxp = (float*)idx;                               // B*1024*NPOOL
    float* fsmp = fmxp + (size_t)B_SZ * 1024 * NPOOL;        // B*1024*NPOOL
    float* fvec = fsmp + (size_t)B_SZ * 1024 * NPOOL;        // B*2048
    float* tbuf = fvec + (size_t)B_SZ * 2048;                // B*512

    const int FBS = 512 * N_PTS;

    const float* w1t = wf + wp.off[0],  *g1 = wf + wp.off[1],  *b1 = wf + wp.off[2];
    const float* w2t = wf + wp.off[3],  *g2 = wf + wp.off[4],  *b2 = wf + wp.off[5];
    const float* w3t = wf + wp.off[6],  *g3 = wf + wp.off[7],  *b3 = wf + wp.off[8];
    const float* w4t = wf + wp.off[9],  *g4 = wf + wp.off[10], *b4 = wf + wp.off[11];
    const float* w5  = wf + wp.off[12], *g5 = wf + wp.off[13], *b5 = wf + wp.off[14];
    const float* fw1 = wf + wp.off[15], *fb1 = wf + wp.off[16];
    const float* g6  = wf + wp.off[17], *b6 = wf + wp.off[18];
    const float* fw2 = wf + wp.off[19], *fb2 = wf + wp.off[20];
    const float* g7  = wf + wp.off[21], *b7 = wf + wp.off[22];

    const int GK = B_SZ * N_PTS / 4;    // 2048 blocks
    const int G8 = B_SZ * N_PTS / 8;    // 1024 blocks (2 queries/wave kernels)
    const int NG = B_SZ * 256;          // gram blocks in k_gx

    if (use_gram) {
        const int rlimit = wp.off[15];
        const int nbrep = (rlimit + 255) / 256;
        const int prep_grid = nbrep + 16 + 32 + 128 + 2048 + 32;
        k_prep<<<prep_grid, 256, 0, stream>>>(wp, wf, rlimit,
                                              d_in[4], wsp2, d_in[7], wsp3,
                                              d_in[10], wsp4, d_in[13], w5sp,
                                              d_in[0], x0, flag);

        // layer 1: fused kNN + EdgeConv (writes featT[0:64) + xxA)
        k_knn3ec<<<G8, 256, 0, stream>>>(x0, w1t, g1, b1, featT, xxA);
        // layer 2
        k_gx<64, 64><<<NG + 64, 256, 0, stream>>>(featT, 0, wsp2, xxA, D, Yh, flag);
        k_selgmax<64><<<G8, 256, 0, stream>>>(D, Yh, g2, b2, featT, 64, xxB);
        // layer 3
        k_gx<64, 128><<<NG + 128, 256, 0, stream>>>(featT, 64, wsp3, xxB, D, Yh, flag);
        k_selgmax<128><<<G8, 256, 0, stream>>>(D, Yh, g3, b3, featT, 128, xxA);
        // layer 4 (writes featT channels [256,512) for conv5)
        k_gx<128, 256><<<NG + 256, 256, 0, stream>>>(featT, 128, wsp4, xxA, D, Yh, flag);
        k_selgmax<256><<<G8, 256, 0, stream>>>(D, Yh, g4, b4, featT, 256, nullptr);

        // conv5 MFMA + pooling partials, then head GEMVs (raw fc weights)
        k_conv5mfma<<<B_SZ * 256, 256, 0, stream>>>(featT, w5sp, g5, b5, fmxp, fsmp, flag);
        k_pool<<<(B_SZ * 1024 + 255) / 256, 256, 0, stream>>>(fmxp, fsmp, fvec);
        k_fc1<<<B_SZ * 512, 256, 0, stream>>>(fvec, d_in[16], d_in[17], d_in[18], d_in[19],
                                              flag, tbuf);
        k_fc2<<<B_SZ * 256, 256, 0, stream>>>(tbuf, d_in[20], d_in[21], d_in[22], d_in[23],
                                              flag, d_out);
    } else {
        k_sniff<<<1, 64, 0, stream>>>((const unsigned short*)d_in[0], flag);
        k_repack<<<(total + 255) / 256, 256, 0, stream>>>(wp, flag, wf, total);
        k_transpose<<<(B_SZ * N_PTS + 255) / 256, 256, 0, stream>>>(d_in[0], flag, x0);

        k_knn<float, 3><<<GK, 256, 0, stream>>>(x0, 3 * N_PTS, idx);
        k_edgeconv<float, 3, 64, false><<<GK, 256, 0, stream>>>(
            x0, 3 * N_PTS, idx, w1t, g1, b1, feat + 0 * N_PTS, FBS, nullptr, 0, nullptr);
        k_knn<bf16, 64><<<GK, 256, 0, stream>>>(feat + 0 * N_PTS, FBS, idx);
        k_edgeconv<bf16, 64, 64, false><<<GK, 256, 0, stream>>>(
            feat + 0 * N_PTS, FBS, idx, w2t, g2, b2, feat + 64 * N_PTS, FBS, nullptr, 0, nullptr);
        k_knn<bf16, 64><<<GK, 256, 0, stream>>>(feat + 64 * N_PTS, FBS, idx);
        k_edgeconv<bf16, 64, 128, false><<<GK, 256, 0, stream>>>(
            feat + 64 * N_PTS, FBS, idx, w3t, g3, b3, feat + 128 * N_PTS, FBS, nullptr, 0, nullptr);
        k_knn<bf16, 128><<<GK, 256, 0, stream>>>(feat + 128 * N_PTS, FBS, idx);
        k_edgeconv<bf16, 128, 256, false><<<GK, 256, 0, stream>>>(
            feat + 128 * N_PTS, FBS, idx, w4t, g4, b4, feat + 256 * N_PTS, FBS, nullptr, 0, nullptr);

        k_conv5pool<<<B_SZ * (1024 / 8) * NCH, 256, 0, stream>>>(feat, w5, g5, b5, fmxp, fsmp);
        k_head<<<B_SZ, 256, 0, stream>>>(fmxp, fsmp, fw1, fb1, g6, b6, fw2, fb2, g7, b7,
                                         flag, d_out);
    }
}

// Round 12
// 323.455 us; speedup vs baseline: 1.0902x; 1.0093x over previous
//
#include <hip/hip_runtime.h>
#include <hip/hip_bf16.h>
#include <float.h>

#define N_PTS 2048
#define B_SZ  4
#define KNN   20
#define LRELU_S 0.2f
#define FT    512          // featT row stride (channels)
#define NPOOL 16           // conv5 n-chunk partials (128 rows each)
#define NTRI  136          // 16*17/2 upper-triangle tiles per batch

typedef __hip_bfloat16 bf16;
typedef __attribute__((ext_vector_type(8))) short short8v;   // 8 bf16 (4 VGPRs)
typedef __attribute__((ext_vector_type(4))) short short4v;   // 4 bf16
typedef __attribute__((ext_vector_type(4))) float floatx4;

__device__ __forceinline__ float b2f(const bf16 v) { return __bfloat162float(v); }
__device__ __forceinline__ float ldf(const float* p) { return *p; }
__device__ __forceinline__ float ldf(const bf16* p)  { return __bfloat162float(*p); }
__device__ __forceinline__ short8v ld8(const bf16* p) { return *(const short8v*)p; }
__device__ __forceinline__ unsigned umin(unsigned a, unsigned b) { return a < b ? a : b; }
__device__ __forceinline__ short bfbits(float f) {
    bf16 t = __float2bfloat16(f);
    return *reinterpret_cast<short*>(&t);
}
// fp16 <-> fp32 via _Float16 (RNE convert, single v_cvt instruction).
__device__ __forceinline__ unsigned short f2h(float f) {
    _Float16 h = (_Float16)f;
    return *reinterpret_cast<unsigned short*>(&h);
}
__device__ __forceinline__ float h2f(unsigned short u) {
    _Float16 h;
    *reinterpret_cast<unsigned short*>(&h) = u;
    return (float)h;
}

// Direct global->LDS DMA, 16 B per lane. LDS dest is wave-uniform base +
// lane*16 (linear); swizzling is achieved by pre-swizzling the GLOBAL source
// address (rule: both-sides-or-neither).
__device__ __forceinline__ void gload16(const void* g, void* l) {
    __builtin_amdgcn_global_load_lds(
        (const __attribute__((address_space(1))) void*)g,
        (__attribute__((address_space(3))) void*)l, 16, 0, 0);
}

// ---------------------------------------------------------------------------
// Dtype sniffer: bf16 (flag=1) vs fp32 (flag=0). Reads 256 B.
__device__ __forceinline__ int sniff_body(const unsigned short* pts_hw) {
    int sane = 0;
    for (int j = 0; j < 64; ++j) {
        unsigned short v = pts_hw[2 * j];
        int e = (v >> 7) & 0xFF;
        if (e >= 100 && e <= 140) ++sane;
    }
    return (sane >= 32) ? 1 : 0;
}

__global__ void k_sniff(const unsigned short* __restrict__ pts_hw, int* __restrict__ flag) {
    if (threadIdx.x != 0 || blockIdx.x != 0) return;
    *flag = sniff_body(pts_hw);
}

// ---------------------------------------------------------------------------
// Weight repack metadata.
struct WPack {
    const void* src[23];
    int off[24];
    int rows[23];
    int cols[23];
};

__device__ __forceinline__ void repack_body(const WPack& wp, int isb,
                                            float* __restrict__ dst, int i, int limit,
                                            int skip12) {
    if (i >= limit) return;
    int lo = 0, hi = 23;
    while (lo + 1 < hi) { int mid = (lo + hi) >> 1; if (i >= wp.off[mid]) lo = mid; else hi = mid; }
    if (skip12 && lo == 12) return;    // gram path reads w5 only via w5sp
    int j = i - wp.off[lo];
    float v = isb ? b2f(((const bf16*)wp.src[lo])[j]) : ((const float*)wp.src[lo])[j];
    int dj = j;
    int cols = wp.cols[lo];
    if (cols) dj = (j % cols) * wp.rows[lo] + (j / cols);
    dst[wp.off[lo] + dj] = v;
}

// Split EdgeConv weights into bf16 hi/lo pairs for MFMA:
// dst = [W2hi | W2lo | Wdhi | Wdlo], each (COUT, C) row-major, Wd = W1 - W2.
template<int C, int COUT>
__device__ __forceinline__ void wsplit_body(const void* __restrict__ W, int isb,
                                            bf16* __restrict__ dst, int i) {
    if (i >= COUT * C) return;
    int o = i / C, c = i % C;
    float w1 = isb ? b2f(((const bf16*)W)[(size_t)o * 2 * C + c])
                   : ((const float*)W)[(size_t)o * 2 * C + c];
    float w2 = isb ? b2f(((const bf16*)W)[(size_t)o * 2 * C + C + c])
                   : ((const float*)W)[(size_t)o * 2 * C + C + c];
    float wd = w1 - w2;
    bf16 h2 = __float2bfloat16(w2);
    bf16 hd = __float2bfloat16(wd);
    dst[i]                = h2;
    dst[COUT * C + i]     = __float2bfloat16(w2 - b2f(h2));
    dst[2 * COUT * C + i] = hd;
    dst[3 * COUT * C + i] = __float2bfloat16(wd - b2f(hd));
}

// Split conv5 weights (1024x512) into bf16 hi/lo: dst = [hi | lo].
// When inputs are bf16 the lo plane is identically zero and never read.
__device__ __forceinline__ void w5split_body(const void* __restrict__ W, int isb,
                                             bf16* __restrict__ dst, int i) {
    if (i >= 1024 * 512) return;
    float w = isb ? b2f(((const bf16*)W)[i]) : ((const float*)W)[i];
    bf16 h = __float2bfloat16(w);
    dst[i] = h;
    if (!isb) dst[1024 * 512 + i] = __float2bfloat16(w - b2f(h));
}

// points (B,N,3) -> x0 (B,3,N) fp32, dtype-dynamic.
__device__ __forceinline__ void transpose_body(const void* __restrict__ pts, int isb,
                                               float* __restrict__ x0, int i) {
    if (i >= B_SZ * N_PTS) return;
    int b = i / N_PTS, n = i % N_PTS;
    for (int c = 0; c < 3; ++c) {
        size_t s = ((size_t)b * N_PTS + n) * 3 + c;
        float v = isb ? b2f(((const bf16*)pts)[s]) : ((const float*)pts)[s];
        x0[((size_t)b * 3 + c) * N_PTS + n] = v;
    }
}

// Merged prep (gram path): self-sniff + repack + 3x wsplit + w5split +
// transpose in one launch, dispatched by blockIdx range.
__global__ void k_prep(WPack wp, float* __restrict__ wf, int rlimit,
                       const void* __restrict__ w2s, bf16* __restrict__ wsp2,
                       const void* __restrict__ w3s, bf16* __restrict__ wsp3,
                       const void* __restrict__ w4s, bf16* __restrict__ wsp4,
                       const void* __restrict__ w5s, bf16* __restrict__ w5sp,
                       const void* __restrict__ pts, float* __restrict__ x0,
                       int* __restrict__ flagout) {
    __shared__ int sfl;
    if (threadIdx.x == 0) {
        int f = sniff_body((const unsigned short*)pts);
        sfl = f;
        if (blockIdx.x == 0) *flagout = f;
    }
    __syncthreads();
    const int isb = sfl;
    const int nbrep = (rlimit + 255) >> 8;
    int ib = blockIdx.x, t = threadIdx.x;
    if (ib < nbrep) { repack_body(wp, isb, wf, ib * 256 + t, rlimit, 1); return; }
    ib -= nbrep;
    if (ib < 16)   { wsplit_body<64, 64>(w2s, isb, wsp2, ib * 256 + t); return; }
    ib -= 16;
    if (ib < 32)   { wsplit_body<64, 128>(w3s, isb, wsp3, ib * 256 + t); return; }
    ib -= 32;
    if (ib < 128)  { wsplit_body<128, 256>(w4s, isb, wsp4, ib * 256 + t); return; }
    ib -= 128;
    if (ib < 2048) { w5split_body(w5s, isb, w5sp, ib * 256 + t); return; }
    ib -= 2048;
    transpose_body(pts, isb, x0, ib * 256 + t);
}

// Standalone versions for the fallback path.
__global__ void k_repack(WPack wp, const int* __restrict__ flag, float* __restrict__ dst, int limit) {
    repack_body(wp, *flag, dst, blockIdx.x * blockDim.x + threadIdx.x, limit, 0);
}
__global__ void k_transpose(const void* __restrict__ pts, const int* __restrict__ flag,
                            float* __restrict__ x0) {
    transpose_body(pts, *flag, x0, blockIdx.x * blockDim.x + threadIdx.x);
}

// ---------------------------------------------------------------------------
// 32-candidate row loads (lane chunk), fp32 out.
__device__ __forceinline__ void load32(const float* row, int mbase, float* r) {
    const float4* p = (const float4*)(row + mbase);
#pragma unroll
    for (int i = 0; i < 8; ++i) {
        float4 f = p[i];
        r[4 * i + 0] = f.x; r[4 * i + 1] = f.y; r[4 * i + 2] = f.z; r[4 * i + 3] = f.w;
    }
}
__device__ __forceinline__ void load32(const bf16* row, int mbase, float* r) {
    const uint4* p = (const uint4*)(row + mbase);
#pragma unroll
    for (int i = 0; i < 4; ++i) {
        uint4 u = p[i];
        r[8 * i + 0] = __uint_as_float(u.x << 16);
        r[8 * i + 1] = __uint_as_float(u.x & 0xFFFF0000u);
        r[8 * i + 2] = __uint_as_float(u.y << 16);
        r[8 * i + 3] = __uint_as_float(u.y & 0xFFFF0000u);
        r[8 * i + 4] = __uint_as_float(u.z << 16);
        r[8 * i + 5] = __uint_as_float(u.z & 0xFFFF0000u);
        r[8 * i + 6] = __uint_as_float(u.w << 16);
        r[8 * i + 7] = __uint_as_float(u.w & 0xFFFF0000u);
    }
}

// ---------------------------------------------------------------------------
// Packed-key top-20 for two queries per wave, cached per-lane sorted top-2.
__device__ __forceinline__ void s2ins(unsigned k, unsigned& m1, unsigned& m2) {
    unsigned lo = umin(m1, k);
    unsigned hi = (m1 < k) ? k : m1;
    m1 = lo;
    m2 = umin(m2, hi);
}

__device__ __forceinline__ void select20x2(const unsigned* ka, const unsigned* kb,
                                           int* outA, int* outB, int lane) {
    const unsigned SENT = 0xFFFFFFFFu;
    unsigned a1 = SENT, a2 = SENT, b1 = SENT, b2 = SENT;
#pragma unroll
    for (int j = 0; j < 32; ++j) {
        s2ins(ka[j], a1, a2);
        s2ins(kb[j], b1, b2);
    }
#pragma unroll 1
    for (int k = 0; k < KNN; ++k) {
        unsigned va = a1, vb = b1;
#pragma unroll
        for (int off = 32; off >= 1; off >>= 1) {
            va = umin(va, (unsigned)__shfl_xor((int)va, off));
            vb = umin(vb, (unsigned)__shfl_xor((int)vb, off));
        }
        if (lane == 0) { outA[k] = (int)(va & 2047u); outB[k] = (int)(vb & 2047u); }
        if (a1 == va) { a1 = a2; a2 = SENT; }
        if (b1 == vb) { b1 = b2; b2 = SENT; }
        if (a1 == SENT) {
#pragma unroll
            for (int j = 0; j < 32; ++j) {
                unsigned t = (ka[j] > va) ? ka[j] : SENT;
                s2ins(t, a1, a2);
            }
        }
        if (b1 == SENT) {
#pragma unroll
            for (int j = 0; j < 32; ++j) {
                unsigned t = (kb[j] > vb) ? kb[j] : SENT;
                s2ins(t, b1, b2);
            }
        }
    }
}

// ---------------------------------------------------------------------------
// Fused layer-1: kNN (C=3, fp32, packed keys) + EdgeConv (C=3 -> 64) for the
// same 8 points. Select into LDS sidx, cooperative neighbor staging into LDS,
// then 2 points/wave, lane = channel.
__global__ __launch_bounds__(256) void k_knn3ec(const float* __restrict__ x0,
        const float* __restrict__ Wt, const float* __restrict__ gam,
        const float* __restrict__ bet, bf16* __restrict__ featT,
        float* __restrict__ xxout) {
    __shared__ float qf[8][3];
    __shared__ int sidx[8][KNN];
    __shared__ float sh[8][KNN][3];
    int ib = blockIdx.x;
    int b  = ib / (N_PTS / 8);
    int q0 = (ib % (N_PTS / 8)) * 8;
    const float* xb = x0 + (size_t)b * 3 * N_PTS;

    if (threadIdx.x < 24) {
        int q = threadIdx.x / 3, c = threadIdx.x % 3;
        qf[q][c] = xb[(size_t)c * N_PTS + q0 + q];
    }
    __syncthreads();

    int w = threadIdx.x >> 6, lane = threadIdx.x & 63;
    int mbase = lane * 32;

    float da[32], db[32];
#pragma unroll
    for (int j = 0; j < 32; ++j) { da[j] = 0.f; db[j] = 0.f; }
#pragma unroll
    for (int c = 0; c < 3; ++c) {
        float r[32];
        load32(xb + (size_t)c * N_PTS, mbase, r);
        float qac = qf[2 * w][c], qbc = qf[2 * w + 1][c];
#pragma unroll
        for (int j = 0; j < 32; ++j) {
            float ta = r[j] - qac; da[j] = fmaf(ta, ta, da[j]);
            float tb = r[j] - qbc; db[j] = fmaf(tb, tb, db[j]);
        }
    }
    unsigned ka[32], kb[32];
#pragma unroll
    for (int j = 0; j < 32; ++j) {
        ka[j] = (__float_as_uint(da[j]) & 0xFFFFF800u) | (unsigned)(mbase + j);
        kb[j] = (__float_as_uint(db[j]) & 0xFFFFF800u) | (unsigned)(mbase + j);
    }
    select20x2(ka, kb, &sidx[2 * w][0], &sidx[2 * w + 1][0], lane);
    __syncthreads();

    // ---- cooperative neighbor staging: 480 parallel loads (2/thread) ----
    for (int t = threadIdx.x; t < 8 * KNN * 3; t += 256) {
        int pt = t / (KNN * 3);
        int r  = t % (KNN * 3);
        int k = r / 3, c = r % 3;
        int m = sidx[pt][k] & (N_PTS - 1);
        sh[pt][k][c] = xb[(size_t)c * N_PTS + m];
    }
    __syncthreads();

    // ---- EdgeConv phase: points q0+2w, q0+2w+1; lane owns channel `lane` ----
    const float inv = rsqrtf(1.0f + 1e-5f);
    float scale = gam[lane] * inv, bias = bet[lane];
    float w1v[3], w2v[3];
#pragma unroll
    for (int c = 0; c < 3; ++c) {
        w1v[c] = Wt[(size_t)c * 64 + lane];
        w2v[c] = Wt[(size_t)(3 + c) * 64 + lane];
    }
#pragma unroll
    for (int p = 0; p < 2; ++p) {
        int pt = 2 * w + p;
        float base = 0.f;
#pragma unroll
        for (int c = 0; c < 3; ++c) base = fmaf(w1v[c] - w2v[c], qf[pt][c], base);
        float mx = -FLT_MAX;
#pragma unroll
        for (int k = 0; k < KNN; ++k) {
            float acc = 0.f;
#pragma unroll
            for (int c = 0; c < 3; ++c) acc = fmaf(w2v[c], sh[pt][k][c], acc);
            float h = (base + acc) * scale + bias;
            h = h > 0.f ? h : LRELU_S * h;
            mx = fmaxf(mx, h);
        }
        bf16 bv = __float2bfloat16(mx);
        size_t i = (size_t)b * N_PTS + q0 + pt;
        featT[i * FT + lane] = bv;
        float qv = b2f(bv);
        float s = qv * qv;
#pragma unroll
        for (int off = 32; off >= 1; off >>= 1) s += __shfl_xor(s, off);
        if (lane == 0) xxout[i] = s;
    }
}

// ---------------------------------------------------------------------------
// kNN (direct, fallback path): wave-per-query.
template<typename T, int C>
__global__ __launch_bounds__(256) void k_knn(const T* __restrict__ x, int bstride,
                                             int* __restrict__ idx) {
    __shared__ float qf[4][C];
    int ib = blockIdx.x;
    int b  = ib / (N_PTS / 4);
    int q0 = (ib % (N_PTS / 4)) * 4;
    const T* xb = x + (size_t)b * bstride;

    for (int t = threadIdx.x; t < 4 * C; t += 256) {
        int pt = t / C, c = t % C;
        qf[pt][c] = ldf(&xb[(size_t)c * N_PTS + (q0 + pt)]);
    }
    __syncthreads();

    int w = threadIdx.x >> 6, lane = threadIdx.x & 63;
    int q = q0 + w;
    int mbase = lane * 32;

    float v[32];
#pragma unroll
    for (int j = 0; j < 32; ++j) v[j] = 0.f;

    for (int c = 0; c < C; ++c) {
        float qc = qf[w][c];
        float r[32];
        load32(xb + (size_t)c * N_PTS, mbase, r);
#pragma unroll
        for (int j = 0; j < 32; ++j) { float t = r[j] - qc; v[j] = fmaf(t, t, v[j]); }
    }

    for (int k = 0; k < KNN; ++k) {
        float bv = FLT_MAX; int bi = 0x7FFFFFFF;
#pragma unroll
        for (int j = 0; j < 32; ++j)
            if (v[j] < bv) { bv = v[j]; bi = mbase + j; }
#pragma unroll
        for (int off = 32; off >= 1; off >>= 1) {
            float ov = __shfl_xor(bv, off);
            int   oi = __shfl_xor(bi, off);
            if (ov < bv || (ov == bv && oi < bi)) { bv = ov; bi = oi; }
        }
        if (lane == 0) idx[((size_t)b * N_PTS + q) * KNN + k] = bi;
        int wl = bi >> 5, wj = bi & 31;
        if (lane == wl) {
#pragma unroll
            for (int j = 0; j < 32; ++j) if (j == wj) v[j] = FLT_MAX;
        }
    }
}

// ---------------------------------------------------------------------------
// Gram body via MFMA, fused symmetric distance epilogue. Only the upper
// triangle of the 16x16 tile grid is computed (dist is symmetric):
// d = fmaf(-2, G, xx[m] + xx[n]) is bit-symmetric (fp32 + is commutative,
// MFMA G[n][m]==G[m][n] exactly). Off-diagonal tiles write BOTH orientations
// from the same accumulators via a second LDS staging pass. Stores are fp16,
// staged in LDS (16B-granule XOR swizzle) and streamed out coalesced.
template<int C>
__device__ __forceinline__ void gram_body(const bf16* __restrict__ featT, int c0,
                                          const float* __restrict__ xx,
                                          unsigned short* __restrict__ D,
                                          short* lds, int ib) {
    const int KC = 64;
    short* At = lds;
    short* Bt = lds + 128 * 64;
    int b = ib / NTRI;
    int t = ib % NTRI;
    int ti = 0;
    while (t >= 16 - ti) { t -= 16 - ti; ++ti; }
    int tj = ti + t;
    int n0 = ti << 7;
    int m0 = tj << 7;

    int tid = threadIdx.x;
    int w = tid >> 6, lane = tid & 63;
    int rw = (w & 1) * 64, cw = (w >> 1) * 64;
    int lrow = lane & 15, quad = lane >> 4;

    floatx4 acc[4][4];
#pragma unroll
    for (int ri = 0; ri < 4; ++ri)
#pragma unroll
        for (int ci = 0; ci < 4; ++ci) acc[ri][ci] = (floatx4){0.f, 0.f, 0.f, 0.f};

    for (int ck = 0; ck < C; ck += KC) {
        __syncthreads();
#pragma unroll
        for (int it = 0; it < 4; ++it) {
            int s = tid + it * 256;
            int row = s >> 3, seg = s & 7;
            int gseg = seg ^ (row & 7);
            gload16(featT + ((size_t)(b * N_PTS + n0 + row) * FT) + c0 + ck + gseg * 8,
                    &At[(s & ~63) * 8]);
            gload16(featT + ((size_t)(b * N_PTS + m0 + row) * FT) + c0 + ck + gseg * 8,
                    &Bt[(s & ~63) * 8]);
        }
        __syncthreads();
#pragma unroll
        for (int kk = 0; kk < KC; kk += 32) {
            int ks = kk >> 3;
            short8v a[4], bb[4];
#pragma unroll
            for (int ri = 0; ri < 4; ++ri) {
                int row = rw + ri * 16 + lrow;
                int seg = (ks + quad) ^ (row & 7);
                a[ri] = *(const short8v*)&At[row * 64 + seg * 8];
            }
#pragma unroll
            for (int ci = 0; ci < 4; ++ci) {
                int row = cw + ci * 16 + lrow;
                int seg = (ks + quad) ^ (row & 7);
                bb[ci] = *(const short8v*)&Bt[row * 64 + seg * 8];
            }
#pragma unroll
            for (int ri = 0; ri < 4; ++ri)
#pragma unroll
                for (int ci = 0; ci < 4; ++ci)
                    acc[ri][ci] = __builtin_amdgcn_mfma_f32_16x16x32_bf16(a[ri], bb[ci], acc[ri][ci], 0, 0, 0);
        }
    }

    const float* xr = xx + (size_t)b * N_PTS;
    float xmv[4];
#pragma unroll
    for (int ci = 0; ci < 4; ++ci)
        xmv[ci] = xr[m0 + cw + ci * 16 + lrow];
    float xnv[4][4];
#pragma unroll
    for (int ri = 0; ri < 4; ++ri)
#pragma unroll
        for (int reg = 0; reg < 4; ++reg)
            xnv[ri][reg] = xr[n0 + rw + ri * 16 + quad * 4 + reg];

    // pass 1: stage rows=n / cols=m, stream out D[n0..][m0..]
    __syncthreads();                       // staging LDS is dead now
    unsigned short* dl = (unsigned short*)lds;   // 128x128 fp16 = 32 KB
#pragma unroll
    for (int ri = 0; ri < 4; ++ri)
#pragma unroll
        for (int ci = 0; ci < 4; ++ci) {
            int ml = cw + ci * 16 + lrow;
#pragma unroll
            for (int reg = 0; reg < 4; ++reg) {
                int nl = rw + ri * 16 + quad * 4 + reg;
                float d = fmaf(-2.f, acc[ri][ci][reg], xmv[ci] + xnv[ri][reg]);
                d = fmaxf(d, 0.f);
                int col = (((ml >> 3) ^ (nl & 15)) << 3) + (ml & 7);
                dl[nl * 128 + col] = f2h(d);
            }
        }
    __syncthreads();
    {
        unsigned short* Drow = D + ((size_t)b * N_PTS + n0) * N_PTS + m0;
#pragma unroll
        for (int it = 0; it < 8; ++it) {
            int ch = tid + it * 256;
            int row = ch >> 4;
            int c8 = (ch & 15) * 8;
            int g  = (((c8 >> 3) ^ (row & 15)) << 3);
            *(uint4*)(Drow + (size_t)row * N_PTS + c8) = *(const uint4*)(dl + row * 128 + g);
        }
    }

    if (ti == tj) return;

    // pass 2: stage rows=m / cols=n, stream out D[m0..][n0..] (mirror)
    __syncthreads();
#pragma unroll
    for (int ri = 0; ri < 4; ++ri)
#pragma unroll
        for (int ci = 0; ci < 4; ++ci) {
            int ml = cw + ci * 16 + lrow;
#pragma unroll
            for (int reg = 0; reg < 4; ++reg) {
                int nl = rw + ri * 16 + quad * 4 + reg;
                float d = fmaf(-2.f, acc[ri][ci][reg], xmv[ci] + xnv[ri][reg]);
                d = fmaxf(d, 0.f);
                int col = (((nl >> 3) ^ (ml & 15)) << 3) + (nl & 7);
                dl[ml * 128 + col] = f2h(d);
            }
        }
    __syncthreads();
    {
        unsigned short* Drow = D + ((size_t)b * N_PTS + m0) * N_PTS + n0;
#pragma unroll
        for (int it = 0; it < 8; ++it) {
            int ch = tid + it * 256;
            int row = ch >> 4;
            int c8 = (ch & 15) * 8;
            int g  = (((c8 >> 3) ^ (row & 15)) << 3);
            *(uint4*)(Drow + (size_t)row * N_PTS + c8) = *(const uint4*)(dl + row * 128 + g);
        }
    }
}

// ---------------------------------------------------------------------------
// Xform body via MFMA, bf16 output, LDS-staged coalesced writes.
// When inputs are bf16 (isb), the W2 lo-correction is identically zero ->
// skip those MFMAs (exact).
template<int COUT, int C>
__device__ __forceinline__ void xform_body(const bf16* __restrict__ featT, int c0,
                                           const bf16* __restrict__ Wsp,
                                           bf16* __restrict__ Yh, int isb,
                                           short* lds, int ib2) {
    const int M2 = 2 * COUT;
    const int KC = 64;
    short* Bt = lds;
    int nt = ib2 & 63;
    int mt = ib2 >> 6;
    int tid = threadIdx.x;
    int w = tid >> 6, lane = tid & 63;
    int rw = (w & 1) * 64, cw = (w >> 1) * 64;
    int l15 = lane & 15, quad = lane >> 4;

    floatx4 acc[4][4];
#pragma unroll
    for (int ri = 0; ri < 4; ++ri)
#pragma unroll
        for (int ci = 0; ci < 4; ++ci) acc[ri][ci] = (floatx4){0.f, 0.f, 0.f, 0.f};

    for (int ck = 0; ck < C; ck += KC) {
        __syncthreads();
#pragma unroll
        for (int it = 0; it < 4; ++it) {
            int s = tid + it * 256;
            int row = s >> 3, seg = s & 7;
            int gseg = seg ^ (row & 7);
            gload16(featT + (size_t)(nt * 128 + row) * FT + c0 + ck + gseg * 8,
                    &Bt[(s & ~63) * 8]);
        }
        __syncthreads();
#pragma unroll
        for (int kk = 0; kk < KC; kk += 32) {
            int ks = kk >> 3;
            short8v bfr[4];
#pragma unroll
            for (int ci = 0; ci < 4; ++ci) {
                int row = cw + ci * 16 + l15;
                int seg = (ks + quad) ^ (row & 7);
                bfr[ci] = *(const short8v*)&Bt[row * 64 + seg * 8];
            }
#pragma unroll
            for (int ri = 0; ri < 4; ++ri) {
                int rbase = mt * 128 + rw + ri * 16;          // band-aligned, lane-uniform
                bool uselo = (!isb) || (rbase >= COUT);       // W2 lo==0 when bf16 input
                int mrow = rbase + l15;
                int base = (mrow < COUT) ? mrow : (mrow + COUT);
                const bf16* hi = Wsp + (size_t)base * C + ck + kk + quad * 8;
                short8v ah = ld8(hi);
                short8v al;
                if (uselo) al = ld8(hi + (size_t)COUT * C);
#pragma unroll
                for (int ci = 0; ci < 4; ++ci) {
                    acc[ri][ci] = __builtin_amdgcn_mfma_f32_16x16x32_bf16(ah, bfr[ci], acc[ri][ci], 0, 0, 0);
                    if (uselo)
                        acc[ri][ci] = __builtin_amdgcn_mfma_f32_16x16x32_bf16(al, bfr[ci], acc[ri][ci], 0, 0, 0);
                }
            }
        }
    }

    // stage bf16 tile (rows = n local, cols = m local) in LDS, swizzled
    __syncthreads();
#pragma unroll
    for (int ri = 0; ri < 4; ++ri)
#pragma unroll
        for (int ci = 0; ci < 4; ++ci) {
            int nl = cw + ci * 16 + l15;
            int ml = rw + ri * 16 + quad * 4;
            short4v o4;
            o4[0] = bfbits(acc[ri][ci][0]);
            o4[1] = bfbits(acc[ri][ci][1]);
            o4[2] = bfbits(acc[ri][ci][2]);
            o4[3] = bfbits(acc[ri][ci][3]);
            int col = (((ml >> 3) ^ (nl & 15)) << 3) + (ml & 7);
            *(short4v*)&lds[nl * 128 + col] = o4;
        }
    __syncthreads();
    short* Ybase = (short*)Yh + (size_t)(nt * 128) * M2 + mt * 128;
#pragma unroll
    for (int it = 0; it < 8; ++it) {
        int ch = tid + it * 256;
        int row = ch >> 4;
        int c8 = (ch & 15) * 8;
        int g  = (((c8 >> 3) ^ (row & 15)) << 3);
        *(uint4*)(Ybase + (size_t)row * M2 + c8) = *(const uint4*)(lds + row * 128 + g);
    }
}

// ---------------------------------------------------------------------------
// Merged gram + xform: first B_SZ*NTRI blocks do the (upper-triangle) gram
// tiles, the trailing COUT blocks do the dense point transform.
template<int C, int COUT>
__global__ __launch_bounds__(256) void k_gx(const bf16* __restrict__ featT, int c0,
        const bf16* __restrict__ Wsp, const float* __restrict__ xx,
        unsigned short* __restrict__ D, bf16* __restrict__ Yh,
        const int* __restrict__ flag) {
    __shared__ __align__(16) short lds[2 * 128 * 64];   // 32 KB
    int ib = blockIdx.x;
    if (ib < B_SZ * NTRI) {
        gram_body<C>(featT, c0, xx, D, lds, ib);
    } else {
        xform_body<COUT, C>(featT, c0, Wsp, Yh, *flag, lds, ib - B_SZ * NTRI);
    }
}

// ---------------------------------------------------------------------------
// Merged select + gather-max: block = 8 queries. Phase 1 builds top-20 keys
// straight from the precomputed fp16 distance rows (no xx loads, no fmaf);
// phase 2 does the gather-max epilogue (2 pts/wave) reading bf16 Y, writes
// featT and next-layer xx.
template<int COUT>
__global__ __launch_bounds__(256) void k_selgmax(const unsigned short* __restrict__ D,
        const bf16* __restrict__ Yh,
        const float* __restrict__ gam, const float* __restrict__ bet,
        bf16* __restrict__ featT, int c0f, float* __restrict__ xxout) {
    const int M2 = 2 * COUT;
    const int OT = COUT / 64;
    __shared__ int sidx[8][KNN];

    int ib = blockIdx.x;
    int b  = ib / (N_PTS / 8);
    int q0 = (ib % (N_PTS / 8)) * 8;
    int w = threadIdx.x >> 6, lane = threadIdx.x & 63;
    int qa = q0 + 2 * w;
    const unsigned short* gA = D + ((size_t)b * N_PTS + qa) * N_PTS;
    const unsigned short* gB = gA + N_PTS;

    unsigned ka[32], kb[32];
#pragma unroll
    for (int r = 0; r < 4; ++r) {
        int m0 = r * 512 + (lane << 3);
        uint4 ua = *(const uint4*)(gA + m0);
        uint4 ub = *(const uint4*)(gB + m0);
        unsigned uw[4] = {ua.x, ua.y, ua.z, ua.w};
        unsigned vw[4] = {ub.x, ub.y, ub.z, ub.w};
#pragma unroll
        for (int h = 0; h < 4; ++h) {
            float a0 = h2f((unsigned short)(uw[h] & 0xFFFFu));
            float a1 = h2f((unsigned short)(uw[h] >> 16));
            ka[8 * r + 2 * h]     = (__float_as_uint(a0) & 0xFFFFF800u) | (unsigned)(m0 + 2 * h);
            ka[8 * r + 2 * h + 1] = (__float_as_uint(a1) & 0xFFFFF800u) | (unsigned)(m0 + 2 * h + 1);
            float c0v = h2f((unsigned short)(vw[h] & 0xFFFFu));
            float c1v = h2f((unsigned short)(vw[h] >> 16));
            kb[8 * r + 2 * h]     = (__float_as_uint(c0v) & 0xFFFFF800u) | (unsigned)(m0 + 2 * h);
            kb[8 * r + 2 * h + 1] = (__float_as_uint(c1v) & 0xFFFFF800u) | (unsigned)(m0 + 2 * h + 1);
        }
    }
    select20x2(ka, kb, &sidx[2 * w][0], &sidx[2 * w + 1][0], lane);
    __syncthreads();

    // ---- gather-max for points qa, qa+1 ----
    size_t iA = (size_t)b * N_PTS + qa;
    const float inv = rsqrtf(1.0f + 1e-5f);
    float yda[OT], ydb[OT], scl[OT], bis[OT], mxa[OT], mxb[OT];
#pragma unroll
    for (int j = 0; j < OT; ++j) {
        int o = lane + 64 * j;
        yda[j] = b2f(Yh[iA * M2 + COUT + o]);
        ydb[j] = b2f(Yh[(iA + 1) * M2 + COUT + o]);
        scl[j] = gam[o] * inv;
        bis[j] = bet[o];
        mxa[j] = -FLT_MAX; mxb[j] = -FLT_MAX;
    }
    const bf16* Yb = Yh + (size_t)b * N_PTS * M2;
#pragma unroll
    for (int k = 0; k < KNN; ++k) {
        int m0 = sidx[2 * w][k] & (N_PTS - 1);
        int m1 = sidx[2 * w + 1][k] & (N_PTS - 1);
        const bf16* r0 = Yb + (size_t)m0 * M2;
        const bf16* r1 = Yb + (size_t)m1 * M2;
#pragma unroll
        for (int j = 0; j < OT; ++j) {
            int o = lane + 64 * j;
            float ha = (yda[j] + b2f(r0[o])) * scl[j] + bis[j];
            ha = ha > 0.f ? ha : LRELU_S * ha;
            mxa[j] = fmaxf(mxa[j], ha);
            float hb = (ydb[j] + b2f(r1[o])) * scl[j] + bis[j];
            hb = hb > 0.f ? hb : LRELU_S * hb;
            mxb[j] = fmaxf(mxb[j], hb);
        }
    }
    float sa = 0.f, sb = 0.f;
#pragma unroll
    for (int j = 0; j < OT; ++j) {
        bf16 va = __float2bfloat16(mxa[j]);
        bf16 vb = __float2bfloat16(mxb[j]);
        featT[iA * FT + c0f + lane + 64 * j] = va;
        featT[(iA + 1) * FT + c0f + lane + 64 * j] = vb;
        if (xxout) {
            float pa = b2f(va); sa = fmaf(pa, pa, sa);
            float pb = b2f(vb); sb = fmaf(pb, pb, sb);
        }
    }
    if (xxout) {
#pragma unroll
        for (int off = 32; off >= 1; off >>= 1) {
            sa += __shfl_xor(sa, off);
            sb += __shfl_xor(sb, off);
        }
        if (lane == 0) { xxout[iA] = sa; xxout[iA + 1] = sb; }
    }
}

// ---------------------------------------------------------------------------
// EdgeConv (VALU): fallback path.
template<typename T, int C, int COUT, bool WF>
__global__ __launch_bounds__(256) void k_edgeconv(const T* __restrict__ x, int bstride,
                           const int* __restrict__ idx,
                           const float* __restrict__ Wt,
                           const float* __restrict__ gam,
                           const float* __restrict__ bet,
                           bf16* __restrict__ out, int ostride,
                           bf16* __restrict__ featT, int c0f,
                           float* __restrict__ xxout) {
    const int PT = 4;
    const int OT = COUT / 64;
    const int CP = (C + 3) & ~3;
    __shared__ float sh[PT][KNN + 1][CP];

    int ib = blockIdx.x;
    int b  = ib / (N_PTS / PT);
    int n0 = (ib % (N_PTS / PT)) * PT;
    const T* xb = x + (size_t)b * bstride;

    const int TOT = PT * (KNN + 1) * C;
    for (int t = threadIdx.x; t < TOT; t += 256) {
        int pt = t / ((KNN + 1) * C);
        int r  = t % ((KNN + 1) * C);
        int row = r / C, c = r % C;
        int n = n0 + pt;
        int m = (row == 0) ? n
                           : (idx[((size_t)b * N_PTS + n) * KNN + (row - 1)] & (N_PTS - 1));
        sh[pt][row][c] = ldf(&xb[(size_t)c * N_PTS + m]);
    }
    __syncthreads();

    int w = threadIdx.x >> 6, lane = threadIdx.x & 63;
    int n = n0 + w;

    constexpr int KT = (OT >= 4) ? 10 : 20;
    constexpr int NPASS = KNN / KT;

    float base[OT];
    float mx[OT];
#pragma unroll
    for (int j = 0; j < OT; ++j) { base[j] = 0.f; mx[j] = -FLT_MAX; }

    const float inv = rsqrtf(1.0f + 1e-5f);

#pragma unroll
    for (int pass = 0; pass < NPASS; ++pass) {
        float acc[OT][KT];
#pragma unroll
        for (int j = 0; j < OT; ++j)
#pragma unroll
            for (int k = 0; k < KT; ++k) acc[j][k] = 0.f;

        for (int c = 0; c < C; ++c) {
            float xq = sh[w][0][c];
            float w2v[OT];
#pragma unroll
            for (int j = 0; j < OT; ++j)
                w2v[j] = Wt[(size_t)(C + c) * COUT + lane + 64 * j];
            if (pass == 0) {
#pragma unroll
                for (int j = 0; j < OT; ++j) {
                    float w1v = Wt[(size_t)c * COUT + lane + 64 * j];
                    base[j] = fmaf(w1v - w2v[j], xq, base[j]);
                }
            }
#pragma unroll
            for (int k = 0; k < KT; ++k) {
                float nv = sh[w][1 + pass * KT + k][c];
#pragma unroll
                for (int j = 0; j < OT; ++j) acc[j][k] = fmaf(w2v[j], nv, acc[j][k]);
            }
        }

#pragma unroll
        for (int j = 0; j < OT; ++j) {
            int o = lane + 64 * j;
            float scale = gam[o] * inv, bias = bet[o];
#pragma unroll
            for (int k = 0; k < KT; ++k) {
                float h = (base[j] + acc[j][k]) * scale + bias;
                h = h > 0.f ? h : LRELU_S * h;
                mx[j] = fmaxf(mx[j], h);
            }
        }
    }

    float s = 0.f;
#pragma unroll
    for (int j = 0; j < OT; ++j) {
        int o = lane + 64 * j;
        bf16 bv = __float2bfloat16(mx[j]);
        if (!WF) out[(size_t)b * ostride + (size_t)o * N_PTS + n] = bv;
        if (WF) {
            featT[((size_t)b * N_PTS + n) * FT + c0f + o] = bv;
            float q = b2f(bv);
            s = fmaf(q, q, s);
        }
    }
    if (WF && xxout) {
#pragma unroll
        for (int off = 32; off >= 1; off >>= 1) s += __shfl_xor(s, off);
        if (lane == 0) xxout[(size_t)b * N_PTS + n] = s;
    }
}

// ---------------------------------------------------------------------------
// conv5 via MFMA. Block: 64o x 128n, 4 waves (wave owns 32 n-rows), NPOOL=16
// n-chunks -> 1024 blocks, ~34 KB LDS -> 4 blocks/CU. When inputs are bf16
// (isb), the lo-correction MFMAs and Al staging are skipped (exact).
__global__ __launch_bounds__(256) void k_conv5mfma(
        const bf16* __restrict__ featT, const bf16* __restrict__ w5sp,
        const float* __restrict__ g5, const float* __restrict__ b5,
        float* __restrict__ fmxp, float* __restrict__ fsmp,
        const int* __restrict__ flag) {
    __shared__ __align__(16) short Bt[128 * 64];   // 16 KB
    __shared__ __align__(16) short Ah[64 * 64];    //  8 KB
    __shared__ __align__(16) short Al[64 * 64];    //  8 KB
    __shared__ float rmx[4][64];
    __shared__ float rsm[4][64];

    const int isb = *flag;
    int ib = blockIdx.x;                 // B * 16 * 16
    int b  = ib / 256;
    int rem = ib % 256;
    int o0 = (rem >> 4) * 64;
    int nt = rem & 15;
    int tid = threadIdx.x;
    int w = tid >> 6, lane = tid & 63;
    int l15 = lane & 15, quad = lane >> 4;

    const bf16* Whi = w5sp;
    const bf16* Wlo = w5sp + 1024 * 512;
    const bf16* fb  = featT + (size_t)b * N_PTS * FT;
    const int nbase0 = nt * 128;

    floatx4 acc[4][2];
#pragma unroll
    for (int mi = 0; mi < 4; ++mi)
#pragma unroll
        for (int ni = 0; ni < 2; ++ni) acc[mi][ni] = (floatx4){0.f, 0.f, 0.f, 0.f};

    for (int ck = 0; ck < 512; ck += 64) {
        __syncthreads();
#pragma unroll
        for (int it = 0; it < 4; ++it) {                 // B: 128 rows x 64k
            int s = tid + it * 256;
            int row = s >> 3, seg = s & 7;
            int gseg = seg ^ (row & 7);
            gload16(fb + (size_t)(nbase0 + row) * FT + ck + gseg * 8,
                    &Bt[(s & ~63) * 8]);
        }
#pragma unroll
        for (int it = 0; it < 2; ++it) {                 // A hi(/lo): 64 rows x 64k
            int s = tid + it * 256;
            int row = s >> 3, seg = s & 7;
            int gseg = seg ^ (row & 7);
            gload16(Whi + (size_t)(o0 + row) * 512 + ck + gseg * 8, &Ah[(s & ~63) * 8]);
            if (!isb)
                gload16(Wlo + (size_t)(o0 + row) * 512 + ck + gseg * 8, &Al[(s & ~63) * 8]);
        }
        __syncthreads();
#pragma unroll
        for (int kk = 0; kk < 64; kk += 32) {
            int ks = kk >> 3;
            short8v bfr[2], ah[4], al[4];
#pragma unroll
            for (int ni = 0; ni < 2; ++ni) {
                int row = w * 32 + ni * 16 + l15;
                int seg = (ks + quad) ^ (row & 7);
                bfr[ni] = *(const short8v*)&Bt[row * 64 + seg * 8];
            }
#pragma unroll
            for (int mi = 0; mi < 4; ++mi) {
                int row = mi * 16 + l15;
                int seg = (ks + quad) ^ (row & 7);
                ah[mi] = *(const short8v*)&Ah[row * 64 + seg * 8];
                if (!isb) al[mi] = *(const short8v*)&Al[row * 64 + seg * 8];
            }
#pragma unroll
            for (int mi = 0; mi < 4; ++mi)
#pragma unroll
                for (int ni = 0; ni < 2; ++ni) {
                    acc[mi][ni] = __builtin_amdgcn_mfma_f32_16x16x32_bf16(ah[mi], bfr[ni], acc[mi][ni], 0, 0, 0);
                    if (!isb)
                        acc[mi][ni] = __builtin_amdgcn_mfma_f32_16x16x32_bf16(al[mi], bfr[ni], acc[mi][ni], 0, 0, 0);
                }
        }
    }

    const float inv = rsqrtf(1.0f + 1e-5f);
#pragma unroll
    for (int mi = 0; mi < 4; ++mi) {
#pragma unroll
        for (int r = 0; r < 4; ++r) {
            int o = o0 + mi * 16 + quad * 4 + r;
            float scale = g5[o] * inv, bias = b5[o];
            float mx = -FLT_MAX, sm = 0.f;
#pragma unroll
            for (int ni = 0; ni < 2; ++ni) {
                float h = acc[mi][ni][r] * scale + bias;
                h = h > 0.f ? h : LRELU_S * h;
                mx = fmaxf(mx, h);
                sm += h;
            }
#pragma unroll
            for (int off = 1; off <= 8; off <<= 1) {
                mx = fmaxf(mx, __shfl_xor(mx, off));
                sm += __shfl_xor(sm, off);
            }
            if (l15 == 0) {
                rmx[w][mi * 16 + quad * 4 + r] = mx;
                rsm[w][mi * 16 + quad * 4 + r] = sm;
            }
        }
    }
    __syncthreads();
    if (tid < 64) {
        float mx = -FLT_MAX, sm = 0.f;
#pragma unroll
        for (int ww = 0; ww < 4; ++ww) { mx = fmaxf(mx, rmx[ww][tid]); sm += rsm[ww][tid]; }
        fmxp[((size_t)b * 1024 + o0 + tid) * NPOOL + nt] = mx;
        fsmp[((size_t)b * 1024 + o0 + tid) * NPOOL + nt] = sm;
    }
}

// ---------------------------------------------------------------------------
// Pool partial reduce -> fvec (B, 2048) = [max(1024) | mean(1024)].
__global__ void k_pool(const float* __restrict__ fmxp, const float* __restrict__ fsmp,
                       float* __restrict__ fvec) {
    int i = blockIdx.x * blockDim.x + threadIdx.x;
    if (i >= B_SZ * 1024) return;
    int b = i >> 10, o = i & 1023;
    float mx = -FLT_MAX, sm = 0.f;
    for (int ch = 0; ch < NPOOL; ++ch) {
        mx = fmaxf(mx, fmxp[(size_t)i * NPOOL + ch]);
        sm += fsmp[(size_t)i * NPOOL + ch];
    }
    fvec[(size_t)b * 2048 + o] = mx;
    fvec[(size_t)b * 2048 + 1024 + o] = sm * (1.0f / N_PTS);
}

// ---------------------------------------------------------------------------
// fc1 (raw-dtype weights): block per (b,o).
__global__ __launch_bounds__(256) void k_fc1(const float* __restrict__ fvec,
        const void* __restrict__ fw1, const void* __restrict__ fb1,
        const void* __restrict__ g6,  const void* __restrict__ b6,
        const int* __restrict__ flag, float* __restrict__ tbuf) {
    __shared__ float red[4];
    int ib = blockIdx.x;
    int b = ib >> 9, o = ib & 511;
    const float* fv = fvec + (size_t)b * 2048;
    int tid = threadIdx.x;
    const int isb = *flag;
    float s = 0.f;
    if (isb) {
        const bf16* wr = (const bf16*)fw1 + (size_t)o * 2048;
        for (int j = tid; j < 2048; j += 256) s = fmaf(b2f(wr[j]), fv[j], s);
    } else {
        const float* wr = (const float*)fw1 + (size_t)o * 2048;
        for (int j = tid; j < 2048; j += 256) s = fmaf(wr[j], fv[j], s);
    }
#pragma unroll
    for (int off = 32; off >= 1; off >>= 1) s += __shfl_xor(s, off);
    if ((tid & 63) == 0) red[tid >> 6] = s;
    __syncthreads();
    if (tid == 0) {
        float fb = isb ? b2f(((const bf16*)fb1)[o]) : ((const float*)fb1)[o];
        float gg = isb ? b2f(((const bf16*)g6)[o])  : ((const float*)g6)[o];
        float bb = isb ? b2f(((const bf16*)b6)[o])  : ((const float*)b6)[o];
        float acc = fb + red[0] + red[1] + red[2] + red[3];
        float h = acc * gg * rsqrtf(1.0f + 1e-5f) + bb;
        tbuf[(size_t)b * 512 + o] = h > 0.f ? h : LRELU_S * h;
    }
}

// ---------------------------------------------------------------------------
// fc2 (raw-dtype weights): block per (b,o).
__global__ __launch_bounds__(256) void k_fc2(const float* __restrict__ tbuf,
        const void* __restrict__ fw2, const void* __restrict__ fb2,
        const void* __restrict__ g7,  const void* __restrict__ b7,
        const int* __restrict__ flag, void* __restrict__ out) {
    __shared__ float red[4];
    int ib = blockIdx.x;
    int b = ib >> 8, o = ib & 255;
    const float* tv = tbuf + (size_t)b * 512;
    int tid = threadIdx.x;
    const int isb = *flag;
    float s;
    if (isb) {
        const bf16* wr = (const bf16*)fw2 + (size_t)o * 512;
        s = fmaf(b2f(wr[tid]), tv[tid], b2f(wr[tid + 256]) * tv[tid + 256]);
    } else {
        const float* wr = (const float*)fw2 + (size_t)o * 512;
        s = fmaf(wr[tid], tv[tid], wr[tid + 256] * tv[tid + 256]);
    }
#pragma unroll
    for (int off = 32; off >= 1; off >>= 1) s += __shfl_xor(s, off);
    if ((tid & 63) == 0) red[tid >> 6] = s;
    __syncthreads();
    if (tid == 0) {
        float fb = isb ? b2f(((const bf16*)fb2)[o]) : ((const float*)fb2)[o];
        float gg = isb ? b2f(((const bf16*)g7)[o])  : ((const float*)g7)[o];
        float bb = isb ? b2f(((const bf16*)b7)[o])  : ((const float*)b7)[o];
        float acc = fb + red[0] + red[1] + red[2] + red[3];
        float h = acc * gg * rsqrtf(1.0f + 1e-5f) + bb;
        if (isb) ((bf16*)out)[(size_t)b * 256 + o] = __float2bfloat16(h);
        else     ((float*)out)[(size_t)b * 256 + o] = h;
    }
}

// ---------------------------------------------------------------------------
// Fallback conv5 (VALU) + head, used when ws too small for the gram path.
#define NCH 2
__global__ __launch_bounds__(256) void k_conv5pool(const bf16* __restrict__ feat,
                            const float* __restrict__ w5,
                            const float* __restrict__ g5,
                            const float* __restrict__ b5,
                            float* __restrict__ fmxp, float* __restrict__ fsmp) {
    const int OT = 8;
    const int NT = 4;
    const int CHN = N_PTS / NCH;
    __shared__ float wl[OT][512];
    __shared__ float rmx[4][OT];
    __shared__ float rsm[4][OT];

    int ib = blockIdx.x;
    int ch = ib % NCH;
    int ot = (ib / NCH) % (1024 / OT);
    int b  = ib / (NCH * (1024 / OT));
    int o0 = ot * OT;
    const bf16* fb = feat + (size_t)b * 512 * N_PTS;

    for (int t = threadIdx.x; t < OT * 512; t += 256) {
        int o = t >> 9, c = t & 511;
        wl[o][c] = w5[(size_t)(o0 + o) * 512 + c];
    }
    __syncthreads();

    const int n0 = ch * CHN + threadIdx.x * NT;

    float acc[OT][NT];
#pragma unroll
    for (int o = 0; o < OT; ++o)
#pragma unroll
        for (int t = 0; t < NT; ++t) acc[o][t] = 0.f;

    for (int c = 0; c < 512; c += 4) {
        float fv[4][NT];
#pragma unroll
        for (int j = 0; j < 4; ++j) {
            uint2 u = *(const uint2*)(fb + (size_t)(c + j) * N_PTS + n0);
            fv[j][0] = __uint_as_float(u.x << 16);
            fv[j][1] = __uint_as_float(u.x & 0xFFFF0000u);
            fv[j][2] = __uint_as_float(u.y << 16);
            fv[j][3] = __uint_as_float(u.y & 0xFFFF0000u);
        }
#pragma unroll
        for (int o = 0; o < OT; ++o) {
            float4 wv = *(const float4*)&wl[o][c];
#pragma unroll
            for (int t = 0; t < NT; ++t) {
                acc[o][t] = fmaf(wv.x, fv[0][t], acc[o][t]);
                acc[o][t] = fmaf(wv.y, fv[1][t], acc[o][t]);
                acc[o][t] = fmaf(wv.z, fv[2][t], acc[o][t]);
                acc[o][t] = fmaf(wv.w, fv[3][t], acc[o][t]);
            }
        }
    }

    const float inv = rsqrtf(1.0f + 1e-5f);
    int w = threadIdx.x >> 6, lane = threadIdx.x & 63;
#pragma unroll
    for (int o = 0; o < OT; ++o) {
        float scale = g5[o0 + o] * inv, bias = b5[o0 + o];
        float mx = -FLT_MAX, sm = 0.f;
#pragma unroll
        for (int t = 0; t < NT; ++t) {
            float h = acc[o][t] * scale + bias;
            h = h > 0.f ? h : LRELU_S * h;
            mx = fmaxf(mx, h);
            sm += h;
        }
#pragma unroll
        for (int off = 32; off >= 1; off >>= 1) {
            mx = fmaxf(mx, __shfl_xor(mx, off));
            sm += __shfl_xor(sm, off);
        }
        if (lane == 0) { rmx[w][o] = mx; rsm[w][o] = sm; }
    }
    __syncthreads();
    if (threadIdx.x < OT) {
        int o = threadIdx.x;
        float mx = -FLT_MAX, sm = 0.f;
#pragma unroll
        for (int ww = 0; ww < 4; ++ww) { mx = fmaxf(mx, rmx[ww][o]); sm += rsm[ww][o]; }
        fmxp[((size_t)b * 1024 + o0 + o) * NCH + ch] = mx;
        fsmp[((size_t)b * 1024 + o0 + o) * NCH + ch] = sm;
    }
}

__global__ void k_head(const float* __restrict__ fmxp, const float* __restrict__ fsmp,
                       const float* __restrict__ fw1, const float* __restrict__ fb1,
                       const float* __restrict__ g6,  const float* __restrict__ b6,
                       const float* __restrict__ fw2, const float* __restrict__ fb2,
                       const float* __restrict__ g7,  const float* __restrict__ b7,
                       const int* __restrict__ flag, void* __restrict__ out) {
    __shared__ float f[2048];
    __shared__ float t[512];
    int b = blockIdx.x;
    for (int i = threadIdx.x; i < 1024; i += 256) {
        float mx = -FLT_MAX, sm = 0.f;
        for (int ch = 0; ch < NCH; ++ch) {
            mx = fmaxf(mx, fmxp[((size_t)b * 1024 + i) * NCH + ch]);
            sm += fsmp[((size_t)b * 1024 + i) * NCH + ch];
        }
        f[i]        = mx;
        f[1024 + i] = sm * (1.0f / N_PTS);
    }
    __syncthreads();
    const float inv = rsqrtf(1.0f + 1e-5f);
    for (int o = threadIdx.x; o < 512; o += 256) {
        const float* wr = fw1 + (size_t)o * 2048;
        float acc = fb1[o];
        for (int j = 0; j < 2048; ++j) acc += wr[j] * f[j];
        float h = acc * g6[o] * inv + b6[o];
        t[o] = h > 0.f ? h : LRELU_S * h;
    }
    __syncthreads();
    {
        int o = threadIdx.x;
        const float* wr = fw2 + (size_t)o * 512;
        float acc = fb2[o];
        for (int j = 0; j < 512; ++j) acc += wr[j] * t[j];
        float h = acc * g7[o] * inv + b7[o];
        if (*flag) ((bf16*)out)[(size_t)b * 256 + o] = __float2bfloat16(h);
        else       ((float*)out)[(size_t)b * 256 + o] = h;
    }
}

// ---------------------------------------------------------------------------
extern "C" void kernel_launch(void* const* d_in, const int* in_sizes, int n_in,
                              void* d_out, int out_size, void* d_ws, size_t ws_size,
                              hipStream_t stream) {
    static const int wsz[23] = {
        384, 64, 64,   8192, 64, 64,   16384, 128, 128,   65536, 256, 256,
        524288, 1024, 1024,   1048576, 512,   512, 512,   131072, 256,   256, 256
    };
    static const int trows[23] = {64,0,0, 64,0,0, 128,0,0, 256,0,0, 0,0,0, 0,0, 0,0, 0,0, 0,0};
    static const int tcols[23] = { 6,0,0,128,0,0, 128,0,0, 256,0,0, 0,0,0, 0,0, 0,0, 0,0, 0,0};

    WPack wp;
    int total = 0;
    for (int i = 0; i < 23; ++i) {
        wp.src[i] = d_in[i + 1]; wp.off[i] = total; total += wsz[i];
        wp.rows[i] = trows[i]; wp.cols[i] = tcols[i];
    }
    wp.off[23] = total;

    const size_t flag_bytes = 16;
    const size_t x0_bytes   = (size_t)B_SZ * 3 * N_PTS * 4;
    const size_t feat_bytes = (size_t)B_SZ * 512 * N_PTS * 2;
    const size_t idx_bytes  = (size_t)B_SZ * N_PTS * KNN * 4;
    const size_t pool_bytes = (size_t)B_SZ * 1024 * 4 * 2;
    const size_t wf_bytes   = (size_t)total * 4;
    const size_t base_need  = flag_bytes + x0_bytes + feat_bytes + idx_bytes + pool_bytes + wf_bytes;

    const size_t featT_bytes = (size_t)B_SZ * N_PTS * FT * 2;           //  8 MB
    const size_t xx_bytes    = (size_t)B_SZ * N_PTS * 4;
    const size_t wsp2_elems  = 4 * 64 * 64;
    const size_t wsp3_elems  = 4 * 128 * 64;
    const size_t wsp4_elems  = 4 * 256 * 128;
    const size_t w5sp_elems  = 2 * 1024 * 512;
    const size_t wsp_bytes   = (wsp2_elems + wsp3_elems + wsp4_elems + w5sp_elems) * 2;
    const size_t Yh_bytes    = (size_t)B_SZ * N_PTS * 512 * 2;          //  8 MB (max M2)
    const size_t S_bytes     = (size_t)B_SZ * N_PTS * N_PTS * 2;        // 32 MB fp16 dist
    const size_t full_need   = base_need + featT_bytes + 2 * xx_bytes + wsp_bytes
                             + Yh_bytes + S_bytes;

    if (ws_size < base_need) return;   // graceful fail
    const bool use_gram = (ws_size >= full_need);

    char* w = (char*)d_ws;
    int*   flag = (int*)w;              w += flag_bytes;
    float* x0   = (float*)w;            w += x0_bytes;
    bf16*  feat = (bf16*)w;             w += feat_bytes;
    int*   idx  = (int*)w;              w += idx_bytes;
    w += pool_bytes;
    float* wf   = (float*)w;            w += wf_bytes;
    bf16*  featT = (bf16*)w;            w += featT_bytes;
    float* xxA   = (float*)w;           w += xx_bytes;
    float* xxB   = (float*)w;           w += xx_bytes;
    bf16*  wsp2  = (bf16*)w;            w += wsp2_elems * 2;
    bf16*  wsp3  = (bf16*)w;            w += wsp3_elems * 2;
    bf16*  wsp4  = (bf16*)w;            w += wsp4_elems * 2;
    bf16*  w5sp  = (bf16*)w;            w += w5sp_elems * 2;
    bf16*  Yh    = (bf16*)w;            w += Yh_bytes;
    unsigned short* D = (unsigned short*)w;   // fp16 distance matrix

    // overlays in the idx region (idx unused in gram path):
    // fmxp+fsmp (512K) + fvec (32K) + tbuf (8K) <= idx_bytes (640K)
    float* fmxp = (float*)idx;                               // B*1024*NPOOL
    float* fsmp = fmxp + (size_t)B_SZ * 1024 * NPOOL;        // B*1024*NPOOL
    float* fvec = fsmp + (size_t)B_SZ * 1024 * NPOOL;        // B*2048
    float* tbuf = fvec + (size_t)B_SZ * 2048;                // B*512

    const int FBS = 512 * N_PTS;

    const float* w1t = wf + wp.off[0],  *g1 = wf + wp.off[1],  *b1 = wf + wp.off[2];
    const float* w2t = wf + wp.off[3],  *g2 = wf + wp.off[4],  *b2 = wf + wp.off[5];
    const float* w3t = wf + wp.off[6],  *g3 = wf + wp.off[7],  *b3 = wf + wp.off[8];
    const float* w4t = wf + wp.off[9],  *g4 = wf + wp.off[10], *b4 = wf + wp.off[11];
    const float* w5  = wf + wp.off[12], *g5 = wf + wp.off[13], *b5 = wf + wp.off[14];
    const float* fw1 = wf + wp.off[15], *fb1 = wf + wp.off[16];
    const float* g6  = wf + wp.off[17], *b6 = wf + wp.off[18];
    const float* fw2 = wf + wp.off[19], *fb2 = wf + wp.off[20];
    const float* g7  = wf + wp.off[21], *b7 = wf + wp.off[22];

    const int GK = B_SZ * N_PTS / 4;    // 2048 blocks
    const int G8 = B_SZ * N_PTS / 8;    // 1024 blocks (2 queries/wave kernels)
    const int NG = B_SZ * NTRI;         // gram blocks in k_gx (upper triangle)

    if (use_gram) {
        const int rlimit = wp.off[15];
        const int nbrep = (rlimit + 255) / 256;
        const int prep_grid = nbrep + 16 + 32 + 128 + 2048 + 32;
        k_prep<<<prep_grid, 256, 0, stream>>>(wp, wf, rlimit,
                                              d_in[4], wsp2, d_in[7], wsp3,
                                              d_in[10], wsp4, d_in[13], w5sp,
                                              d_in[0], x0, flag);

        // layer 1: fused kNN + EdgeConv (writes featT[0:64) + xxA)
        k_knn3ec<<<G8, 256, 0, stream>>>(x0, w1t, g1, b1, featT, xxA);
        // layer 2
        k_gx<64, 64><<<NG + 64, 256, 0, stream>>>(featT, 0, wsp2, xxA, D, Yh, flag);
        k_selgmax<64><<<G8, 256, 0, stream>>>(D, Yh, g2, b2, featT, 64, xxB);
        // layer 3
        k_gx<64, 128><<<NG + 128, 256, 0, stream>>>(featT, 64, wsp3, xxB, D, Yh, flag);
        k_selgmax<128><<<G8, 256, 0, stream>>>(D, Yh, g3, b3, featT, 128, xxA);
        // layer 4 (writes featT channels [256,512) for conv5)
        k_gx<128, 256><<<NG + 256, 256, 0, stream>>>(featT, 128, wsp4, xxA, D, Yh, flag);
        k_selgmax<256><<<G8, 256, 0, stream>>>(D, Yh, g4, b4, featT, 256, nullptr);

        // conv5 MFMA + pooling partials, then head GEMVs (raw fc weights)
        k_conv5mfma<<<B_SZ * 256, 256, 0, stream>>>(featT, w5sp, g5, b5, fmxp, fsmp, flag);
        k_pool<<<(B_SZ * 1024 + 255) / 256, 256, 0, stream>>>(fmxp, fsmp, fvec);
        k_fc1<<<B_SZ * 512, 256, 0, stream>>>(fvec, d_in[16], d_in[17], d_in[18], d_in[19],
                                              flag, tbuf);
        k_fc2<<<B_SZ * 256, 256, 0, stream>>>(tbuf, d_in[20], d_in[21], d_in[22], d_in[23],
                                              flag, d_out);
    } else {
        k_sniff<<<1, 64, 0, stream>>>((const unsigned short*)d_in[0], flag);
        k_repack<<<(total + 255) / 256, 256, 0, stream>>>(wp, flag, wf, total);
        k_transpose<<<(B_SZ * N_PTS + 255) / 256, 256, 0, stream>>>(d_in[0], flag, x0);

        k_knn<float, 3><<<GK, 256, 0, stream>>>(x0, 3 * N_PTS, idx);
        k_edgeconv<float, 3, 64, false><<<GK, 256, 0, stream>>>(
            x0, 3 * N_PTS, idx, w1t, g1, b1, feat + 0 * N_PTS, FBS, nullptr, 0, nullptr);
        k_knn<bf16, 64><<<GK, 256, 0, stream>>>(feat + 0 * N_PTS, FBS, idx);
        k_edgeconv<bf16, 64, 64, false><<<GK, 256, 0, stream>>>(
            feat + 0 * N_PTS, FBS, idx, w2t, g2, b2, feat + 64 * N_PTS, FBS, nullptr, 0, nullptr);
        k_knn<bf16, 64><<<GK, 256, 0, stream>>>(feat + 64 * N_PTS, FBS, idx);
        k_edgeconv<bf16, 64, 128, false><<<GK, 256, 0, stream>>>(
            feat + 64 * N_PTS, FBS, idx, w3t, g3, b3, feat + 128 * N_PTS, FBS, nullptr, 0, nullptr);
        k_knn<bf16, 128><<<GK, 256, 0, stream>>>(feat + 128 * N_PTS, FBS, idx);
        k_edgeconv<bf16, 128, 256, false><<<GK, 256, 0, stream>>>(
            feat + 128 * N_PTS, FBS, idx, w4t, g4, b4, feat + 256 * N_PTS, FBS, nullptr, 0, nullptr);

        k_conv5pool<<<B_SZ * (1024 / 8) * NCH, 256, 0, stream>>>(feat, w5, g5, b5, fmxp, fsmp);
        k_head<<<B_SZ, 256, 0, stream>>>(fmxp, fsmp, fw1, fb1, g6, b6, fw2, fb2, g7, b7,
                                         flag, d_out);
    }
}